// Round 4
// baseline (444.824 us; speedup 1.0000x reference)
//
#include <hip/hip_runtime.h>

#define D_MODEL 1024
#define QLEN 1024
#define MLEN 1024
#define KLEN 2048

typedef __bf16 bf16x8 __attribute__((ext_vector_type(8)));
typedef __bf16 bf16x4 __attribute__((ext_vector_type(4)));
typedef float f32x4 __attribute__((ext_vector_type(4)));

__device__ __forceinline__ void gload16(const void* g, void* l) {
    __builtin_amdgcn_global_load_lds(
        (const __attribute__((address_space(1))) void*)g,
        (__attribute__((address_space(3))) void*)l, 16, 0, 0);
}

// ============ bf16 MFMA GEMM: C[M,N] = A[M,K] @ Bt[N,K]^T (+U, +bias, relu) ============
// 4 waves in 2x2 grid. MT = m-frags per wave (BM = MT*32). BN=128, BK=64.
// LDS XOR-swizzle chunk c' = c ^ (row&7); staged linearly via pre-swizzled global source.
template<int MT>
__global__ __launch_bounds__(256) void gemm_bf16_k(
    const __bf16* __restrict__ A,   // [M][K]
    const __bf16* __restrict__ Bt,  // [N][K]
    float* __restrict__ C, __bf16* __restrict__ Cb,
    const float* __restrict__ U, const float* __restrict__ bias,
    int K, int ldC, int ldU, int relu,
    long long sB, long long sC, long long sU)
{
    __shared__ __bf16 As[MT * 32][64];
    __shared__ __bf16 Bs[128][64];

    const int bz = blockIdx.z;
    Bt += (long long)bz * sB;
    if (C)  C  += (long long)bz * sC;
    if (Cb) Cb += (long long)bz * sC;
    if (U)  U  += (long long)bz * sU;

    const int t = threadIdx.x;
    const int lane = t & 63, w = t >> 6;
    const int l15 = lane & 15, lg = lane >> 4;
    const int m0 = blockIdx.y * (MT * 32);
    const int n0 = blockIdx.x * 128;
    const int wm = w >> 1, wn = w & 1;

    const int srow = lane >> 3;   // 0..7
    const int cpr  = lane & 7;    // dest chunk'

    f32x4 acc[MT][4] = {};

    for (int k0 = 0; k0 < K; k0 += 64) {
        #pragma unroll
        for (int i = 0; i < MT; ++i) {
            int r = i * 32 + w * 8 + srow;
            int c = cpr ^ (r & 7);
            gload16(&A[(long long)(m0 + r) * K + k0 + c * 8], &As[i * 32 + w * 8][0]);
        }
        #pragma unroll
        for (int i = 0; i < 4; ++i) {
            int r = i * 32 + w * 8 + srow;
            int c = cpr ^ (r & 7);
            gload16(&Bt[(long long)(n0 + r) * K + k0 + c * 8], &Bs[i * 32 + w * 8][0]);
        }
        __syncthreads();
        #pragma unroll
        for (int kk = 0; kk < 2; ++kk) {
            bf16x8 bfr[4];
            #pragma unroll
            for (int nt = 0; nt < 4; ++nt) {
                int nr = wn * 64 + nt * 16 + l15;
                bfr[nt] = *(const bf16x8*)&Bs[nr][((kk * 4 + lg) ^ (nr & 7)) * 8];
            }
            #pragma unroll
            for (int mt = 0; mt < MT; ++mt) {
                int mr = wm * (MT * 16) + mt * 16 + l15;
                bf16x8 afr = *(const bf16x8*)&As[mr][((kk * 4 + lg) ^ (mr & 7)) * 8];
                #pragma unroll
                for (int nt = 0; nt < 4; ++nt)
                    acc[mt][nt] = __builtin_amdgcn_mfma_f32_16x16x32_bf16(afr, bfr[nt], acc[mt][nt], 0, 0, 0);
            }
        }
        __syncthreads();
    }

    #pragma unroll
    for (int mt = 0; mt < MT; ++mt) {
        #pragma unroll
        for (int nt = 0; nt < 4; ++nt) {
            #pragma unroll
            for (int rg = 0; rg < 4; ++rg) {
                int m = m0 + wm * (MT * 16) + mt * 16 + lg * 4 + rg;
                int n = n0 + wn * 64 + nt * 16 + l15;
                float v = acc[mt][nt][rg];
                if (U)    v += U[(long long)m * ldU + n];
                if (bias) v += bias[n];
                if (relu) v = fmaxf(v, 0.0f);
                if (Cb) Cb[(long long)m * ldC + n] = (__bf16)v;
                else    C [(long long)m * ldC + n] = v;
            }
        }
    }
}

// ============ fp32 -> bf16 elementwise convert (n % 4 == 0) ============
__global__ __launch_bounds__(256) void conv_bf16(
    const float* __restrict__ s, __bf16* __restrict__ d, int n)
{
    int i = (blockIdx.x * 256 + threadIdx.x) * 4;
    if (i < n) {
        float4 v = *(const float4*)&s[i];
        bf16x4 o = { (__bf16)v.x, (__bf16)v.y, (__bf16)v.z, (__bf16)v.w };
        *(bf16x4*)&d[i] = o;
    }
}

// ============ transpose-convert: S[R][Cc] fp32 -> D[Cc][R] bf16 ============
__global__ __launch_bounds__(256) void transp_bf16(
    const float* __restrict__ S, __bf16* __restrict__ D,
    int R, int Cc, long long sS, long long sD)
{
    S += (long long)blockIdx.z * sS;
    D += (long long)blockIdx.z * sD;
    __shared__ float ts[32][33];
    int r0 = blockIdx.y * 32, c0 = blockIdx.x * 32;
    int tr = threadIdx.x >> 5, tc = threadIdx.x & 31;
    #pragma unroll
    for (int p = 0; p < 4; ++p)
        ts[tr + p * 8][tc] = S[(long long)(r0 + tr + p * 8) * Cc + c0 + tc];
    __syncthreads();
    #pragma unroll
    for (int p = 0; p < 4; ++p)
        D[(long long)(c0 + tr + p * 8) * R + r0 + tc] = (__bf16)ts[tc][tr + p * 8];
}

// zero pos_t rows [2048, 2112) : 64 x 1024 bf16
__global__ __launch_bounds__(256) void pad_pos(__bf16* __restrict__ pt) {
    int i = (blockIdx.x * 256 + threadIdx.x) * 4;     // 16384 threads
    bf16x4 zv = { (__bf16)0.f, (__bf16)0.f, (__bf16)0.f, (__bf16)0.f };
    *(bf16x4*)&pt[2048 * 1024 + i] = zv;
}

// ================= MFMA flash attention (band j-i in [25,1024]) =================
// wh bf16 (B,3072,2048); rk bf16 compact [1024][1152], col cp = p - 960.
__global__ __launch_bounds__(256) void attn_mfma(
    const __bf16* __restrict__ WH, const __bf16* __restrict__ RK,
    const float* __restrict__ rwb, const float* __restrict__ rrb,
    __bf16* __restrict__ AVt)       // out: (B, Q, 1024) token-major bf16
{
    __shared__ __bf16 KT[64][72];
    __shared__ __bf16 RT[128][72];
    __shared__ __bf16 VS[64][72];
    __shared__ __bf16 PS[64][72];
    __shared__ __bf16 BT[64][136];

    const int d = blockIdx.x;
    const int xcd = d & 7, idx = d >> 3;
    const int qt = idx & 15;
    const int gq = xcd + 8 * (idx >> 4);
    const int b = gq >> 4, n = gq & 15;
    const int i0 = qt * 64;

    const int t = threadIdx.x;
    const int lane = t & 63, w = t >> 6;
    const int l15 = lane & 15, lg = lane >> 4;

    const __bf16* whb = WH + (long long)b * 3072 * 2048;
    const __bf16* qb = whb + (long long)(n * 64) * 2048;
    const __bf16* kb = whb + (long long)(1024 + n * 64) * 2048;
    const __bf16* vb = whb + (long long)(2048 + n * 64) * 2048;
    const __bf16* rb = RK + (long long)(n * 64) * 1152;

    // ---- prologue: stage Q transposed (+biases): Qw -> PS[q][dh], Qr -> BT[q][dh]
    {
        int c8 = (t & 7) * 8;
        int dh0 = t >> 3;            // 0..31
        #pragma unroll
        for (int di = 0; di < 2; ++di) {
            int dh = dh0 + di * 32;
            bf16x8 qv = *(const bf16x8*)&qb[(long long)dh * 2048 + 1024 + i0 + c8];
            float bw = rwb[n * 64 + dh], br = rrb[n * 64 + dh];
            #pragma unroll
            for (int e = 0; e < 8; ++e) {
                float qf = (float)qv[e];
                PS[c8 + e][dh] = (__bf16)(qf + bw);
                BT[c8 + e][dh] = (__bf16)(qf + br);
            }
        }
    }
    __syncthreads();
    bf16x8 qw0, qw1, qr0, qr1;
    {
        int mrow = w * 16 + l15;
        int k8 = lg * 8;
        qw0 = *(const bf16x8*)&PS[mrow][k8];
        qw1 = *(const bf16x8*)&PS[mrow][32 + k8];
        qr0 = *(const bf16x8*)&BT[mrow][k8];
        qr1 = *(const bf16x8*)&BT[mrow][32 + k8];
    }

    f32x4 O0 = {}, O1 = {}, O2 = {}, O3 = {};
    float rm[4] = {-1e30f, -1e30f, -1e30f, -1e30f};
    float rl[4] = {0.f, 0.f, 0.f, 0.f};

    for (int kt = 0; kt <= 16; ++kt) {
        const int j0 = i0 + kt * 64;
        const int pbc = kt * 64;          // compact col base: p = 960 + pbc + pi
        __syncthreads();
        {
            int c8 = (t & 7) * 8;
            int dh0 = t >> 3;             // 0..31
            #pragma unroll
            for (int di = 0; di < 2; ++di) {
                int dh = dh0 + di * 32;
                bf16x8 kv = *(const bf16x8*)&kb[(long long)dh * 2048 + j0 + c8];
                #pragma unroll
                for (int e = 0; e < 8; ++e) KT[c8 + e][dh] = kv[e];
                *(bf16x8*)&VS[dh][c8] = *(const bf16x8*)&vb[(long long)dh * 2048 + j0 + c8];
            }
            int pc = (t & 15) * 8;
            int dh1 = t >> 4;             // 0..15
            #pragma unroll
            for (int di = 0; di < 4; ++di) {
                int dh = dh1 + di * 16;
                bf16x8 rv = *(const bf16x8*)&rb[(long long)dh * 1152 + pbc + pc];
                #pragma unroll
                for (int e = 0; e < 8; ++e) RT[pc + e][dh] = rv[e];
            }
        }
        __syncthreads();

        // ---- BD_raw[own 16 q rows][128 p] -> BT (wave-private rows)
        #pragma unroll
        for (int pt = 0; pt < 8; ++pt) {
            f32x4 c = {};
            c = __builtin_amdgcn_mfma_f32_16x16x32_bf16(qr0, *(const bf16x8*)&RT[pt * 16 + l15][lg * 8], c, 0, 0, 0);
            c = __builtin_amdgcn_mfma_f32_16x16x32_bf16(qr1, *(const bf16x8*)&RT[pt * 16 + l15][32 + lg * 8], c, 0, 0, 0);
            #pragma unroll
            for (int rg = 0; rg < 4; ++rg)
                BT[w * 16 + lg * 4 + rg][pt * 16 + l15] = (__bf16)c[rg];
        }

        // ---- AC + BD lookup + scale + band mask
        float sv[4][4];
        #pragma unroll
        for (int nt = 0; nt < 4; ++nt) {
            f32x4 c = {};
            c = __builtin_amdgcn_mfma_f32_16x16x32_bf16(qw0, *(const bf16x8*)&KT[nt * 16 + l15][lg * 8], c, 0, 0, 0);
            c = __builtin_amdgcn_mfma_f32_16x16x32_bf16(qw1, *(const bf16x8*)&KT[nt * 16 + l15][32 + lg * 8], c, 0, 0, 0);
            int jc = nt * 16 + l15;
            #pragma unroll
            for (int rg = 0; rg < 4; ++rg) {
                int ir = w * 16 + lg * 4 + rg;
                int dji = jc - ir;
                float s = (c[rg] + (float)BT[ir][dji + 63]) * 0.125f;
                bool valid = (kt == 0) ? (dji >= 25)
                           : (kt == 1) ? (dji >= -39)
                           : (kt == 16) ? (dji <= 0) : true;
                sv[nt][rg] = valid ? s : -1e30f;
            }
        }

        // ---- online softmax
        float fac[4], nm[4];
        #pragma unroll
        for (int rg = 0; rg < 4; ++rg) {
            float mx = fmaxf(fmaxf(sv[0][rg], sv[1][rg]), fmaxf(sv[2][rg], sv[3][rg]));
            mx = fmaxf(mx, __shfl_xor(mx, 1, 16));
            mx = fmaxf(mx, __shfl_xor(mx, 2, 16));
            mx = fmaxf(mx, __shfl_xor(mx, 4, 16));
            mx = fmaxf(mx, __shfl_xor(mx, 8, 16));
            nm[rg] = fmaxf(rm[rg], mx);
            fac[rg] = __expf(rm[rg] - nm[rg]);
            rm[rg] = nm[rg];
        }
        float ls[4] = {0.f, 0.f, 0.f, 0.f};
        #pragma unroll
        for (int nt = 0; nt < 4; ++nt) {
            int jc = nt * 16 + l15;
            #pragma unroll
            for (int rg = 0; rg < 4; ++rg) {
                float p = (sv[nt][rg] > -1e29f) ? __expf(sv[nt][rg] - nm[rg]) : 0.0f;
                ls[rg] += p;
                PS[w * 16 + lg * 4 + rg][jc] = (__bf16)p;
            }
        }
        #pragma unroll
        for (int rg = 0; rg < 4; ++rg) {
            float s2 = ls[rg];
            s2 += __shfl_xor(s2, 1, 16);
            s2 += __shfl_xor(s2, 2, 16);
            s2 += __shfl_xor(s2, 4, 16);
            s2 += __shfl_xor(s2, 8, 16);
            rl[rg] = rl[rg] * fac[rg] + s2;
            O0[rg] *= fac[rg]; O1[rg] *= fac[rg]; O2[rg] *= fac[rg]; O3[rg] *= fac[rg];
        }

        // ---- PV
        bf16x8 pa0 = *(const bf16x8*)&PS[w * 16 + l15][lg * 8];
        bf16x8 pa1 = *(const bf16x8*)&PS[w * 16 + l15][32 + lg * 8];
        O0 = __builtin_amdgcn_mfma_f32_16x16x32_bf16(pa0, *(const bf16x8*)&VS[ 0 + l15][lg * 8], O0, 0, 0, 0);
        O0 = __builtin_amdgcn_mfma_f32_16x16x32_bf16(pa1, *(const bf16x8*)&VS[ 0 + l15][32 + lg * 8], O0, 0, 0, 0);
        O1 = __builtin_amdgcn_mfma_f32_16x16x32_bf16(pa0, *(const bf16x8*)&VS[16 + l15][lg * 8], O1, 0, 0, 0);
        O1 = __builtin_amdgcn_mfma_f32_16x16x32_bf16(pa1, *(const bf16x8*)&VS[16 + l15][32 + lg * 8], O1, 0, 0, 0);
        O2 = __builtin_amdgcn_mfma_f32_16x16x32_bf16(pa0, *(const bf16x8*)&VS[32 + l15][lg * 8], O2, 0, 0, 0);
        O2 = __builtin_amdgcn_mfma_f32_16x16x32_bf16(pa1, *(const bf16x8*)&VS[32 + l15][32 + lg * 8], O2, 0, 0, 0);
        O3 = __builtin_amdgcn_mfma_f32_16x16x32_bf16(pa0, *(const bf16x8*)&VS[48 + l15][lg * 8], O3, 0, 0, 0);
        O3 = __builtin_amdgcn_mfma_f32_16x16x32_bf16(pa1, *(const bf16x8*)&VS[48 + l15][32 + lg * 8], O3, 0, 0, 0);
    }

    // epilogue
    #pragma unroll
    for (int rg = 0; rg < 4; ++rg) {
        float inv = 1.0f / rl[rg];
        int q = i0 + w * 16 + lg * 4 + rg;
        long long base = ((long long)b * 1024 + q) * 1024 + n * 64;
        AVt[base +  0 + l15] = (__bf16)(O0[rg] * inv);
        AVt[base + 16 + l15] = (__bf16)(O1[rg] * inv);
        AVt[base + 32 + l15] = (__bf16)(O2[rg] * inv);
        AVt[base + 48 + l15] = (__bf16)(O3[rg] * inv);
    }
}

// ================= LN1 =================
__global__ __launch_bounds__(256) void ln1_kernel(
    const float* __restrict__ AO, const float* __restrict__ bo,
    const float* __restrict__ Z, __bf16* __restrict__ Hb)
{
    int i = blockIdx.x, b = blockIdx.y, t = threadIdx.x;
    __shared__ float xs[D_MODEL];
    __shared__ float red[256];
    __shared__ float smu, srstd;
    long long base = (long long)b * D_MODEL * QLEN;

    float lsum = 0.0f;
    for (int dd = t; dd < D_MODEL; dd += 256) {
        float v = AO[base + (long long)dd * QLEN + i] + bo[dd] + Z[base + (long long)dd * QLEN + i];
        xs[dd] = v;
        lsum += v;
    }
    red[t] = lsum; __syncthreads();
    for (int s2 = 128; s2 > 0; s2 >>= 1) { if (t < s2) red[t] += red[t + s2]; __syncthreads(); }
    if (t == 0) smu = red[0] * (1.0f / D_MODEL);
    __syncthreads();
    float mu = smu;

    float lq = 0.0f;
    for (int dd = t; dd < D_MODEL; dd += 256) { float c = xs[dd] - mu; lq += c * c; }
    red[t] = lq; __syncthreads();
    for (int s2 = 128; s2 > 0; s2 >>= 1) { if (t < s2) red[t] += red[t + s2]; __syncthreads(); }
    if (t == 0) srstd = rsqrtf(red[0] * (1.0f / D_MODEL) + 1e-5f);
    __syncthreads();
    float rstd = srstd;

    long long ob = ((long long)b * 1024 + i) * 1024;
    for (int dd = t; dd < D_MODEL; dd += 256)
        Hb[ob + dd] = (__bf16)((xs[dd] - mu) * rstd);
}

// ================= LN2 =================
__global__ __launch_bounds__(256) void ln2_kernel(
    const float* __restrict__ F2, const __bf16* __restrict__ Hb, float* __restrict__ OUT)
{
    int i = blockIdx.x, b = blockIdx.y, t = threadIdx.x;
    __shared__ float xs[D_MODEL];
    __shared__ float red[256];
    __shared__ float smu, srstd;
    long long tb = ((long long)b * 1024 + i) * 1024;

    float lsum = 0.0f;
    for (int dd = t; dd < D_MODEL; dd += 256) {
        float v = F2[tb + dd] + (float)Hb[tb + dd];
        xs[dd] = v;
        lsum += v;
    }
    red[t] = lsum; __syncthreads();
    for (int s2 = 128; s2 > 0; s2 >>= 1) { if (t < s2) red[t] += red[t + s2]; __syncthreads(); }
    if (t == 0) smu = red[0] * (1.0f / D_MODEL);
    __syncthreads();
    float mu = smu;

    float lq = 0.0f;
    for (int dd = t; dd < D_MODEL; dd += 256) { float c = xs[dd] - mu; lq += c * c; }
    red[t] = lq; __syncthreads();
    for (int s2 = 128; s2 > 0; s2 >>= 1) { if (t < s2) red[t] += red[t + s2]; __syncthreads(); }
    if (t == 0) srstd = rsqrtf(red[0] * (1.0f / D_MODEL) + 1e-5f);
    __syncthreads();
    float rstd = srstd;

    long long base = (long long)b * D_MODEL * QLEN;
    for (int dd = t; dd < D_MODEL; dd += 256)
        OUT[base + (long long)dd * QLEN + i] = (xs[dd] - mu) * rstd;
}

// ================= launch =================
extern "C" void kernel_launch(void* const* d_in, const int* in_sizes, int n_in,
                              void* d_out, int out_size, void* d_ws, size_t ws_size,
                              hipStream_t stream) {
    const float* z    = (const float*)d_in[0];
    const float* zh   = (const float*)d_in[1];
    const float* u    = (const float*)d_in[2];
    const float* pos  = (const float*)d_in[3];
    const float* Wqkv = (const float*)d_in[4];
    const float* Wr   = (const float*)d_in[5];
    const float* rwb  = (const float*)d_in[6];
    const float* rrb  = (const float*)d_in[7];
    const float* Wo   = (const float*)d_in[8];
    const float* bo   = (const float*)d_in[9];
    const float* Wff1 = (const float*)d_in[10];
    const float* bff1 = (const float*)d_in[11];
    const float* Wff2 = (const float*)d_in[12];
    const float* bff2 = (const float*)d_in[13];
    float* out = (float*)d_out;
    float* ws  = (float*)d_ws;

    // ---- workspace (f32-slot offsets), total 27,361,280 slots = 109.4 MB ----
    __bf16* wh_bf = (__bf16*)ws;                         // (2,3072,2048) bf16 : 6,291,456 slots
    __bf16* rk_bf = (__bf16*)(ws + 6291456);             // (1024,1152) bf16   :   589,824
    __bf16* cat_t = (__bf16*)(ws + 6881280);             // (2,2048,1024) bf16 : 2,097,152
    __bf16* pos_t = (__bf16*)(ws + 8978432);             // (2112,1024) bf16   : 1,081,344
    __bf16* Wqkvb = (__bf16*)(ws + 10059776);            // 1,572,864
    __bf16* Wrb   = (__bf16*)(ws + 11632640);            //   524,288
    __bf16* Wob   = (__bf16*)(ws + 12156928);            //   524,288
    __bf16* Wff1b = (__bf16*)(ws + 12681216);            // 2,097,152
    __bf16* Wff2b = (__bf16*)(ws + 14778368);            // 2,097,152
    __bf16* av_t  = (__bf16*)(ws + 16875520);            // (2,1024,1024) bf16 : 1,048,576
    float*  ao    = ws + 17924096;                       // (2,1024,1024) f32  : 2,097,152
    __bf16* h_bf  = (__bf16*)(ws + 20021248);            // (2048,1024) bf16   : 1,048,576
    __bf16* f1b   = (__bf16*)(ws + 21069824);            // (2048,4096) bf16   : 4,194,304
    float*  f2    = ws + 25264128;                       // (2048,1024) f32    : 2,097,152

    // ---- converts & transposes ----
    conv_bf16<<<3072, 256, 0, stream>>>(Wqkv, Wqkvb, 3145728);
    conv_bf16<<<1024, 256, 0, stream>>>(Wr,   Wrb,   1048576);
    conv_bf16<<<1024, 256, 0, stream>>>(Wo,   Wob,   1048576);
    conv_bf16<<<4096, 256, 0, stream>>>(Wff1, Wff1b, 4194304);
    conv_bf16<<<4096, 256, 0, stream>>>(Wff2, Wff2b, 4194304);
    transp_bf16<<<dim3(32, 32, 2), 256, 0, stream>>>(zh, cat_t,           1024, 1024, 1048576LL, 2097152LL);
    transp_bf16<<<dim3(32, 32, 2), 256, 0, stream>>>(z,  cat_t + 1048576, 1024, 1024, 1048576LL, 2097152LL);
    transp_bf16<<<dim3(64, 32, 1), 256, 0, stream>>>(pos, pos_t, 1024, 2048, 0LL, 0LL);
    pad_pos<<<64, 256, 0, stream>>>(pos_t);

    // ---- wh = bf16(Wqkv @ cat + u) : M=3072 N=2048 K=1024, z=2 ----
    gemm_bf16_k<4><<<dim3(16, 24, 2), 256, 0, stream>>>(
        Wqkvb, cat_t, nullptr, wh_bf, u, nullptr,
        1024, 2048, 2048, 0, 2097152LL, 6291456LL, 6291456LL);
    // ---- rk compact = bf16(Wr @ pos[:, 960:2112]) : M=1024 N=1152 K=1024 ----
    gemm_bf16_k<2><<<dim3(9, 16, 1), 256, 0, stream>>>(
        Wrb, pos_t + 960 * 1024, nullptr, rk_bf, nullptr, nullptr,
        1024, 1152, 0, 0, 0LL, 0LL, 0LL);
    // ---- attention -> av_t (bf16, token-major) ----
    attn_mfma<<<512, 256, 0, stream>>>(wh_bf, rk_bf, rwb, rrb, av_t);
    // ---- ao = Wo @ av : M=1024 N=1024 K=1024, z=2 ----
    gemm_bf16_k<2><<<dim3(8, 16, 2), 256, 0, stream>>>(
        Wob, av_t, ao, nullptr, nullptr, nullptr,
        1024, 1024, 0, 0, 1048576LL, 1048576LL, 0LL);
    // ---- h = LN(ao + bo + z) ----
    ln1_kernel<<<dim3(1024, 2), 256, 0, stream>>>(ao, bo, z, h_bf);
    // ---- f1 = relu(h @ Wff1^T + bff1) : M=2048 N=4096 K=1024, out bf16 ----
    gemm_bf16_k<4><<<dim3(32, 16, 1), 256, 0, stream>>>(
        h_bf, Wff1b, nullptr, f1b, nullptr, bff1,
        1024, 4096, 0, 1, 0LL, 0LL, 0LL);
    // ---- f2 = f1 @ Wff2^T + bff2 : M=2048 N=1024 K=4096, out f32 ----
    gemm_bf16_k<2><<<dim3(8, 32, 1), 256, 0, stream>>>(
        f1b, Wff2b, f2, nullptr, nullptr, bff2,
        4096, 1024, 0, 0, 0LL, 0LL, 0LL);
    // ---- out = LN(f2 + h) transposed ----
    ln2_kernel<<<dim3(1024, 2), 256, 0, stream>>>(f2, h_bf, out);
}

// Round 5
// 350.113 us; speedup vs baseline: 1.2705x; 1.2705x over previous
//
#include <hip/hip_runtime.h>

#define D_MODEL 1024
#define QLEN 1024

typedef __bf16 bf16x8 __attribute__((ext_vector_type(8)));
typedef __bf16 bf16x4 __attribute__((ext_vector_type(4)));
typedef float f32x4 __attribute__((ext_vector_type(4)));

__device__ __forceinline__ void gload16(const void* g, void* l) {
    __builtin_amdgcn_global_load_lds(
        (const __attribute__((address_space(1))) void*)g,
        (__attribute__((address_space(3))) void*)l, 16, 0, 0);
}

// ============ bf16 MFMA GEMM: C[M,N] = A[M,K] @ Bt[N,K]^T (+U/Ub, +bias, relu) ============
// 4 waves 2x2. BM = MT*32, BN = 128, BK = 64. KS=1: blockIdx.y LSB selects K-half,
// halves write disjoint partial buffers (C + half*sSplit); U/bias applied on half 0 only.
template<int MT, int KS>
__global__ __launch_bounds__(256) void gemm_bf16_k(
    const __bf16* __restrict__ A, const __bf16* __restrict__ Bt,
    float* __restrict__ C, __bf16* __restrict__ Cb,
    const float* __restrict__ U, const __bf16* __restrict__ Ub,
    const float* __restrict__ bias,
    int K, int lda, int ldb, int ldC, int ldU, int relu,
    long long sA, long long sB, long long sC, long long sU, long long sSplit)
{
    __shared__ __bf16 As[MT * 32][64];
    __shared__ __bf16 Bs[128][64];

    const int bz = blockIdx.z;
    int yb = blockIdx.y;
    int half = 0;
    if (KS) { half = yb & 1; yb >>= 1; }
    A  += (long long)bz * sA + (long long)half * K;
    Bt += (long long)bz * sB + (long long)half * K;
    if (C)  C  += (long long)bz * sC + (long long)half * sSplit;
    if (Cb) Cb += (long long)bz * sC;
    if (U)  U  += (long long)bz * sU;
    if (Ub) Ub += (long long)bz * sU;
    if (KS && half) { bias = nullptr; U = nullptr; Ub = nullptr; }

    const int t = threadIdx.x;
    const int lane = t & 63, w = t >> 6;
    const int l15 = lane & 15, lg = lane >> 4;
    const int m0 = yb * (MT * 32);
    const int n0 = blockIdx.x * 128;
    const int wm = w >> 1, wn = w & 1;

    const int srow = lane >> 3;
    const int cpr  = lane & 7;

    f32x4 acc[MT][4] = {};

    for (int k0 = 0; k0 < K; k0 += 64) {
        #pragma unroll
        for (int i = 0; i < MT; ++i) {
            int r = i * 32 + w * 8 + srow;
            int c = cpr ^ (r & 7);
            gload16(&A[(long long)(m0 + r) * lda + k0 + c * 8], &As[i * 32 + w * 8][0]);
        }
        #pragma unroll
        for (int i = 0; i < 4; ++i) {
            int r = i * 32 + w * 8 + srow;
            int c = cpr ^ (r & 7);
            gload16(&Bt[(long long)(n0 + r) * ldb + k0 + c * 8], &Bs[i * 32 + w * 8][0]);
        }
        __syncthreads();
        #pragma unroll
        for (int kk = 0; kk < 2; ++kk) {
            bf16x8 bfr[4];
            #pragma unroll
            for (int nt = 0; nt < 4; ++nt) {
                int nr = wn * 64 + nt * 16 + l15;
                bfr[nt] = *(const bf16x8*)&Bs[nr][((kk * 4 + lg) ^ (nr & 7)) * 8];
            }
            #pragma unroll
            for (int mt = 0; mt < MT; ++mt) {
                int mr = wm * (MT * 16) + mt * 16 + l15;
                bf16x8 afr = *(const bf16x8*)&As[mr][((kk * 4 + lg) ^ (mr & 7)) * 8];
                #pragma unroll
                for (int nt = 0; nt < 4; ++nt)
                    acc[mt][nt] = __builtin_amdgcn_mfma_f32_16x16x32_bf16(afr, bfr[nt], acc[mt][nt], 0, 0, 0);
            }
        }
        __syncthreads();
    }

    #pragma unroll
    for (int mt = 0; mt < MT; ++mt) {
        #pragma unroll
        for (int nt = 0; nt < 4; ++nt) {
            #pragma unroll
            for (int rg = 0; rg < 4; ++rg) {
                int m = m0 + wm * (MT * 16) + mt * 16 + lg * 4 + rg;
                int n = n0 + wn * 64 + nt * 16 + l15;
                float v = acc[mt][nt][rg];
                if (U)    v += U[(long long)m * ldU + n];
                if (Ub)   v += (float)Ub[(long long)m * ldU + n];
                if (bias) v += bias[n];
                if (relu) v = fmaxf(v, 0.0f);
                if (Cb) Cb[(long long)m * ldC + n] = (__bf16)v;
                else    C [(long long)m * ldC + n] = v;
            }
        }
    }
}

// ============ fp32 -> bf16 elementwise convert ============
__global__ __launch_bounds__(256) void conv_bf16(
    const float* __restrict__ s, __bf16* __restrict__ d, int n)
{
    int i = (blockIdx.x * 256 + threadIdx.x) * 4;
    if (i < n) {
        float4 v = *(const float4*)&s[i];
        bf16x4 o = { (__bf16)v.x, (__bf16)v.y, (__bf16)v.z, (__bf16)v.w };
        *(bf16x4*)&d[i] = o;
    }
}

// ============ transpose-convert: S[R][Cc] fp32 -> D[Cc][R] bf16 ============
__global__ __launch_bounds__(256) void transp_bf16(
    const float* __restrict__ S, __bf16* __restrict__ D,
    int R, int Cc, long long sS, long long sD)
{
    S += (long long)blockIdx.z * sS;
    D += (long long)blockIdx.z * sD;
    __shared__ float ts[32][33];
    int r0 = blockIdx.y * 32, c0 = blockIdx.x * 32;
    int tr = threadIdx.x >> 5, tc = threadIdx.x & 31;
    #pragma unroll
    for (int p = 0; p < 4; ++p)
        ts[tr + p * 8][tc] = S[(long long)(r0 + tr + p * 8) * Cc + c0 + tc];
    __syncthreads();
    #pragma unroll
    for (int p = 0; p < 4; ++p)
        D[(long long)(c0 + tr + p * 8) * R + r0 + tc] = (__bf16)ts[tc][tr + p * 8];
}

// zero pos_t rows [2048, 2112)
__global__ __launch_bounds__(256) void pad_pos(__bf16* __restrict__ pt) {
    int i = (blockIdx.x * 256 + threadIdx.x) * 4;
    bf16x4 zv = { (__bf16)0.f, (__bf16)0.f, (__bf16)0.f, (__bf16)0.f };
    *(bf16x4*)&pt[2048 * 1024 + i] = zv;
}

// ================= MFMA flash attention (band j-i in [25,1024]) =================
// qkT [b][2048 tok][2048 feat] bf16 (Q = feat 0..1023, K = 1024..2047), token-major.
// whv [b][1024 feat][2048 tok] bf16 (V natural). rkT [1152 p][1024 feat] bf16.
// All LDS tiles: [row][64] chunk-XOR swizzle (chunk' = chunk ^ (row&7)), lane-linear b128 writes.
__global__ __launch_bounds__(256) void attn_mfma(
    const __bf16* __restrict__ QKT, const __bf16* __restrict__ WHV,
    const __bf16* __restrict__ RKT,
    const float* __restrict__ rwb, const float* __restrict__ rrb,
    __bf16* __restrict__ AVt)       // (B, Q, 1024) token-major bf16
{
    __shared__ __bf16 SM[29184];
    __bf16* PS = SM;            // [64][64] sw : Qw staging, then P
    __bf16* KT = SM + 4096;     // [64][64] sw : K^T tile
    __bf16* RT = SM + 8192;     // [128][64] sw : r_k^T tile (prologue: Qr staging)
    __bf16* VS = SM + 16384;    // [64][64] sw : V tile (rows=dh, cols=j)
    __bf16* BT = SM + 20480;    // [64][136]   : BD_raw Toeplitz tile

    const int d = blockIdx.x;
    const int xcd = d & 7, idx = d >> 3;
    const int qt = idx & 15;
    const int gq = xcd + 8 * (idx >> 4);
    const int b = gq >> 4, n = gq & 15;
    const int i0 = qt * 64;

    const int t = threadIdx.x;
    const int lane = t & 63, w = t >> 6;
    const int l15 = lane & 15, lg = lane >> 4;
    const int fco = n * 64;

    const __bf16* qkb = QKT + (long long)b * (2048 * 2048);
    const __bf16* vb  = WHV + (long long)b * (1024 * 2048) + (long long)fco * 2048;

    // ---- prologue: stage Qw -> PS, Qr -> RT (both [q][dh] swizzled)
    #pragma unroll
    for (int p = 0; p < 2; ++p) {
        int cid = p * 256 + t;
        int q = cid >> 3, s = cid & 7, c = s ^ (q & 7);
        bf16x8 qv = *(const bf16x8*)&qkb[(long long)(1024 + i0 + q) * 2048 + fco + c * 8];
        bf16x8 ow, orr;
        #pragma unroll
        for (int e = 0; e < 8; ++e) {
            float qf = (float)qv[e];
            ow[e]  = (__bf16)(qf + rwb[fco + c * 8 + e]);
            orr[e] = (__bf16)(qf + rrb[fco + c * 8 + e]);
        }
        *(bf16x8*)&PS[q * 64 + s * 8] = ow;
        *(bf16x8*)&RT[q * 64 + s * 8] = orr;
    }
    __syncthreads();

    #define LDF(buf, row, ch) (*(const bf16x8*)&(buf)[(row) * 64 + (((ch) ^ ((row) & 7)) * 8)])

    const int mrow = w * 16 + l15;
    bf16x8 qw0 = LDF(PS, mrow, lg), qw1 = LDF(PS, mrow, lg + 4);
    bf16x8 qr0 = LDF(RT, mrow, lg), qr1 = LDF(RT, mrow, lg + 4);

    f32x4 O0 = {}, O1 = {}, O2 = {}, O3 = {};
    float rm[4] = {-1e30f, -1e30f, -1e30f, -1e30f};
    float rl[4] = {0.f, 0.f, 0.f, 0.f};

    for (int kt = 0; kt <= 16; ++kt) {
        const int j0 = i0 + kt * 64;
        const int pbc = kt * 64;          // p = 960 + pbc + pi ; rkT row = pbc + pi
        __syncthreads();
        // ---- stage K^T (rows j), V (rows dh), r_k^T (rows p): lane-linear b128 writes
        #pragma unroll
        for (int p = 0; p < 2; ++p) {
            int cid = p * 256 + t;
            int r = cid >> 3, s = cid & 7, c = s ^ (r & 7);
            *(bf16x8*)&KT[r * 64 + s * 8] =
                *(const bf16x8*)&qkb[(long long)(j0 + r) * 2048 + 1024 + fco + c * 8];
            *(bf16x8*)&VS[r * 64 + s * 8] =
                *(const bf16x8*)&vb[(long long)r * 2048 + j0 + c * 8];
        }
        #pragma unroll
        for (int p = 0; p < 4; ++p) {
            int cid = p * 256 + t;
            int r = cid >> 3, s = cid & 7, c = s ^ (r & 7);
            *(bf16x8*)&RT[r * 64 + s * 8] =
                *(const bf16x8*)&RKT[(long long)(pbc + r) * 1024 + fco + c * 8];
        }
        __syncthreads();

        // ---- BD_raw[own 16 q rows][128 p] -> BT (wave-private rows)
        #pragma unroll
        for (int pt = 0; pt < 8; ++pt) {
            int pr = pt * 16 + l15;
            f32x4 c = {};
            c = __builtin_amdgcn_mfma_f32_16x16x32_bf16(qr0, LDF(RT, pr, lg), c, 0, 0, 0);
            c = __builtin_amdgcn_mfma_f32_16x16x32_bf16(qr1, LDF(RT, pr, lg + 4), c, 0, 0, 0);
            #pragma unroll
            for (int rg = 0; rg < 4; ++rg)
                BT[(w * 16 + lg * 4 + rg) * 136 + pt * 16 + l15] = (__bf16)c[rg];
        }

        // ---- AC + BD lookup + scale + band mask
        float sv[4][4];
        #pragma unroll
        for (int nt = 0; nt < 4; ++nt) {
            int jr = nt * 16 + l15;
            f32x4 c = {};
            c = __builtin_amdgcn_mfma_f32_16x16x32_bf16(qw0, LDF(KT, jr, lg), c, 0, 0, 0);
            c = __builtin_amdgcn_mfma_f32_16x16x32_bf16(qw1, LDF(KT, jr, lg + 4), c, 0, 0, 0);
            #pragma unroll
            for (int rg = 0; rg < 4; ++rg) {
                int ir = w * 16 + lg * 4 + rg;
                int dji = jr - ir;
                float s = (c[rg] + (float)BT[ir * 136 + dji + 63]) * 0.125f;
                bool valid = (kt == 0) ? (dji >= 25)
                           : (kt == 1) ? (dji >= -39)
                           : (kt == 16) ? (dji <= 0) : true;
                sv[nt][rg] = valid ? s : -1e30f;
            }
        }

        // ---- online softmax (rows live in 16-lane groups)
        float fac[4], nm[4];
        #pragma unroll
        for (int rg = 0; rg < 4; ++rg) {
            float mx = fmaxf(fmaxf(sv[0][rg], sv[1][rg]), fmaxf(sv[2][rg], sv[3][rg]));
            mx = fmaxf(mx, __shfl_xor(mx, 1, 16));
            mx = fmaxf(mx, __shfl_xor(mx, 2, 16));
            mx = fmaxf(mx, __shfl_xor(mx, 4, 16));
            mx = fmaxf(mx, __shfl_xor(mx, 8, 16));
            nm[rg] = fmaxf(rm[rg], mx);
            fac[rg] = __expf(rm[rg] - nm[rg]);
            rm[rg] = nm[rg];
        }
        float ls[4] = {0.f, 0.f, 0.f, 0.f};
        #pragma unroll
        for (int nt = 0; nt < 4; ++nt) {
            int jc = nt * 16 + l15;
            #pragma unroll
            for (int rg = 0; rg < 4; ++rg) {
                float p = (sv[nt][rg] > -1e29f) ? __expf(sv[nt][rg] - nm[rg]) : 0.0f;
                ls[rg] += p;
                int row = w * 16 + lg * 4 + rg;
                PS[row * 64 + (((jc >> 3) ^ (row & 7)) * 8) + (jc & 7)] = (__bf16)p;
            }
        }
        #pragma unroll
        for (int rg = 0; rg < 4; ++rg) {
            float s2 = ls[rg];
            s2 += __shfl_xor(s2, 1, 16);
            s2 += __shfl_xor(s2, 2, 16);
            s2 += __shfl_xor(s2, 4, 16);
            s2 += __shfl_xor(s2, 8, 16);
            rl[rg] = rl[rg] * fac[rg] + s2;
            O0[rg] *= fac[rg]; O1[rg] *= fac[rg]; O2[rg] *= fac[rg]; O3[rg] *= fac[rg];
        }

        // ---- PV: O[q][dh] += P[q][j] * V[dh][j]
        bf16x8 pa0 = LDF(PS, mrow, lg), pa1 = LDF(PS, mrow, lg + 4);
        O0 = __builtin_amdgcn_mfma_f32_16x16x32_bf16(pa0, LDF(VS,  0 + l15, lg),     O0, 0, 0, 0);
        O0 = __builtin_amdgcn_mfma_f32_16x16x32_bf16(pa1, LDF(VS,  0 + l15, lg + 4), O0, 0, 0, 0);
        O1 = __builtin_amdgcn_mfma_f32_16x16x32_bf16(pa0, LDF(VS, 16 + l15, lg),     O1, 0, 0, 0);
        O1 = __builtin_amdgcn_mfma_f32_16x16x32_bf16(pa1, LDF(VS, 16 + l15, lg + 4), O1, 0, 0, 0);
        O2 = __builtin_amdgcn_mfma_f32_16x16x32_bf16(pa0, LDF(VS, 32 + l15, lg),     O2, 0, 0, 0);
        O2 = __builtin_amdgcn_mfma_f32_16x16x32_bf16(pa1, LDF(VS, 32 + l15, lg + 4), O2, 0, 0, 0);
        O3 = __builtin_amdgcn_mfma_f32_16x16x32_bf16(pa0, LDF(VS, 48 + l15, lg),     O3, 0, 0, 0);
        O3 = __builtin_amdgcn_mfma_f32_16x16x32_bf16(pa1, LDF(VS, 48 + l15, lg + 4), O3, 0, 0, 0);
    }

    // ---- epilogue: AVt[b, q, feat]
    #pragma unroll
    for (int rg = 0; rg < 4; ++rg) {
        float inv = 1.0f / rl[rg];
        int q = i0 + w * 16 + lg * 4 + rg;
        long long base = ((long long)b * 1024 + q) * 1024 + fco;
        AVt[base +  0 + l15] = (__bf16)(O0[rg] * inv);
        AVt[base + 16 + l15] = (__bf16)(O1[rg] * inv);
        AVt[base + 32 + l15] = (__bf16)(O2[rg] * inv);
        AVt[base + 48 + l15] = (__bf16)(O3[rg] * inv);
    }
    #undef LDF
}

// ================= LN1: h = LN_d(ao_a + ao_b + b_o + z), token-major bf16 out ==========
__global__ __launch_bounds__(256) void ln1_kernel(
    const float* __restrict__ AO, const float* __restrict__ AO2,
    const float* __restrict__ bo, const float* __restrict__ Z,
    __bf16* __restrict__ Hb)
{
    int i = blockIdx.x, b = blockIdx.y, t = threadIdx.x;
    __shared__ float xs[D_MODEL];
    __shared__ float red[256];
    __shared__ float smu, srstd;
    long long base = (long long)b * D_MODEL * QLEN;

    float lsum = 0.0f;
    for (int dd = t; dd < D_MODEL; dd += 256) {
        long long o = base + (long long)dd * QLEN + i;
        float v = AO[o] + AO2[o] + bo[dd] + Z[o];
        xs[dd] = v;
        lsum += v;
    }
    red[t] = lsum; __syncthreads();
    for (int s2 = 128; s2 > 0; s2 >>= 1) { if (t < s2) red[t] += red[t + s2]; __syncthreads(); }
    if (t == 0) smu = red[0] * (1.0f / D_MODEL);
    __syncthreads();
    float mu = smu;

    float lq = 0.0f;
    for (int dd = t; dd < D_MODEL; dd += 256) { float c = xs[dd] - mu; lq += c * c; }
    red[t] = lq; __syncthreads();
    for (int s2 = 128; s2 > 0; s2 >>= 1) { if (t < s2) red[t] += red[t + s2]; __syncthreads(); }
    if (t == 0) srstd = rsqrtf(red[0] * (1.0f / D_MODEL) + 1e-5f);
    __syncthreads();
    float rstd = srstd;

    long long ob = ((long long)b * 1024 + i) * 1024;
    for (int dd = t; dd < D_MODEL; dd += 256)
        Hb[ob + dd] = (__bf16)((xs[dd] - mu) * rstd);
}

// ================= LN2: out[b,d,i] = LN_d(f2a + f2b + h), transposed write =================
__global__ __launch_bounds__(256) void ln2_kernel(
    const float* __restrict__ F2a, const float* __restrict__ F2b,
    const __bf16* __restrict__ Hb, float* __restrict__ OUT)
{
    int i = blockIdx.x, b = blockIdx.y, t = threadIdx.x;
    __shared__ float xs[D_MODEL];
    __shared__ float red[256];
    __shared__ float smu, srstd;
    long long tb = ((long long)b * 1024 + i) * 1024;

    float lsum = 0.0f;
    for (int dd = t; dd < D_MODEL; dd += 256) {
        float v = F2a[tb + dd] + F2b[tb + dd] + (float)Hb[tb + dd];
        xs[dd] = v;
        lsum += v;
    }
    red[t] = lsum; __syncthreads();
    for (int s2 = 128; s2 > 0; s2 >>= 1) { if (t < s2) red[t] += red[t + s2]; __syncthreads(); }
    if (t == 0) smu = red[0] * (1.0f / D_MODEL);
    __syncthreads();
    float mu = smu;

    float lq = 0.0f;
    for (int dd = t; dd < D_MODEL; dd += 256) { float c = xs[dd] - mu; lq += c * c; }
    red[t] = lq; __syncthreads();
    for (int s2 = 128; s2 > 0; s2 >>= 1) { if (t < s2) red[t] += red[t + s2]; __syncthreads(); }
    if (t == 0) srstd = rsqrtf(red[0] * (1.0f / D_MODEL) + 1e-5f);
    __syncthreads();
    float rstd = srstd;

    long long base = (long long)b * D_MODEL * QLEN;
    for (int dd = t; dd < D_MODEL; dd += 256)
        OUT[base + (long long)dd * QLEN + i] = (xs[dd] - mu) * rstd;
}

// ================= launch =================
extern "C" void kernel_launch(void* const* d_in, const int* in_sizes, int n_in,
                              void* d_out, int out_size, void* d_ws, size_t ws_size,
                              hipStream_t stream) {
    const float* z    = (const float*)d_in[0];
    const float* zh   = (const float*)d_in[1];
    const float* u    = (const float*)d_in[2];
    const float* pos  = (const float*)d_in[3];
    const float* Wqkv = (const float*)d_in[4];
    const float* Wr   = (const float*)d_in[5];
    const float* rwb  = (const float*)d_in[6];
    const float* rrb  = (const float*)d_in[7];
    const float* Wo   = (const float*)d_in[8];
    const float* bo   = (const float*)d_in[9];
    const float* Wff1 = (const float*)d_in[10];
    const float* bff1 = (const float*)d_in[11];
    const float* Wff2 = (const float*)d_in[12];
    const float* bff2 = (const float*)d_in[13];
    float* out = (float*)d_out;
    float* ws  = (float*)d_ws;

    // ---- workspace (f32-slot offsets), total 27,361,280 slots = 109.4 MB ----
    __bf16* cat_t = (__bf16*)ws;                         // [2][2048][1024]  : 2,097,152
    __bf16* pos_t = (__bf16*)(ws + 2097152);             // [2112][1024]     : 1,081,344
    __bf16* Wqkvb = (__bf16*)(ws + 3178496);             //                  : 1,572,864
    __bf16* Wrb   = (__bf16*)(ws + 4751360);             //                  :   524,288
    __bf16* Wob   = (__bf16*)(ws + 5275648);             //                  :   524,288
    __bf16* Wff1b = (__bf16*)(ws + 5799936);             //                  : 2,097,152
    __bf16* Wff2b = (__bf16*)(ws + 7897088);             //                  : 2,097,152
    __bf16* uqkT  = (__bf16*)(ws + 9994240);             // [2][2048][2048]  : 4,194,304
    __bf16* qkT   = (__bf16*)(ws + 14188544);            // [2][2048][2048]  : 4,194,304
    __bf16* wh_v  = (__bf16*)(ws + 18382848);            // [2][1024][2048]  : 2,097,152
    __bf16* rkT   = (__bf16*)(ws + 20480000);            // [1152][1024]     :   589,824
    __bf16* av_t  = (__bf16*)(ws + 21069824);            // [2][1024][1024]  : 1,048,576
    float*  ao    = ws + 22118400;                       // [2 halves][2][1M]: 4,194,304
    __bf16* h_bf  = (__bf16*)(ws + 26312704);            // [2048][1024]     : 1,048,576
    __bf16* f1b   = (__bf16*)(ws + 14188544);            // overlays qkT (dead after attn)
    float*  f2    = ws + 9994240;                        // overlays uqkT (dead after qkT GEMM)

    // ---- prep: converts & transposes ----
    conv_bf16<<<3072, 256, 0, stream>>>(Wqkv, Wqkvb, 3145728);
    conv_bf16<<<1024, 256, 0, stream>>>(Wr,   Wrb,   1048576);
    conv_bf16<<<1024, 256, 0, stream>>>(Wo,   Wob,   1048576);
    conv_bf16<<<4096, 256, 0, stream>>>(Wff1, Wff1b, 4194304);
    conv_bf16<<<4096, 256, 0, stream>>>(Wff2, Wff2b, 4194304);
    transp_bf16<<<dim3(32, 32, 2), 256, 0, stream>>>(zh, cat_t,           1024, 1024, 1048576LL, 2097152LL);
    transp_bf16<<<dim3(32, 32, 2), 256, 0, stream>>>(z,  cat_t + 1048576, 1024, 1024, 1048576LL, 2097152LL);
    transp_bf16<<<dim3(64, 32, 1), 256, 0, stream>>>(pos, pos_t, 1024, 2048, 0LL, 0LL);
    pad_pos<<<64, 256, 0, stream>>>(pos_t);
    // u QK-part transposed to token-major bf16: uqkT[b][tok][feat 0..2047]
    transp_bf16<<<dim3(64, 64, 2), 256, 0, stream>>>(u, uqkT, 2048, 2048, 6291456LL, 4194304LL);

    // ---- qkT = bf16(cat^T @ Wqkv[0:2048]^T + u^T) : M=2048 tok, N=2048 feat, K=1024 ----
    gemm_bf16_k<2, 0><<<dim3(16, 32, 2), 256, 0, stream>>>(
        cat_t, Wqkvb, nullptr, qkT, nullptr, uqkT, nullptr,
        1024, 1024, 1024, 2048, 2048, 0, 2097152LL, 0LL, 4194304LL, 4194304LL, 0LL);
    // ---- wh_v = bf16(Wqkv[2048:] @ cat + u_V) : M=1024 feat, N=2048 tok ----
    gemm_bf16_k<2, 0><<<dim3(16, 16, 2), 256, 0, stream>>>(
        Wqkvb + 2048 * 1024, cat_t, nullptr, wh_v, u + 4194304, nullptr, nullptr,
        1024, 1024, 1024, 2048, 2048, 0, 0LL, 2097152LL, 2097152LL, 6291456LL, 0LL);
    // ---- rkT = bf16(pos^T[960:2112] @ Wr^T) : M=1152 p, N=1024 feat ----
    gemm_bf16_k<2, 0><<<dim3(8, 18, 1), 256, 0, stream>>>(
        pos_t + 960 * 1024, Wrb, nullptr, rkT, nullptr, nullptr, nullptr,
        1024, 1024, 1024, 1024, 0, 0, 0LL, 0LL, 0LL, 0LL, 0LL);
    // ---- attention -> av_t ----
    attn_mfma<<<512, 256, 0, stream>>>(qkT, wh_v, rkT, rwb, rrb, av_t);
    // ---- ao partials = Wo @ av (K-split 2x512) ----
    gemm_bf16_k<2, 1><<<dim3(8, 32, 2), 256, 0, stream>>>(
        Wob, av_t, ao, nullptr, nullptr, nullptr, nullptr,
        512, 1024, 1024, 1024, 0, 0, 0LL, 1048576LL, 1048576LL, 0LL, 2097152LL);
    // ---- h = LN(ao_a + ao_b + bo + z) ----
    ln1_kernel<<<dim3(1024, 2), 256, 0, stream>>>(ao, ao + 2097152, bo, z, h_bf);
    // ---- f1 = relu(h @ Wff1^T + bff1) : M=2048, N=4096, K=1024 ----
    gemm_bf16_k<2, 0><<<dim3(32, 32, 1), 256, 0, stream>>>(
        h_bf, Wff1b, nullptr, f1b, nullptr, nullptr, bff1,
        1024, 1024, 1024, 4096, 0, 1, 0LL, 0LL, 0LL, 0LL, 0LL);
    // ---- f2 partials = f1 @ Wff2^T + bff2 (K-split 2x2048) ----
    gemm_bf16_k<2, 1><<<dim3(8, 64, 1), 256, 0, stream>>>(
        f1b, Wff2b, f2, nullptr, nullptr, nullptr, bff2,
        2048, 4096, 4096, 1024, 0, 0, 0LL, 0LL, 0LL, 0LL, 2097152LL);
    // ---- out = LN(f2a + f2b + h) transposed ----
    ln2_kernel<<<dim3(1024, 2), 256, 0, stream>>>(f2, f2 + 2097152, h_bf, out);
}

// Round 6
// 317.854 us; speedup vs baseline: 1.3995x; 1.1015x over previous
//
#include <hip/hip_runtime.h>

#define D_MODEL 1024
#define QLEN 1024

typedef __bf16 bf16x8 __attribute__((ext_vector_type(8)));
typedef __bf16 bf16x4 __attribute__((ext_vector_type(4)));
typedef float f32x4 __attribute__((ext_vector_type(4)));

__device__ __forceinline__ void gload16(const void* g, void* l) {
    __builtin_amdgcn_global_load_lds(
        (const __attribute__((address_space(1))) void*)g,
        (__attribute__((address_space(3))) void*)l, 16, 0, 0);
}

// ============ bf16 MFMA GEMM: C[M,N] = A[M,K] @ Bt[N,K]^T (+U/Ub, +bias, relu) ============
// 4 waves 2x2. BM = MT*32, BN = 128, BK = 64. KS=1: blockIdx.y LSB selects K-half,
// halves write disjoint partial buffers (C + half*sSplit); U/bias applied on half 0 only.
template<int MT, int KS>
__global__ __launch_bounds__(256) void gemm_bf16_k(
    const __bf16* __restrict__ A, const __bf16* __restrict__ Bt,
    float* __restrict__ C, __bf16* __restrict__ Cb,
    const float* __restrict__ U, const __bf16* __restrict__ Ub,
    const float* __restrict__ bias,
    int K, int lda, int ldb, int ldC, int ldU, int relu,
    long long sA, long long sB, long long sC, long long sU, long long sSplit)
{
    __shared__ __bf16 As[MT * 32][64];
    __shared__ __bf16 Bs[128][64];

    const int bz = blockIdx.z;
    int yb = blockIdx.y;
    int half = 0;
    if (KS) { half = yb & 1; yb >>= 1; }
    A  += (long long)bz * sA + (long long)half * K;
    Bt += (long long)bz * sB + (long long)half * K;
    if (C)  C  += (long long)bz * sC + (long long)half * sSplit;
    if (Cb) Cb += (long long)bz * sC;
    if (U)  U  += (long long)bz * sU;
    if (Ub) Ub += (long long)bz * sU;
    if (KS && half) { bias = nullptr; U = nullptr; Ub = nullptr; }

    const int t = threadIdx.x;
    const int lane = t & 63, w = t >> 6;
    const int l15 = lane & 15, lg = lane >> 4;
    const int m0 = yb * (MT * 32);
    const int n0 = blockIdx.x * 128;
    const int wm = w >> 1, wn = w & 1;

    const int srow = lane >> 3;
    const int cpr  = lane & 7;

    f32x4 acc[MT][4] = {};

    for (int k0 = 0; k0 < K; k0 += 64) {
        #pragma unroll
        for (int i = 0; i < MT; ++i) {
            int r = i * 32 + w * 8 + srow;
            int c = cpr ^ (r & 7);
            gload16(&A[(long long)(m0 + r) * lda + k0 + c * 8], &As[i * 32 + w * 8][0]);
        }
        #pragma unroll
        for (int i = 0; i < 4; ++i) {
            int r = i * 32 + w * 8 + srow;
            int c = cpr ^ (r & 7);
            gload16(&Bt[(long long)(n0 + r) * ldb + k0 + c * 8], &Bs[i * 32 + w * 8][0]);
        }
        __syncthreads();
        #pragma unroll
        for (int kk = 0; kk < 2; ++kk) {
            bf16x8 bfr[4];
            #pragma unroll
            for (int nt = 0; nt < 4; ++nt) {
                int nr = wn * 64 + nt * 16 + l15;
                bfr[nt] = *(const bf16x8*)&Bs[nr][((kk * 4 + lg) ^ (nr & 7)) * 8];
            }
            #pragma unroll
            for (int mt = 0; mt < MT; ++mt) {
                int mr = wm * (MT * 16) + mt * 16 + l15;
                bf16x8 afr = *(const bf16x8*)&As[mr][((kk * 4 + lg) ^ (mr & 7)) * 8];
                #pragma unroll
                for (int nt = 0; nt < 4; ++nt)
                    acc[mt][nt] = __builtin_amdgcn_mfma_f32_16x16x32_bf16(afr, bfr[nt], acc[mt][nt], 0, 0, 0);
            }
        }
        __syncthreads();
    }

    #pragma unroll
    for (int mt = 0; mt < MT; ++mt) {
        #pragma unroll
        for (int nt = 0; nt < 4; ++nt) {
            #pragma unroll
            for (int rg = 0; rg < 4; ++rg) {
                int m = m0 + wm * (MT * 16) + mt * 16 + lg * 4 + rg;
                int n = n0 + wn * 64 + nt * 16 + l15;
                float v = acc[mt][nt][rg];
                if (U)    v += U[(long long)m * ldU + n];
                if (Ub)   v += (float)Ub[(long long)m * ldU + n];
                if (bias) v += bias[n];
                if (relu) v = fmaxf(v, 0.0f);
                if (Cb) Cb[(long long)m * ldC + n] = (__bf16)v;
                else    C [(long long)m * ldC + n] = v;
            }
        }
    }
}

// ============ fused fp32 -> bf16 convert over 5 weight arrays ============
__global__ __launch_bounds__(256) void conv_multi(
    const float* __restrict__ s0, __bf16* __restrict__ d0, int n0,
    const float* __restrict__ s1, __bf16* __restrict__ d1, int n1,
    const float* __restrict__ s2, __bf16* __restrict__ d2, int n2,
    const float* __restrict__ s3, __bf16* __restrict__ d3, int n3,
    const float* __restrict__ s4, __bf16* __restrict__ d4, int n4)
{
    long long i = ((long long)blockIdx.x * 256 + threadIdx.x) * 4;
    const float* s; __bf16* dd;
    if (i < n0)              { s = s0 + i; dd = d0 + i; }
    else if ((i -= n0) < n1) { s = s1 + i; dd = d1 + i; }
    else if ((i -= n1) < n2) { s = s2 + i; dd = d2 + i; }
    else if ((i -= n2) < n3) { s = s3 + i; dd = d3 + i; }
    else if ((i -= n3) < n4) { s = s4 + i; dd = d4 + i; }
    else return;
    float4 v = *(const float4*)s;
    bf16x4 o = { (__bf16)v.x, (__bf16)v.y, (__bf16)v.z, (__bf16)v.w };
    *(bf16x4*)dd = o;
}

// ============ transpose-convert: S[R][Cc] fp32 -> D[Cc][R] bf16 ============
__global__ __launch_bounds__(256) void transp_bf16(
    const float* __restrict__ S, __bf16* __restrict__ D,
    int R, int Cc, long long sS, long long sD)
{
    S += (long long)blockIdx.z * sS;
    D += (long long)blockIdx.z * sD;
    __shared__ float ts[32][33];
    int r0 = blockIdx.y * 32, c0 = blockIdx.x * 32;
    int tr = threadIdx.x >> 5, tc = threadIdx.x & 31;
    #pragma unroll
    for (int p = 0; p < 4; ++p)
        ts[tr + p * 8][tc] = S[(long long)(r0 + tr + p * 8) * Cc + c0 + tc];
    __syncthreads();
    #pragma unroll
    for (int p = 0; p < 4; ++p)
        D[(long long)(c0 + tr + p * 8) * R + r0 + tc] = (__bf16)ts[tc][tr + p * 8];
}

// zero pos_t rows [2048, 2112)
__global__ __launch_bounds__(256) void pad_pos(__bf16* __restrict__ pt) {
    int i = (blockIdx.x * 256 + threadIdx.x) * 4;
    bf16x4 zv = { (__bf16)0.f, (__bf16)0.f, (__bf16)0.f, (__bf16)0.f };
    *(bf16x4*)&pt[2048 * 1024 + i] = zv;
}

// ================= MFMA flash attention (band j-i in [25,1024]) =================
// qkT [b][2048 tok][2048 feat] bf16 (Q = feat 0..1023, K = 1024..2047), token-major.
// whv [b][1024 feat][2048 tok] bf16 (V natural). rkT [1152 p][1024 feat] bf16.
// LDS tiles: [row][64] chunk-XOR swizzle, lane-linear b128 writes.
__global__ __launch_bounds__(256) void attn_mfma(
    const __bf16* __restrict__ QKT, const __bf16* __restrict__ WHV,
    const __bf16* __restrict__ RKT,
    const float* __restrict__ rwb, const float* __restrict__ rrb,
    __bf16* __restrict__ AVt)       // (B, Q, 1024) token-major bf16
{
    __shared__ __bf16 SM[29184];
    __bf16* PS = SM;            // [64][64] sw : Qw staging, then P
    __bf16* KT = SM + 4096;     // [64][64] sw : K^T tile
    __bf16* RT = SM + 8192;     // [128][64] sw : r_k^T tile (prologue: Qr staging)
    __bf16* VS = SM + 16384;    // [64][64] sw : V tile (rows=dh, cols=j)
    __bf16* BT = SM + 20480;    // [64][136]   : BD_raw Toeplitz tile

    const int d = blockIdx.x;
    const int xcd = d & 7, idx = d >> 3;
    const int qt = idx & 15;
    const int gq = xcd + 8 * (idx >> 4);
    const int b = gq >> 4, n = gq & 15;
    const int i0 = qt * 64;

    const int t = threadIdx.x;
    const int lane = t & 63, w = t >> 6;
    const int l15 = lane & 15, lg = lane >> 4;
    const int fco = n * 64;

    const __bf16* qkb = QKT + (long long)b * (2048 * 2048);
    const __bf16* vb  = WHV + (long long)b * (1024 * 2048) + (long long)fco * 2048;

    // ---- prologue: stage Qw -> PS, Qr -> RT (both [q][dh] swizzled)
    #pragma unroll
    for (int p = 0; p < 2; ++p) {
        int cid = p * 256 + t;
        int q = cid >> 3, s = cid & 7, c = s ^ (q & 7);
        bf16x8 qv = *(const bf16x8*)&qkb[(long long)(1024 + i0 + q) * 2048 + fco + c * 8];
        bf16x8 ow, orr;
        #pragma unroll
        for (int e = 0; e < 8; ++e) {
            float qf = (float)qv[e];
            ow[e]  = (__bf16)(qf + rwb[fco + c * 8 + e]);
            orr[e] = (__bf16)(qf + rrb[fco + c * 8 + e]);
        }
        *(bf16x8*)&PS[q * 64 + s * 8] = ow;
        *(bf16x8*)&RT[q * 64 + s * 8] = orr;
    }
    __syncthreads();

    #define LDF(buf, row, ch) (*(const bf16x8*)&(buf)[(row) * 64 + (((ch) ^ ((row) & 7)) * 8)])

    const int mrow = w * 16 + l15;
    bf16x8 qw0 = LDF(PS, mrow, lg), qw1 = LDF(PS, mrow, lg + 4);
    bf16x8 qr0 = LDF(RT, mrow, lg), qr1 = LDF(RT, mrow, lg + 4);

    f32x4 O0 = {}, O1 = {}, O2 = {}, O3 = {};
    float rm[4] = {-1e30f, -1e30f, -1e30f, -1e30f};
    float rl[4] = {0.f, 0.f, 0.f, 0.f};

    for (int kt = 0; kt <= 16; ++kt) {
        const int j0 = i0 + kt * 64;
        const int pbc = kt * 64;          // p = 960 + pbc + pi ; rkT row = pbc + pi
        __syncthreads();
        // ---- stage K^T (rows j), V (rows dh), r_k^T (rows p): lane-linear b128 writes
        #pragma unroll
        for (int p = 0; p < 2; ++p) {
            int cid = p * 256 + t;
            int r = cid >> 3, s = cid & 7, c = s ^ (r & 7);
            *(bf16x8*)&KT[r * 64 + s * 8] =
                *(const bf16x8*)&qkb[(long long)(j0 + r) * 2048 + 1024 + fco + c * 8];
            *(bf16x8*)&VS[r * 64 + s * 8] =
                *(const bf16x8*)&vb[(long long)r * 2048 + j0 + c * 8];
        }
        #pragma unroll
        for (int p = 0; p < 4; ++p) {
            int cid = p * 256 + t;
            int r = cid >> 3, s = cid & 7, c = s ^ (r & 7);
            *(bf16x8*)&RT[r * 64 + s * 8] =
                *(const bf16x8*)&RKT[(long long)(pbc + r) * 1024 + fco + c * 8];
        }
        __syncthreads();

        // ---- BD_raw: wave w only needs p_idx in [48-16w, 126-16w] -> 5 of 8 tiles
        __builtin_amdgcn_s_setprio(1);
        #pragma unroll
        for (int k5 = 0; k5 < 5; ++k5) {
            int pt = 3 - w + k5;
            int pr = pt * 16 + l15;
            f32x4 c = {};
            c = __builtin_amdgcn_mfma_f32_16x16x32_bf16(qr0, LDF(RT, pr, lg), c, 0, 0, 0);
            c = __builtin_amdgcn_mfma_f32_16x16x32_bf16(qr1, LDF(RT, pr, lg + 4), c, 0, 0, 0);
            #pragma unroll
            for (int rg = 0; rg < 4; ++rg)
                BT[(w * 16 + lg * 4 + rg) * 136 + pt * 16 + l15] = (__bf16)c[rg];
        }
        __builtin_amdgcn_s_setprio(0);

        // ---- AC + BD lookup + scale + band mask
        float sv[4][4];
        __builtin_amdgcn_s_setprio(1);
        #pragma unroll
        for (int nt = 0; nt < 4; ++nt) {
            int jr = nt * 16 + l15;
            f32x4 c = {};
            c = __builtin_amdgcn_mfma_f32_16x16x32_bf16(qw0, LDF(KT, jr, lg), c, 0, 0, 0);
            c = __builtin_amdgcn_mfma_f32_16x16x32_bf16(qw1, LDF(KT, jr, lg + 4), c, 0, 0, 0);
            #pragma unroll
            for (int rg = 0; rg < 4; ++rg) {
                int ir = w * 16 + lg * 4 + rg;
                int dji = jr - ir;
                float s = (c[rg] + (float)BT[ir * 136 + dji + 63]) * 0.125f;
                bool valid = (kt == 0) ? (dji >= 25)
                           : (kt == 1) ? (dji >= -39)
                           : (kt == 16) ? (dji <= 0) : true;
                sv[nt][rg] = valid ? s : -1e30f;
            }
        }
        __builtin_amdgcn_s_setprio(0);

        // ---- online softmax with defer-max (T13, THR=8)
        float mx[4];
        bool need = false;
        #pragma unroll
        for (int rg = 0; rg < 4; ++rg) {
            float m = fmaxf(fmaxf(sv[0][rg], sv[1][rg]), fmaxf(sv[2][rg], sv[3][rg]));
            m = fmaxf(m, __shfl_xor(m, 1, 16));
            m = fmaxf(m, __shfl_xor(m, 2, 16));
            m = fmaxf(m, __shfl_xor(m, 4, 16));
            m = fmaxf(m, __shfl_xor(m, 8, 16));
            mx[rg] = m;
            need = need || (m > rm[rg] + 8.0f);
        }
        if (__any(need)) {
            #pragma unroll
            for (int rg = 0; rg < 4; ++rg) {
                float nm = fmaxf(rm[rg], mx[rg]);
                float fac = __expf(rm[rg] - nm);
                rm[rg] = nm;
                rl[rg] *= fac;
                O0[rg] *= fac; O1[rg] *= fac; O2[rg] *= fac; O3[rg] *= fac;
            }
        }
        float ls[4] = {0.f, 0.f, 0.f, 0.f};
        #pragma unroll
        for (int nt = 0; nt < 4; ++nt) {
            int jc = nt * 16 + l15;
            #pragma unroll
            for (int rg = 0; rg < 4; ++rg) {
                float p = (sv[nt][rg] > -1e29f) ? __expf(sv[nt][rg] - rm[rg]) : 0.0f;
                ls[rg] += p;
                int row = w * 16 + lg * 4 + rg;
                PS[row * 64 + (((jc >> 3) ^ (row & 7)) * 8) + (jc & 7)] = (__bf16)p;
            }
        }
        #pragma unroll
        for (int rg = 0; rg < 4; ++rg) {
            float s2 = ls[rg];
            s2 += __shfl_xor(s2, 1, 16);
            s2 += __shfl_xor(s2, 2, 16);
            s2 += __shfl_xor(s2, 4, 16);
            s2 += __shfl_xor(s2, 8, 16);
            rl[rg] += s2;
        }

        // ---- PV: O[q][dh] += P[q][j] * V[dh][j]
        bf16x8 pa0 = LDF(PS, mrow, lg), pa1 = LDF(PS, mrow, lg + 4);
        __builtin_amdgcn_s_setprio(1);
        O0 = __builtin_amdgcn_mfma_f32_16x16x32_bf16(pa0, LDF(VS,  0 + l15, lg),     O0, 0, 0, 0);
        O0 = __builtin_amdgcn_mfma_f32_16x16x32_bf16(pa1, LDF(VS,  0 + l15, lg + 4), O0, 0, 0, 0);
        O1 = __builtin_amdgcn_mfma_f32_16x16x32_bf16(pa0, LDF(VS, 16 + l15, lg),     O1, 0, 0, 0);
        O1 = __builtin_amdgcn_mfma_f32_16x16x32_bf16(pa1, LDF(VS, 16 + l15, lg + 4), O1, 0, 0, 0);
        O2 = __builtin_amdgcn_mfma_f32_16x16x32_bf16(pa0, LDF(VS, 32 + l15, lg),     O2, 0, 0, 0);
        O2 = __builtin_amdgcn_mfma_f32_16x16x32_bf16(pa1, LDF(VS, 32 + l15, lg + 4), O2, 0, 0, 0);
        O3 = __builtin_amdgcn_mfma_f32_16x16x32_bf16(pa0, LDF(VS, 48 + l15, lg),     O3, 0, 0, 0);
        O3 = __builtin_amdgcn_mfma_f32_16x16x32_bf16(pa1, LDF(VS, 48 + l15, lg + 4), O3, 0, 0, 0);
        __builtin_amdgcn_s_setprio(0);
    }

    // ---- epilogue: AVt[b, q, feat]
    #pragma unroll
    for (int rg = 0; rg < 4; ++rg) {
        float inv = 1.0f / rl[rg];
        int q = i0 + w * 16 + lg * 4 + rg;
        long long base = ((long long)b * 1024 + q) * 1024 + fco;
        AVt[base +  0 + l15] = (__bf16)(O0[rg] * inv);
        AVt[base + 16 + l15] = (__bf16)(O1[rg] * inv);
        AVt[base + 32 + l15] = (__bf16)(O2[rg] * inv);
        AVt[base + 48 + l15] = (__bf16)(O3[rg] * inv);
    }
    #undef LDF
}

// ================= LN1: h = LN_d(ao_a + ao_b + b_o + z), token-major in/out ==========
__global__ __launch_bounds__(256) void ln1_kernel(
    const float* __restrict__ AO, const float* __restrict__ AO2,
    const float* __restrict__ bo, const float* __restrict__ Z,
    __bf16* __restrict__ Hb)
{
    int i = blockIdx.x, b = blockIdx.y, t = threadIdx.x;
    __shared__ float xs[D_MODEL];
    __shared__ float red[256];
    __shared__ float smu, srstd;
    long long zb = (long long)b * D_MODEL * QLEN;
    long long tb = ((long long)b * 1024 + i) * 1024;

    float lsum = 0.0f;
    for (int dd = t; dd < D_MODEL; dd += 256) {
        float v = AO[tb + dd] + AO2[tb + dd] + bo[dd] + Z[zb + (long long)dd * QLEN + i];
        xs[dd] = v;
        lsum += v;
    }
    red[t] = lsum; __syncthreads();
    for (int s2 = 128; s2 > 0; s2 >>= 1) { if (t < s2) red[t] += red[t + s2]; __syncthreads(); }
    if (t == 0) smu = red[0] * (1.0f / D_MODEL);
    __syncthreads();
    float mu = smu;

    float lq = 0.0f;
    for (int dd = t; dd < D_MODEL; dd += 256) { float c = xs[dd] - mu; lq += c * c; }
    red[t] = lq; __syncthreads();
    for (int s2 = 128; s2 > 0; s2 >>= 1) { if (t < s2) red[t] += red[t + s2]; __syncthreads(); }
    if (t == 0) srstd = rsqrtf(red[0] * (1.0f / D_MODEL) + 1e-5f);
    __syncthreads();
    float rstd = srstd;

    for (int dd = t; dd < D_MODEL; dd += 256)
        Hb[tb + dd] = (__bf16)((xs[dd] - mu) * rstd);
}

// ================= LN2: out[b,d,i] = LN_d(f2a + f2b + h), transposed write =================
__global__ __launch_bounds__(256) void ln2_kernel(
    const float* __restrict__ F2a, const float* __restrict__ F2b,
    const __bf16* __restrict__ Hb, float* __restrict__ OUT)
{
    int i = blockIdx.x, b = blockIdx.y, t = threadIdx.x;
    __shared__ float xs[D_MODEL];
    __shared__ float red[256];
    __shared__ float smu, srstd;
    long long tb = ((long long)b * 1024 + i) * 1024;

    float lsum = 0.0f;
    for (int dd = t; dd < D_MODEL; dd += 256) {
        float v = F2a[tb + dd] + F2b[tb + dd] + (float)Hb[tb + dd];
        xs[dd] = v;
        lsum += v;
    }
    red[t] = lsum; __syncthreads();
    for (int s2 = 128; s2 > 0; s2 >>= 1) { if (t < s2) red[t] += red[t + s2]; __syncthreads(); }
    if (t == 0) smu = red[0] * (1.0f / D_MODEL);
    __syncthreads();
    float mu = smu;

    float lq = 0.0f;
    for (int dd = t; dd < D_MODEL; dd += 256) { float c = xs[dd] - mu; lq += c * c; }
    red[t] = lq; __syncthreads();
    for (int s2 = 128; s2 > 0; s2 >>= 1) { if (t < s2) red[t] += red[t + s2]; __syncthreads(); }
    if (t == 0) srstd = rsqrtf(red[0] * (1.0f / D_MODEL) + 1e-5f);
    __syncthreads();
    float rstd = srstd;

    long long base = (long long)b * D_MODEL * QLEN;
    for (int dd = t; dd < D_MODEL; dd += 256)
        OUT[base + (long long)dd * QLEN + i] = (xs[dd] - mu) * rstd;
}

// ================= launch =================
extern "C" void kernel_launch(void* const* d_in, const int* in_sizes, int n_in,
                              void* d_out, int out_size, void* d_ws, size_t ws_size,
                              hipStream_t stream) {
    const float* z    = (const float*)d_in[0];
    const float* zh   = (const float*)d_in[1];
    const float* u    = (const float*)d_in[2];
    const float* pos  = (const float*)d_in[3];
    const float* Wqkv = (const float*)d_in[4];
    const float* Wr   = (const float*)d_in[5];
    const float* rwb  = (const float*)d_in[6];
    const float* rrb  = (const float*)d_in[7];
    const float* Wo   = (const float*)d_in[8];
    const float* bo   = (const float*)d_in[9];
    const float* Wff1 = (const float*)d_in[10];
    const float* bff1 = (const float*)d_in[11];
    const float* Wff2 = (const float*)d_in[12];
    const float* bff2 = (const float*)d_in[13];
    float* out = (float*)d_out;
    float* ws  = (float*)d_ws;

    // ---- workspace (f32-slot offsets), total 27,361,280 slots = 109.4 MB ----
    __bf16* cat_t = (__bf16*)ws;                         // [2][2048][1024]  : 2,097,152
    __bf16* pos_t = (__bf16*)(ws + 2097152);             // [2112][1024]     : 1,081,344
    __bf16* Wqkvb = (__bf16*)(ws + 3178496);             //                  : 1,572,864
    __bf16* Wrb   = (__bf16*)(ws + 4751360);             //                  :   524,288
    __bf16* Wob   = (__bf16*)(ws + 5275648);             //                  :   524,288
    __bf16* Wff1b = (__bf16*)(ws + 5799936);             //                  : 2,097,152
    __bf16* Wff2b = (__bf16*)(ws + 7897088);             //                  : 2,097,152
    __bf16* uqkT  = (__bf16*)(ws + 9994240);             // [2][2048][2048]  : 4,194,304
    __bf16* qkT   = (__bf16*)(ws + 14188544);            // [2][2048][2048]  : 4,194,304
    __bf16* wh_v  = (__bf16*)(ws + 18382848);            // [2][1024][2048]  : 2,097,152
    __bf16* rkT   = (__bf16*)(ws + 20480000);            // [1152][1024]     :   589,824
    __bf16* av_t  = (__bf16*)(ws + 21069824);            // [2][1024][1024]  : 1,048,576
    float*  ao    = ws + 22118400;                       // [2 halves][2048][1024]: 4,194,304
    __bf16* h_bf  = (__bf16*)(ws + 26312704);            // [2048][1024]     : 1,048,576
    __bf16* f1b   = (__bf16*)(ws + 14188544);            // overlays qkT (dead after attn)
    float*  f2    = ws + 9994240;                        // overlays uqkT (dead after qkT GEMM)

    // ---- prep ----
    conv_multi<<<13312, 256, 0, stream>>>(
        Wqkv, Wqkvb, 3145728, Wr, Wrb, 1048576, Wo, Wob, 1048576,
        Wff1, Wff1b, 4194304, Wff2, Wff2b, 4194304);
    transp_bf16<<<dim3(32, 32, 2), 256, 0, stream>>>(zh, cat_t,           1024, 1024, 1048576LL, 2097152LL);
    transp_bf16<<<dim3(32, 32, 2), 256, 0, stream>>>(z,  cat_t + 1048576, 1024, 1024, 1048576LL, 2097152LL);
    transp_bf16<<<dim3(64, 32, 1), 256, 0, stream>>>(pos, pos_t, 1024, 2048, 0LL, 0LL);
    pad_pos<<<64, 256, 0, stream>>>(pos_t);
    transp_bf16<<<dim3(64, 64, 2), 256, 0, stream>>>(u, uqkT, 2048, 2048, 6291456LL, 4194304LL);

    // ---- qkT = bf16(cat^T @ Wqkv[0:2048]^T + u^T) : M=2048 tok, N=2048 feat, K=1024 ----
    gemm_bf16_k<4, 0><<<dim3(16, 16, 2), 256, 0, stream>>>(
        cat_t, Wqkvb, nullptr, qkT, nullptr, uqkT, nullptr,
        1024, 1024, 1024, 2048, 2048, 0, 2097152LL, 0LL, 4194304LL, 4194304LL, 0LL);
    // ---- wh_v = bf16(Wqkv[2048:] @ cat + u_V) : M=1024 feat, N=2048 tok ----
    gemm_bf16_k<2, 0><<<dim3(16, 16, 2), 256, 0, stream>>>(
        Wqkvb + 2048 * 1024, cat_t, nullptr, wh_v, u + 4194304, nullptr, nullptr,
        1024, 1024, 1024, 2048, 2048, 0, 0LL, 2097152LL, 2097152LL, 6291456LL, 0LL);
    // ---- rkT = bf16(pos^T[960:2112] @ Wr^T) : M=1152 p, N=1024 feat ----
    gemm_bf16_k<2, 0><<<dim3(8, 18, 1), 256, 0, stream>>>(
        pos_t + 960 * 1024, Wrb, nullptr, rkT, nullptr, nullptr, nullptr,
        1024, 1024, 1024, 1024, 0, 0, 0LL, 0LL, 0LL, 0LL, 0LL);
    // ---- attention -> av_t ----
    attn_mfma<<<512, 256, 0, stream>>>(qkT, wh_v, rkT, rwb, rrb, av_t);
    // ---- ao_t partials = av_t @ Wo^T (token-major, K-split 2x512) ----
    gemm_bf16_k<2, 1><<<dim3(8, 64, 1), 256, 0, stream>>>(
        av_t, Wob, ao, nullptr, nullptr, nullptr, nullptr,
        512, 1024, 1024, 1024, 0, 0, 0LL, 0LL, 0LL, 0LL, 2097152LL);
    // ---- h = LN(ao_a + ao_b + bo + z) ----
    ln1_kernel<<<dim3(1024, 2), 256, 0, stream>>>(ao, ao + 2097152, bo, z, h_bf);
    // ---- f1 = relu(h @ Wff1^T + bff1) : M=2048, N=4096, K=1024 ----
    gemm_bf16_k<4, 0><<<dim3(32, 16, 1), 256, 0, stream>>>(
        h_bf, Wff1b, nullptr, f1b, nullptr, nullptr, bff1,
        1024, 1024, 1024, 4096, 0, 1, 0LL, 0LL, 0LL, 0LL, 0LL);
    // ---- f2 partials = f1 @ Wff2^T + bff2 (K-split 2x2048) ----
    gemm_bf16_k<2, 1><<<dim3(8, 64, 1), 256, 0, stream>>>(
        f1b, Wff2b, f2, nullptr, nullptr, nullptr, bff2,
        2048, 4096, 4096, 1024, 0, 0, 0LL, 0LL, 0LL, 0LL, 2097152LL);
    // ---- out = LN(f2a + f2b + h) transposed ----
    ln2_kernel<<<dim3(1024, 2), 256, 0, stream>>>(f2, f2 + 2097152, h_bf, out);
}

// Round 7
// 295.239 us; speedup vs baseline: 1.5067x; 1.0766x over previous
//
#include <hip/hip_runtime.h>

#define D_MODEL 1024
#define QLEN 1024

typedef __bf16 bf16x8 __attribute__((ext_vector_type(8)));
typedef __bf16 bf16x4 __attribute__((ext_vector_type(4)));
typedef float f32x4 __attribute__((ext_vector_type(4)));

__device__ __forceinline__ void gload16(const void* g, void* l) {
    __builtin_amdgcn_global_load_lds(
        (const __attribute__((address_space(1))) void*)g,
        (__attribute__((address_space(3))) void*)l, 16, 0, 0);
}

// ============ bf16 MFMA GEMM: C[M,N] = A[M,K] @ Bt[N,K]^T (+U/Ub, +bias, relu) ============
template<int MT, int KS>
__global__ __launch_bounds__(256) void gemm_bf16_k(
    const __bf16* __restrict__ A, const __bf16* __restrict__ Bt,
    float* __restrict__ C, __bf16* __restrict__ Cb,
    const float* __restrict__ U, const __bf16* __restrict__ Ub,
    const float* __restrict__ bias,
    int K, int lda, int ldb, int ldC, int ldU, int relu,
    long long sA, long long sB, long long sC, long long sU, long long sSplit)
{
    __shared__ __bf16 As[MT * 32][64];
    __shared__ __bf16 Bs[128][64];

    const int bz = blockIdx.z;
    int yb = blockIdx.y;
    int half = 0;
    if (KS) { half = yb & 1; yb >>= 1; }
    A  += (long long)bz * sA + (long long)half * K;
    Bt += (long long)bz * sB + (long long)half * K;
    if (C)  C  += (long long)bz * sC + (long long)half * sSplit;
    if (Cb) Cb += (long long)bz * sC;
    if (U)  U  += (long long)bz * sU;
    if (Ub) Ub += (long long)bz * sU;
    if (KS && half) { bias = nullptr; U = nullptr; Ub = nullptr; }

    const int t = threadIdx.x;
    const int lane = t & 63, w = t >> 6;
    const int l15 = lane & 15, lg = lane >> 4;
    const int m0 = yb * (MT * 32);
    const int n0 = blockIdx.x * 128;
    const int wm = w >> 1, wn = w & 1;

    const int srow = lane >> 3;
    const int cpr  = lane & 7;

    f32x4 acc[MT][4] = {};

    for (int k0 = 0; k0 < K; k0 += 64) {
        #pragma unroll
        for (int i = 0; i < MT; ++i) {
            int r = i * 32 + w * 8 + srow;
            int c = cpr ^ (r & 7);
            gload16(&A[(long long)(m0 + r) * lda + k0 + c * 8], &As[i * 32 + w * 8][0]);
        }
        #pragma unroll
        for (int i = 0; i < 4; ++i) {
            int r = i * 32 + w * 8 + srow;
            int c = cpr ^ (r & 7);
            gload16(&Bt[(long long)(n0 + r) * ldb + k0 + c * 8], &Bs[i * 32 + w * 8][0]);
        }
        __syncthreads();
        #pragma unroll
        for (int kk = 0; kk < 2; ++kk) {
            bf16x8 bfr[4];
            #pragma unroll
            for (int nt = 0; nt < 4; ++nt) {
                int nr = wn * 64 + nt * 16 + l15;
                bfr[nt] = *(const bf16x8*)&Bs[nr][((kk * 4 + lg) ^ (nr & 7)) * 8];
            }
            #pragma unroll
            for (int mt = 0; mt < MT; ++mt) {
                int mr = wm * (MT * 16) + mt * 16 + l15;
                bf16x8 afr = *(const bf16x8*)&As[mr][((kk * 4 + lg) ^ (mr & 7)) * 8];
                #pragma unroll
                for (int nt = 0; nt < 4; ++nt)
                    acc[mt][nt] = __builtin_amdgcn_mfma_f32_16x16x32_bf16(afr, bfr[nt], acc[mt][nt], 0, 0, 0);
            }
        }
        __syncthreads();
    }

    #pragma unroll
    for (int mt = 0; mt < MT; ++mt) {
        #pragma unroll
        for (int nt = 0; nt < 4; ++nt) {
            #pragma unroll
            for (int rg = 0; rg < 4; ++rg) {
                int m = m0 + wm * (MT * 16) + mt * 16 + lg * 4 + rg;
                int n = n0 + wn * 64 + nt * 16 + l15;
                float v = acc[mt][nt][rg];
                if (U)    v += U[(long long)m * ldU + n];
                if (Ub)   v += (float)Ub[(long long)m * ldU + n];
                if (bias) v += bias[n];
                if (relu) v = fmaxf(v, 0.0f);
                if (Cb) Cb[(long long)m * ldC + n] = (__bf16)v;
                else    C [(long long)m * ldC + n] = v;
            }
        }
    }
}

// ============ fused fp32 -> bf16 convert over 5 weight arrays ============
__global__ __launch_bounds__(256) void conv_multi(
    const float* __restrict__ s0, __bf16* __restrict__ d0, int n0,
    const float* __restrict__ s1, __bf16* __restrict__ d1, int n1,
    const float* __restrict__ s2, __bf16* __restrict__ d2, int n2,
    const float* __restrict__ s3, __bf16* __restrict__ d3, int n3,
    const float* __restrict__ s4, __bf16* __restrict__ d4, int n4)
{
    long long i = ((long long)blockIdx.x * 256 + threadIdx.x) * 4;
    const float* s; __bf16* dd;
    if (i < n0)              { s = s0 + i; dd = d0 + i; }
    else if ((i -= n0) < n1) { s = s1 + i; dd = d1 + i; }
    else if ((i -= n1) < n2) { s = s2 + i; dd = d2 + i; }
    else if ((i -= n2) < n3) { s = s3 + i; dd = d3 + i; }
    else if ((i -= n3) < n4) { s = s4 + i; dd = d4 + i; }
    else return;
    float4 v = *(const float4*)s;
    bf16x4 o = { (__bf16)v.x, (__bf16)v.y, (__bf16)v.z, (__bf16)v.w };
    *(bf16x4*)dd = o;
}

// ============ transpose-convert: S[R][Cc] fp32 -> D[Cc][R] bf16 ============
__global__ __launch_bounds__(256) void transp_bf16(
    const float* __restrict__ S, __bf16* __restrict__ D,
    int R, int Cc, long long sS, long long sD)
{
    S += (long long)blockIdx.z * sS;
    D += (long long)blockIdx.z * sD;
    __shared__ float ts[32][33];
    int r0 = blockIdx.y * 32, c0 = blockIdx.x * 32;
    int tr = threadIdx.x >> 5, tc = threadIdx.x & 31;
    #pragma unroll
    for (int p = 0; p < 4; ++p)
        ts[tr + p * 8][tc] = S[(long long)(r0 + tr + p * 8) * Cc + c0 + tc];
    __syncthreads();
    #pragma unroll
    for (int p = 0; p < 4; ++p)
        D[(long long)(c0 + tr + p * 8) * R + r0 + tc] = (__bf16)ts[tc][tr + p * 8];
}

// zero pos_t rows [2048, 2112)
__global__ __launch_bounds__(256) void pad_pos(__bf16* __restrict__ pt) {
    int i = (blockIdx.x * 256 + threadIdx.x) * 4;
    bf16x4 zv = { (__bf16)0.f, (__bf16)0.f, (__bf16)0.f, (__bf16)0.f };
    *(bf16x4*)&pt[2048 * 1024 + i] = zv;
}

// ================= MFMA flash attention, software-pipelined =================
// qkT [b][2048 tok][2048 feat]; whv [b][1024 feat][2048 tok]; rkT [1152 p][1024 feat].
// KT/VS double-buffered, RT 128-row ring (64 new rows/iter), direct global_load_lds,
// raw barriers with counted drains (one vmcnt(0) per iter).
__global__ __launch_bounds__(256) void attn_mfma(
    const __bf16* __restrict__ QKT, const __bf16* __restrict__ WHV,
    const __bf16* __restrict__ RKT,
    const float* __restrict__ rwb, const float* __restrict__ rrb,
    __bf16* __restrict__ AVt)
{
    __shared__ __bf16 SM[37376];
    __bf16* KT0 = SM;             // [64][64] sw
    __bf16* KT1 = SM + 4096;
    __bf16* VS0 = SM + 8192;      // [64][64] sw (prologue: Qr temp)
    __bf16* VS1 = SM + 12288;
    __bf16* RT  = SM + 16384;     // [128][64] sw ring
    __bf16* PS  = SM + 24576;     // [64][64] sw (prologue: Qw temp; then P)
    __bf16* BT  = SM + 28672;     // [64][136]

    const int d = blockIdx.x;
    const int xcd = d & 7, idx = d >> 3;
    const int qt = idx & 15;
    const int gq = xcd + 8 * (idx >> 4);
    const int b = gq >> 4, n = gq & 15;
    const int i0 = qt * 64;

    const int t = threadIdx.x;
    const int lane = t & 63, w = t >> 6;
    const int l15 = lane & 15, lg = lane >> 4;
    const int fco = n * 64;

    const __bf16* qkb = QKT + (long long)b * (2048 * 2048);
    const __bf16* vb  = WHV + (long long)b * (1024 * 2048) + (long long)fco * 2048;

    // ---- prologue: Qw -> PS, Qr -> VS0 (swizzled [q][dh])
    #pragma unroll
    for (int pp = 0; pp < 2; ++pp) {
        int cid = pp * 256 + t;
        int q = cid >> 3, s = cid & 7, c = s ^ (q & 7);
        bf16x8 qv = *(const bf16x8*)&qkb[(long long)(1024 + i0 + q) * 2048 + fco + c * 8];
        bf16x8 ow, orr;
        #pragma unroll
        for (int e = 0; e < 8; ++e) {
            float qf = (float)qv[e];
            ow[e]  = (__bf16)(qf + rwb[fco + c * 8 + e]);
            orr[e] = (__bf16)(qf + rrb[fco + c * 8 + e]);
        }
        *(bf16x8*)&PS[q * 64 + s * 8] = ow;
        *(bf16x8*)&VS0[q * 64 + s * 8] = orr;
    }
    __syncthreads();

    #define LDF(buf, row, ch) (*(const bf16x8*)&(buf)[(row) * 64 + ((((ch) ^ ((row) & 7))) * 8)])

    const int mrow = w * 16 + l15;
    bf16x8 qw0 = LDF(PS, mrow, lg), qw1 = LDF(PS, mrow, lg + 4);
    bf16x8 qr0 = LDF(VS0, mrow, lg), qr1 = LDF(VS0, mrow, lg + 4);
    asm volatile("s_waitcnt lgkmcnt(0)" ::: "memory");
    __builtin_amdgcn_sched_barrier(0);
    __builtin_amdgcn_s_barrier();        // all waves' Q-frag reads done

    // ---- prologue gloads: KT0/VS0 (kt=0), RT rows 0..127
    #pragma unroll
    for (int pp = 0; pp < 2; ++pp) {
        int cid = pp * 256 + t;
        int r = cid >> 3, s = cid & 7, c = s ^ (r & 7);
        gload16(&qkb[(long long)(i0 + r) * 2048 + 1024 + fco + c * 8], &KT0[(pp * 32 + w * 8) * 64]);
        gload16(&vb[(long long)r * 2048 + i0 + c * 8], &VS0[(pp * 32 + w * 8) * 64]);
    }
    #pragma unroll
    for (int pp = 0; pp < 4; ++pp) {
        int cid = pp * 256 + t;
        int r = cid >> 3, s = cid & 7, c = s ^ (r & 7);
        gload16(&RKT[(long long)r * 1024 + fco + c * 8], &RT[(pp * 32 + w * 8) * 64]);
    }
    asm volatile("s_waitcnt vmcnt(0)" ::: "memory");
    __builtin_amdgcn_sched_barrier(0);
    __builtin_amdgcn_s_barrier();

    f32x4 O0 = {}, O1 = {}, O2 = {}, O3 = {};
    float rm[4] = {-1e30f, -1e30f, -1e30f, -1e30f};
    float rl[4] = {0.f, 0.f, 0.f, 0.f};
    int cur = 0;

    for (int kt = 0; kt <= 16; ++kt) {
        __bf16* KTc = cur ? KT1 : KT0;
        __bf16* VSc = cur ? VS1 : VS0;
        __bf16* KTn = cur ? KT0 : KT1;
        __bf16* VSn = cur ? VS0 : VS1;

        // (1) issue KT/VS prefetch for kt+1 (lands before end-of-iter drain)
        if (kt < 16) {
            int j0n = i0 + (kt + 1) * 64;
            #pragma unroll
            for (int pp = 0; pp < 2; ++pp) {
                int cid = pp * 256 + t;
                int r = cid >> 3, s = cid & 7, c = s ^ (r & 7);
                gload16(&qkb[(long long)(j0n + r) * 2048 + 1024 + fco + c * 8], &KTn[(pp * 32 + w * 8) * 64]);
                gload16(&vb[(long long)r * 2048 + j0n + c * 8], &VSn[(pp * 32 + w * 8) * 64]);
            }
        }
        __builtin_amdgcn_sched_barrier(0);

        // (2) BD phase from RT ring (rows (64kt+pr)&127), writes own BT rows
        const int rbase = (kt * 64) & 127;
        __builtin_amdgcn_s_setprio(1);
        #pragma unroll
        for (int k5 = 0; k5 < 5; ++k5) {
            int pt = 3 - w + k5;
            int pr = pt * 16 + l15;
            int lr = (rbase + pr) & 127;
            f32x4 cc = {};
            cc = __builtin_amdgcn_mfma_f32_16x16x32_bf16(qr0, LDF(RT, lr, lg), cc, 0, 0, 0);
            cc = __builtin_amdgcn_mfma_f32_16x16x32_bf16(qr1, LDF(RT, lr, lg + 4), cc, 0, 0, 0);
            #pragma unroll
            for (int rg = 0; rg < 4; ++rg)
                BT[(w * 16 + lg * 4 + rg) * 136 + pt * 16 + l15] = (__bf16)cc[rg];
        }
        __builtin_amdgcn_s_setprio(0);
        asm volatile("s_waitcnt lgkmcnt(0)" ::: "memory");
        __builtin_amdgcn_sched_barrier(0);
        __builtin_amdgcn_s_barrier();     // mid: all BD RT-reads complete

        // (3) issue RT ring prefetch: absolute rows 64kt+128..+191
        if (kt < 16) {
            int rb = kt * 64 + 128;
            int lb = rb & 127;
            #pragma unroll
            for (int pp = 0; pp < 2; ++pp) {
                int cid = pp * 256 + t;
                int r = cid >> 3, s = cid & 7, c = s ^ (r & 7);
                gload16(&RKT[(long long)(rb + r) * 1024 + fco + c * 8], &RT[(lb + pp * 32 + w * 8) * 64]);
            }
        }
        __builtin_amdgcn_sched_barrier(0);

        // (4) AC + BD lookup + scale + band mask
        float sv[4][4];
        __builtin_amdgcn_s_setprio(1);
        #pragma unroll
        for (int nt = 0; nt < 4; ++nt) {
            int jr = nt * 16 + l15;
            f32x4 cc = {};
            cc = __builtin_amdgcn_mfma_f32_16x16x32_bf16(qw0, LDF(KTc, jr, lg), cc, 0, 0, 0);
            cc = __builtin_amdgcn_mfma_f32_16x16x32_bf16(qw1, LDF(KTc, jr, lg + 4), cc, 0, 0, 0);
            #pragma unroll
            for (int rg = 0; rg < 4; ++rg) {
                int ir = w * 16 + lg * 4 + rg;
                int dji = jr - ir;
                float s = (cc[rg] + (float)BT[ir * 136 + dji + 63]) * 0.125f;
                bool valid = (kt == 0) ? (dji >= 25)
                           : (kt == 1) ? (dji >= -39)
                           : (kt == 16) ? (dji <= 0) : true;
                sv[nt][rg] = valid ? s : -1e30f;
            }
        }
        __builtin_amdgcn_s_setprio(0);

        // (5) online softmax with defer-max (THR=8)
        float mx[4];
        bool need = false;
        #pragma unroll
        for (int rg = 0; rg < 4; ++rg) {
            float m = fmaxf(fmaxf(sv[0][rg], sv[1][rg]), fmaxf(sv[2][rg], sv[3][rg]));
            m = fmaxf(m, __shfl_xor(m, 1, 16));
            m = fmaxf(m, __shfl_xor(m, 2, 16));
            m = fmaxf(m, __shfl_xor(m, 4, 16));
            m = fmaxf(m, __shfl_xor(m, 8, 16));
            mx[rg] = m;
            need = need || (m > rm[rg] + 8.0f);
        }
        if (__any(need)) {
            #pragma unroll
            for (int rg = 0; rg < 4; ++rg) {
                float nm = fmaxf(rm[rg], mx[rg]);
                float fac = __expf(rm[rg] - nm);
                rm[rg] = nm;
                rl[rg] *= fac;
                O0[rg] *= fac; O1[rg] *= fac; O2[rg] *= fac; O3[rg] *= fac;
            }
        }
        float ls[4] = {0.f, 0.f, 0.f, 0.f};
        #pragma unroll
        for (int nt = 0; nt < 4; ++nt) {
            int jc = nt * 16 + l15;
            #pragma unroll
            for (int rg = 0; rg < 4; ++rg) {
                float p = (sv[nt][rg] > -1e29f) ? __expf(sv[nt][rg] - rm[rg]) : 0.0f;
                ls[rg] += p;
                int row = w * 16 + lg * 4 + rg;
                PS[row * 64 + (((jc >> 3) ^ (row & 7)) * 8) + (jc & 7)] = (__bf16)p;
            }
        }
        #pragma unroll
        for (int rg = 0; rg < 4; ++rg) {
            float s2 = ls[rg];
            s2 += __shfl_xor(s2, 1, 16);
            s2 += __shfl_xor(s2, 2, 16);
            s2 += __shfl_xor(s2, 4, 16);
            s2 += __shfl_xor(s2, 8, 16);
            rl[rg] += s2;
        }

        // (6) PV: O[q][dh] += P[q][j] * V[dh][j]
        bf16x8 pa0 = LDF(PS, mrow, lg), pa1 = LDF(PS, mrow, lg + 4);
        __builtin_amdgcn_s_setprio(1);
        O0 = __builtin_amdgcn_mfma_f32_16x16x32_bf16(pa0, LDF(VSc,  0 + l15, lg),     O0, 0, 0, 0);
        O0 = __builtin_amdgcn_mfma_f32_16x16x32_bf16(pa1, LDF(VSc,  0 + l15, lg + 4), O0, 0, 0, 0);
        O1 = __builtin_amdgcn_mfma_f32_16x16x32_bf16(pa0, LDF(VSc, 16 + l15, lg),     O1, 0, 0, 0);
        O1 = __builtin_amdgcn_mfma_f32_16x16x32_bf16(pa1, LDF(VSc, 16 + l15, lg + 4), O1, 0, 0, 0);
        O2 = __builtin_amdgcn_mfma_f32_16x16x32_bf16(pa0, LDF(VSc, 32 + l15, lg),     O2, 0, 0, 0);
        O2 = __builtin_amdgcn_mfma_f32_16x16x32_bf16(pa1, LDF(VSc, 32 + l15, lg + 4), O2, 0, 0, 0);
        O3 = __builtin_amdgcn_mfma_f32_16x16x32_bf16(pa0, LDF(VSc, 48 + l15, lg),     O3, 0, 0, 0);
        O3 = __builtin_amdgcn_mfma_f32_16x16x32_bf16(pa1, LDF(VSc, 48 + l15, lg + 4), O3, 0, 0, 0);
        __builtin_amdgcn_s_setprio(0);

        // (7) end: drain prefetches + sync
        asm volatile("s_waitcnt vmcnt(0)" ::: "memory");
        __builtin_amdgcn_sched_barrier(0);
        __builtin_amdgcn_s_barrier();
        cur ^= 1;
    }

    // ---- epilogue
    #pragma unroll
    for (int rg = 0; rg < 4; ++rg) {
        float inv = 1.0f / rl[rg];
        int q = i0 + w * 16 + lg * 4 + rg;
        long long base = ((long long)b * 1024 + q) * 1024 + fco;
        AVt[base +  0 + l15] = (__bf16)(O0[rg] * inv);
        AVt[base + 16 + l15] = (__bf16)(O1[rg] * inv);
        AVt[base + 32 + l15] = (__bf16)(O2[rg] * inv);
        AVt[base + 48 + l15] = (__bf16)(O3[rg] * inv);
    }
    #undef LDF
}

// ================= LN1: h = LN_d(ao_a + ao_b + b_o + z), z read from cat_t (bf16) ====
__global__ __launch_bounds__(256) void ln1_kernel(
    const float* __restrict__ AO, const float* __restrict__ AO2,
    const float* __restrict__ bo, const __bf16* __restrict__ CatT,
    __bf16* __restrict__ Hb)
{
    int i = blockIdx.x, b = blockIdx.y, t = threadIdx.x;
    __shared__ float xs[D_MODEL];
    __shared__ float red[256];
    __shared__ float smu, srstd;
    long long tb = ((long long)b * 1024 + i) * 1024;
    long long zb = ((long long)b * 2048 + 1024 + i) * 1024;

    float lsum = 0.0f;
    for (int dd = t; dd < D_MODEL; dd += 256) {
        float v = AO[tb + dd] + AO2[tb + dd] + bo[dd] + (float)CatT[zb + dd];
        xs[dd] = v;
        lsum += v;
    }
    red[t] = lsum; __syncthreads();
    for (int s2 = 128; s2 > 0; s2 >>= 1) { if (t < s2) red[t] += red[t + s2]; __syncthreads(); }
    if (t == 0) smu = red[0] * (1.0f / D_MODEL);
    __syncthreads();
    float mu = smu;

    float lq = 0.0f;
    for (int dd = t; dd < D_MODEL; dd += 256) { float c = xs[dd] - mu; lq += c * c; }
    red[t] = lq; __syncthreads();
    for (int s2 = 128; s2 > 0; s2 >>= 1) { if (t < s2) red[t] += red[t + s2]; __syncthreads(); }
    if (t == 0) srstd = rsqrtf(red[0] * (1.0f / D_MODEL) + 1e-5f);
    __syncthreads();
    float rstd = srstd;

    for (int dd = t; dd < D_MODEL; dd += 256)
        Hb[tb + dd] = (__bf16)((xs[dd] - mu) * rstd);
}

// ================= LN2 pass 1: per-token mu / rstd =================
__global__ __launch_bounds__(256) void ln2_stats(
    const float* __restrict__ F2a, const float* __restrict__ F2b,
    const __bf16* __restrict__ Hb, float2* __restrict__ st)
{
    int i = blockIdx.x, b = blockIdx.y, t = threadIdx.x;
    __shared__ float rs[256], rq[256];
    long long tb = ((long long)b * 1024 + i) * 1024;

    float s = 0.f, q = 0.f;
    for (int dd = t; dd < D_MODEL; dd += 256) {
        float v = F2a[tb + dd] + F2b[tb + dd] + (float)Hb[tb + dd];
        s += v; q += v * v;
    }
    rs[t] = s; rq[t] = q; __syncthreads();
    for (int s2 = 128; s2 > 0; s2 >>= 1) {
        if (t < s2) { rs[t] += rs[t + s2]; rq[t] += rq[t + s2]; }
        __syncthreads();
    }
    if (t == 0) {
        float mu = rs[0] * (1.0f / D_MODEL);
        float var = rq[0] * (1.0f / D_MODEL) - mu * mu;
        st[(long long)b * 1024 + i] = make_float2(mu, rsqrtf(var + 1e-5f));
    }
}

// ================= LN2 pass 2: normalized transpose-write (coalesced) =================
__global__ __launch_bounds__(256) void ln2_write(
    const float* __restrict__ F2a, const float* __restrict__ F2b,
    const __bf16* __restrict__ Hb, const float2* __restrict__ st,
    float* __restrict__ OUT)
{
    __shared__ float ts[32][33];
    int f0 = blockIdx.x * 32, i0 = blockIdx.y * 32, b = blockIdx.z;
    int tr = threadIdx.x >> 5, tc = threadIdx.x & 31;
    #pragma unroll
    for (int p = 0; p < 4; ++p) {
        int tok = i0 + tr + p * 8;
        long long tb = ((long long)b * 1024 + tok) * 1024;
        float2 s = st[(long long)b * 1024 + tok];
        float v = F2a[tb + f0 + tc] + F2b[tb + f0 + tc] + (float)Hb[tb + f0 + tc];
        ts[tr + p * 8][tc] = (v - s.x) * s.y;
    }
    __syncthreads();
    #pragma unroll
    for (int p = 0; p < 4; ++p)
        OUT[((long long)b * 1024 + f0 + tr + p * 8) * 1024 + i0 + tc] = ts[tc][tr + p * 8];
}

// ================= launch =================
extern "C" void kernel_launch(void* const* d_in, const int* in_sizes, int n_in,
                              void* d_out, int out_size, void* d_ws, size_t ws_size,
                              hipStream_t stream) {
    const float* z    = (const float*)d_in[0];
    const float* zh   = (const float*)d_in[1];
    const float* u    = (const float*)d_in[2];
    const float* pos  = (const float*)d_in[3];
    const float* Wqkv = (const float*)d_in[4];
    const float* Wr   = (const float*)d_in[5];
    const float* rwb  = (const float*)d_in[6];
    const float* rrb  = (const float*)d_in[7];
    const float* Wo   = (const float*)d_in[8];
    const float* bo   = (const float*)d_in[9];
    const float* Wff1 = (const float*)d_in[10];
    const float* bff1 = (const float*)d_in[11];
    const float* Wff2 = (const float*)d_in[12];
    const float* bff2 = (const float*)d_in[13];
    float* out = (float*)d_out;
    float* ws  = (float*)d_ws;

    // ---- workspace (f32-slot offsets) ----
    __bf16* cat_t = (__bf16*)ws;                         // [2][2048][1024]
    __bf16* pos_t = (__bf16*)(ws + 2097152);             // [2112][1024]
    __bf16* Wqkvb = (__bf16*)(ws + 3178496);
    __bf16* Wrb   = (__bf16*)(ws + 4751360);
    __bf16* Wob   = (__bf16*)(ws + 5275648);
    __bf16* Wff1b = (__bf16*)(ws + 5799936);
    __bf16* Wff2b = (__bf16*)(ws + 7897088);
    __bf16* uqkT  = (__bf16*)(ws + 9994240);             // [2][2048][2048]
    __bf16* qkT   = (__bf16*)(ws + 14188544);            // [2][2048][2048]
    __bf16* wh_v  = (__bf16*)(ws + 18382848);            // [2][1024][2048]
    __bf16* rkT   = (__bf16*)(ws + 20480000);            // [1152][1024]
    __bf16* av_t  = (__bf16*)(ws + 21069824);            // [2][1024][1024]
    float*  ao    = ws + 22118400;                       // [2 halves][2048][1024]
    __bf16* h_bf  = (__bf16*)(ws + 26312704);            // [2048][1024]
    float2* st2   = (float2*)(ws + 27361280);            // [2][1024] float2
    __bf16* f1b   = (__bf16*)(ws + 14188544);            // overlays qkT (dead after attn)
    float*  f2    = ws + 9994240;                        // overlays uqkT (dead after qkT GEMM)

    // ---- prep ----
    conv_multi<<<13312, 256, 0, stream>>>(
        Wqkv, Wqkvb, 3145728, Wr, Wrb, 1048576, Wo, Wob, 1048576,
        Wff1, Wff1b, 4194304, Wff2, Wff2b, 4194304);
    transp_bf16<<<dim3(32, 32, 2), 256, 0, stream>>>(zh, cat_t,           1024, 1024, 1048576LL, 2097152LL);
    transp_bf16<<<dim3(32, 32, 2), 256, 0, stream>>>(z,  cat_t + 1048576, 1024, 1024, 1048576LL, 2097152LL);
    transp_bf16<<<dim3(64, 32, 1), 256, 0, stream>>>(pos, pos_t, 1024, 2048, 0LL, 0LL);
    pad_pos<<<64, 256, 0, stream>>>(pos_t);
    transp_bf16<<<dim3(64, 64, 2), 256, 0, stream>>>(u, uqkT, 2048, 2048, 6291456LL, 4194304LL);

    // ---- qkT = bf16(cat^T @ Wqkv[0:2048]^T + u^T) ----
    gemm_bf16_k<4, 0><<<dim3(16, 16, 2), 256, 0, stream>>>(
        cat_t, Wqkvb, nullptr, qkT, nullptr, uqkT, nullptr,
        1024, 1024, 1024, 2048, 2048, 0, 2097152LL, 0LL, 4194304LL, 4194304LL, 0LL);
    // ---- wh_v = bf16(Wqkv[2048:] @ cat + u_V) ----
    gemm_bf16_k<2, 0><<<dim3(16, 16, 2), 256, 0, stream>>>(
        Wqkvb + 2048 * 1024, cat_t, nullptr, wh_v, u + 4194304, nullptr, nullptr,
        1024, 1024, 1024, 2048, 2048, 0, 0LL, 2097152LL, 2097152LL, 6291456LL, 0LL);
    // ---- rkT = bf16(pos^T[960:2112] @ Wr^T) ----
    gemm_bf16_k<2, 0><<<dim3(8, 18, 1), 256, 0, stream>>>(
        pos_t + 960 * 1024, Wrb, nullptr, rkT, nullptr, nullptr, nullptr,
        1024, 1024, 1024, 1024, 0, 0, 0LL, 0LL, 0LL, 0LL, 0LL);
    // ---- attention -> av_t ----
    attn_mfma<<<512, 256, 0, stream>>>(qkT, wh_v, rkT, rwb, rrb, av_t);
    // ---- ao_t partials = av_t @ Wo^T (K-split 2x512) ----
    gemm_bf16_k<2, 1><<<dim3(8, 64, 1), 256, 0, stream>>>(
        av_t, Wob, ao, nullptr, nullptr, nullptr, nullptr,
        512, 1024, 1024, 1024, 0, 0, 0LL, 0LL, 0LL, 0LL, 2097152LL);
    // ---- h = LN(ao_a + ao_b + bo + z) ----
    ln1_kernel<<<dim3(1024, 2), 256, 0, stream>>>(ao, ao + 2097152, bo, cat_t, h_bf);
    // ---- f1 = relu(h @ Wff1^T + bff1) ----
    gemm_bf16_k<4, 0><<<dim3(32, 16, 1), 256, 0, stream>>>(
        h_bf, Wff1b, nullptr, f1b, nullptr, nullptr, bff1,
        1024, 1024, 1024, 4096, 0, 1, 0LL, 0LL, 0LL, 0LL, 0LL);
    // ---- f2 partials = f1 @ Wff2^T + bff2 (K-split 2x2048) ----
    gemm_bf16_k<2, 1><<<dim3(8, 64, 1), 256, 0, stream>>>(
        f1b, Wff2b, f2, nullptr, nullptr, nullptr, bff2,
        2048, 4096, 4096, 1024, 0, 0, 0LL, 0LL, 0LL, 0LL, 2097152LL);
    // ---- out = LN(f2a + f2b + h), two-pass transposed ----
    ln2_stats<<<dim3(1024, 2), 256, 0, stream>>>(f2, f2 + 2097152, h_bf, st2);
    ln2_write<<<dim3(32, 32, 2), 256, 0, stream>>>(f2, f2 + 2097152, h_bf, st2, out);
}

// Round 8
// 283.685 us; speedup vs baseline: 1.5680x; 1.0407x over previous
//
#include <hip/hip_runtime.h>

#define D_MODEL 1024
#define QLEN 1024

typedef __bf16 bf16x8 __attribute__((ext_vector_type(8)));
typedef __bf16 bf16x4 __attribute__((ext_vector_type(4)));
typedef float f32x4 __attribute__((ext_vector_type(4)));

__device__ __forceinline__ void gload16(const void* g, void* l) {
    __builtin_amdgcn_global_load_lds(
        (const __attribute__((address_space(1))) void*)g,
        (__attribute__((address_space(3))) void*)l, 16, 0, 0);
}

// ============ bf16 MFMA GEMM: C[M,N] = A[M,K] @ Bt[N,K]^T (+U/Ub, +bias, relu) ============
template<int MT, int KS>
__global__ __launch_bounds__(256) void gemm_bf16_k(
    const __bf16* __restrict__ A, const __bf16* __restrict__ Bt,
    float* __restrict__ C, __bf16* __restrict__ Cb,
    const float* __restrict__ U, const __bf16* __restrict__ Ub,
    const float* __restrict__ bias,
    int K, int lda, int ldb, int ldC, int ldU, int relu,
    long long sA, long long sB, long long sC, long long sU, long long sSplit)
{
    __shared__ __bf16 As[MT * 32][64];
    __shared__ __bf16 Bs[128][64];

    const int bz = blockIdx.z;
    int yb = blockIdx.y;
    int half = 0;
    if (KS) { half = yb & 1; yb >>= 1; }
    A  += (long long)bz * sA + (long long)half * K;
    Bt += (long long)bz * sB + (long long)half * K;
    if (C)  C  += (long long)bz * sC + (long long)half * sSplit;
    if (Cb) Cb += (long long)bz * sC;
    if (U)  U  += (long long)bz * sU;
    if (Ub) Ub += (long long)bz * sU;
    if (KS && half) { bias = nullptr; U = nullptr; Ub = nullptr; }

    const int t = threadIdx.x;
    const int lane = t & 63, w = t >> 6;
    const int l15 = lane & 15, lg = lane >> 4;
    const int m0 = yb * (MT * 32);
    const int n0 = blockIdx.x * 128;
    const int wm = w >> 1, wn = w & 1;

    const int srow = lane >> 3;
    const int cpr  = lane & 7;

    f32x4 acc[MT][4] = {};

    for (int k0 = 0; k0 < K; k0 += 64) {
        #pragma unroll
        for (int i = 0; i < MT; ++i) {
            int r = i * 32 + w * 8 + srow;
            int c = cpr ^ (r & 7);
            gload16(&A[(long long)(m0 + r) * lda + k0 + c * 8], &As[i * 32 + w * 8][0]);
        }
        #pragma unroll
        for (int i = 0; i < 4; ++i) {
            int r = i * 32 + w * 8 + srow;
            int c = cpr ^ (r & 7);
            gload16(&Bt[(long long)(n0 + r) * ldb + k0 + c * 8], &Bs[i * 32 + w * 8][0]);
        }
        __syncthreads();
        #pragma unroll
        for (int kk = 0; kk < 2; ++kk) {
            bf16x8 bfr[4];
            #pragma unroll
            for (int nt = 0; nt < 4; ++nt) {
                int nr = wn * 64 + nt * 16 + l15;
                bfr[nt] = *(const bf16x8*)&Bs[nr][((kk * 4 + lg) ^ (nr & 7)) * 8];
            }
            #pragma unroll
            for (int mt = 0; mt < MT; ++mt) {
                int mr = wm * (MT * 16) + mt * 16 + l15;
                bf16x8 afr = *(const bf16x8*)&As[mr][((kk * 4 + lg) ^ (mr & 7)) * 8];
                #pragma unroll
                for (int nt = 0; nt < 4; ++nt)
                    acc[mt][nt] = __builtin_amdgcn_mfma_f32_16x16x32_bf16(afr, bfr[nt], acc[mt][nt], 0, 0, 0);
            }
        }
        __syncthreads();
    }

    #pragma unroll
    for (int mt = 0; mt < MT; ++mt) {
        #pragma unroll
        for (int nt = 0; nt < 4; ++nt) {
            #pragma unroll
            for (int rg = 0; rg < 4; ++rg) {
                int m = m0 + wm * (MT * 16) + mt * 16 + lg * 4 + rg;
                int n = n0 + wn * 64 + nt * 16 + l15;
                float v = acc[mt][nt][rg];
                if (U)    v += U[(long long)m * ldU + n];
                if (Ub)   v += (float)Ub[(long long)m * ldU + n];
                if (bias) v += bias[n];
                if (relu) v = fmaxf(v, 0.0f);
                if (Cb) Cb[(long long)m * ldC + n] = (__bf16)v;
                else    C [(long long)m * ldC + n] = v;
            }
        }
    }
}

// ============ fused fp32 -> bf16 convert over 5 weight arrays ============
__global__ __launch_bounds__(256) void conv_multi(
    const float* __restrict__ s0, __bf16* __restrict__ d0, int n0,
    const float* __restrict__ s1, __bf16* __restrict__ d1, int n1,
    const float* __restrict__ s2, __bf16* __restrict__ d2, int n2,
    const float* __restrict__ s3, __bf16* __restrict__ d3, int n3,
    const float* __restrict__ s4, __bf16* __restrict__ d4, int n4)
{
    long long i = ((long long)blockIdx.x * 256 + threadIdx.x) * 4;
    const float* s; __bf16* dd;
    if (i < n0)              { s = s0 + i; dd = d0 + i; }
    else if ((i -= n0) < n1) { s = s1 + i; dd = d1 + i; }
    else if ((i -= n1) < n2) { s = s2 + i; dd = d2 + i; }
    else if ((i -= n2) < n3) { s = s3 + i; dd = d3 + i; }
    else if ((i -= n3) < n4) { s = s4 + i; dd = d4 + i; }
    else return;
    float4 v = *(const float4*)s;
    bf16x4 o = { (__bf16)v.x, (__bf16)v.y, (__bf16)v.z, (__bf16)v.w };
    *(bf16x4*)dd = o;
}

// ============ transpose-convert: S[R][Cc] fp32 -> D[Cc][R] bf16 ============
__global__ __launch_bounds__(256) void transp_bf16(
    const float* __restrict__ S, __bf16* __restrict__ D,
    int R, int Cc, long long sS, long long sD)
{
    S += (long long)blockIdx.z * sS;
    D += (long long)blockIdx.z * sD;
    __shared__ float ts[32][33];
    int r0 = blockIdx.y * 32, c0 = blockIdx.x * 32;
    int tr = threadIdx.x >> 5, tc = threadIdx.x & 31;
    #pragma unroll
    for (int p = 0; p < 4; ++p)
        ts[tr + p * 8][tc] = S[(long long)(r0 + tr + p * 8) * Cc + c0 + tc];
    __syncthreads();
    #pragma unroll
    for (int p = 0; p < 4; ++p)
        D[(long long)(c0 + tr + p * 8) * R + r0 + tc] = (__bf16)ts[tc][tr + p * 8];
}

// zero pos_t rows [2048, 2112)
__global__ __launch_bounds__(256) void pad_pos(__bf16* __restrict__ pt) {
    int i = (blockIdx.x * 256 + threadIdx.x) * 4;
    bf16x4 zv = { (__bf16)0.f, (__bf16)0.f, (__bf16)0.f, (__bf16)0.f };
    *(bf16x4*)&pt[2048 * 1024 + i] = zv;
}

// ================= MFMA flash attention, 1-barrier pipelined =================
// RT ring = 192 rows: iter kt reads ring rows [64kt,64kt+127]%192 while prefetch
// writes [64kt+128,+191]%192 (disjoint) -> RT prefetch issues at top of iter.
// BT per-wave [16][80]; row-sum via all-ones MFMA; defer-max from lane-local max.
__global__ __launch_bounds__(256) void attn_mfma(
    const __bf16* __restrict__ QKT, const __bf16* __restrict__ WHV,
    const __bf16* __restrict__ RKT,
    const float* __restrict__ rwb, const float* __restrict__ rrb,
    __bf16* __restrict__ AVt)
{
    __shared__ __bf16 SM[37888];
    __bf16* KT0 = SM;              // [64][64] sw
    __bf16* KT1 = SM + 4096;
    __bf16* VS0 = SM + 8192;       // [64][64] sw (prologue: Qr temp)
    __bf16* VS1 = SM + 12288;
    __bf16* RT  = SM + 16384;      // [192][64] sw ring
    __bf16* PS  = SM + 28672;      // [64][64] sw (prologue: Qw temp; then P)
    __bf16* BT  = SM + 32768;      // per-wave [16][80], w*1280 offset

    const int d = blockIdx.x;
    const int xcd = d & 7, idx = d >> 3;
    const int qt = idx & 15;
    const int gq = xcd + 8 * (idx >> 4);
    const int b = gq >> 4, n = gq & 15;
    const int i0 = qt * 64;

    const int t = threadIdx.x;
    const int lane = t & 63, w = t >> 6;
    const int l15 = lane & 15, lg = lane >> 4;
    const int fco = n * 64;

    const __bf16* qkb = QKT + (long long)b * (2048 * 2048);
    const __bf16* vb  = WHV + (long long)b * (1024 * 2048) + (long long)fco * 2048;
    __bf16* BTw = BT + w * 1280;

    // ---- prologue: Qw -> PS, Qr -> VS0 (swizzled [q][dh])
    #pragma unroll
    for (int pp = 0; pp < 2; ++pp) {
        int cid = pp * 256 + t;
        int q = cid >> 3, s = cid & 7, c = s ^ (q & 7);
        bf16x8 qv = *(const bf16x8*)&qkb[(long long)(1024 + i0 + q) * 2048 + fco + c * 8];
        bf16x8 ow, orr;
        #pragma unroll
        for (int e = 0; e < 8; ++e) {
            float qf = (float)qv[e];
            ow[e]  = (__bf16)(qf + rwb[fco + c * 8 + e]);
            orr[e] = (__bf16)(qf + rrb[fco + c * 8 + e]);
        }
        *(bf16x8*)&PS[q * 64 + s * 8] = ow;
        *(bf16x8*)&VS0[q * 64 + s * 8] = orr;
    }
    __syncthreads();

    #define LDF(buf, row, ch) (*(const bf16x8*)&(buf)[(row) * 64 + ((((ch) ^ ((row) & 7))) * 8)])

    const int mrow = w * 16 + l15;
    bf16x8 qw0 = LDF(PS, mrow, lg), qw1 = LDF(PS, mrow, lg + 4);
    bf16x8 qr0 = LDF(VS0, mrow, lg), qr1 = LDF(VS0, mrow, lg + 4);
    asm volatile("s_waitcnt lgkmcnt(0)" ::: "memory");
    __builtin_amdgcn_sched_barrier(0);
    __builtin_amdgcn_s_barrier();        // all waves' Q-frag reads done

    // ---- prologue gloads: KT0/VS0 (kt=0), RT ring rows 0..191
    #pragma unroll
    for (int pp = 0; pp < 2; ++pp) {
        int cid = pp * 256 + t;
        int r = cid >> 3, s = cid & 7, c = s ^ (r & 7);
        gload16(&qkb[(long long)(i0 + r) * 2048 + 1024 + fco + c * 8], &KT0[(pp * 32 + w * 8) * 64]);
        gload16(&vb[(long long)r * 2048 + i0 + c * 8], &VS0[(pp * 32 + w * 8) * 64]);
    }
    #pragma unroll
    for (int pp = 0; pp < 6; ++pp) {
        int cid = pp * 256 + t;
        int r = cid >> 3, s = cid & 7, c = s ^ (r & 7);
        gload16(&RKT[(long long)r * 1024 + fco + c * 8], &RT[(pp * 32 + w * 8) * 64]);
    }
    asm volatile("s_waitcnt vmcnt(0)" ::: "memory");
    __builtin_amdgcn_sched_barrier(0);
    __builtin_amdgcn_s_barrier();

    const bf16x8 ones = { (__bf16)1.f, (__bf16)1.f, (__bf16)1.f, (__bf16)1.f,
                          (__bf16)1.f, (__bf16)1.f, (__bf16)1.f, (__bf16)1.f };

    f32x4 O0 = {}, O1 = {}, O2 = {}, O3 = {};
    float rm[4] = {-1e30f, -1e30f, -1e30f, -1e30f};
    float rl[4] = {0.f, 0.f, 0.f, 0.f};
    int cur = 0;

    for (int kt = 0; kt <= 16; ++kt) {
        __bf16* KTc = cur ? KT1 : KT0;
        __bf16* VSc = cur ? VS1 : VS0;
        __bf16* KTn = cur ? KT0 : KT1;
        __bf16* VSn = cur ? VS0 : VS1;
        const int rbase = (kt % 3) * 64;          // ring base for this iter's p-window

        // (1) issue ALL prefetches for kt+1: KT/VS (dbuf) + RT ring rows 64kt+128..+191
        if (kt < 16) {
            int j0n = i0 + (kt + 1) * 64;
            #pragma unroll
            for (int pp = 0; pp < 2; ++pp) {
                int cid = pp * 256 + t;
                int r = cid >> 3, s = cid & 7, c = s ^ (r & 7);
                gload16(&qkb[(long long)(j0n + r) * 2048 + 1024 + fco + c * 8], &KTn[(pp * 32 + w * 8) * 64]);
                gload16(&vb[(long long)r * 2048 + j0n + c * 8], &VSn[(pp * 32 + w * 8) * 64]);
            }
            int rb = kt * 64 + 128;               // absolute rkT row
            int lb = ((kt + 2) % 3) * 64;         // ring slot (contiguous 64 rows)
            #pragma unroll
            for (int pp = 0; pp < 2; ++pp) {
                int cid = pp * 256 + t;
                int r = cid >> 3, s = cid & 7, c = s ^ (r & 7);
                gload16(&RKT[(long long)(rb + r) * 1024 + fco + c * 8], &RT[(lb + pp * 32 + w * 8) * 64]);
            }
        }
        __builtin_amdgcn_sched_barrier(0);

        // (2) BD: 5 p-tiles, write per-wave BT[16][80] (col = k5*16+l15)
        __builtin_amdgcn_s_setprio(1);
        #pragma unroll
        for (int k5 = 0; k5 < 5; ++k5) {
            int pr = (3 - w + k5) * 16 + l15;     // p-index within [0,128)
            int lr = rbase + pr; if (lr >= 192) lr -= 192;
            const __bf16* rrow = &RT[lr * 64];
            f32x4 cc = {};
            cc = __builtin_amdgcn_mfma_f32_16x16x32_bf16(qr0, *(const bf16x8*)&rrow[((lg ^ (pr & 7)) * 8)], cc, 0, 0, 0);
            cc = __builtin_amdgcn_mfma_f32_16x16x32_bf16(qr1, *(const bf16x8*)&rrow[(((lg + 4) ^ (pr & 7)) * 8)], cc, 0, 0, 0);
            #pragma unroll
            for (int rg = 0; rg < 4; ++rg)
                BTw[(lg * 4 + rg) * 80 + k5 * 16 + l15] = (__bf16)cc[rg];
        }
        __builtin_amdgcn_s_setprio(0);

        // (3) AC + BD lookup + scale + band mask (BT read col = jr - r4 + 15)
        float sv[4][4];
        __builtin_amdgcn_s_setprio(1);
        #pragma unroll
        for (int nt = 0; nt < 4; ++nt) {
            int jr = nt * 16 + l15;
            f32x4 cc = {};
            cc = __builtin_amdgcn_mfma_f32_16x16x32_bf16(qw0, LDF(KTc, jr, lg), cc, 0, 0, 0);
            cc = __builtin_amdgcn_mfma_f32_16x16x32_bf16(qw1, LDF(KTc, jr, lg + 4), cc, 0, 0, 0);
            #pragma unroll
            for (int rg = 0; rg < 4; ++rg) {
                int r4 = lg * 4 + rg;
                int dji = jr - (w * 16 + r4);
                float s = (cc[rg] + (float)BTw[r4 * 80 + jr - r4 + 15]) * 0.125f;
                bool valid = (kt == 0) ? (dji >= 25)
                           : (kt == 1) ? (dji >= -39)
                           : (kt == 16) ? (dji <= 0) : true;
                sv[nt][rg] = valid ? s : -1e30f;
            }
        }
        __builtin_amdgcn_s_setprio(0);

        // (4) defer-max from LANE-LOCAL max (shuffle-free common path)
        float lmax[4];
        bool need = false;
        #pragma unroll
        for (int rg = 0; rg < 4; ++rg) {
            lmax[rg] = fmaxf(fmaxf(sv[0][rg], sv[1][rg]), fmaxf(sv[2][rg], sv[3][rg]));
            need = need || (lmax[rg] > rm[rg] + 8.0f);
        }
        if (__any(need)) {
            #pragma unroll
            for (int rg = 0; rg < 4; ++rg) {
                float m = lmax[rg];
                m = fmaxf(m, __shfl_xor(m, 1, 16));
                m = fmaxf(m, __shfl_xor(m, 2, 16));
                m = fmaxf(m, __shfl_xor(m, 4, 16));
                m = fmaxf(m, __shfl_xor(m, 8, 16));
                float nm = fmaxf(rm[rg], m);
                float fac = __expf(rm[rg] - nm);
                rm[rg] = nm;
                rl[rg] *= fac;
                O0[rg] *= fac; O1[rg] *= fac; O2[rg] *= fac; O3[rg] *= fac;
            }
        }

        // (5) exp + write P (bf16, swizzled)
        #pragma unroll
        for (int nt = 0; nt < 4; ++nt) {
            int jc = nt * 16 + l15;
            #pragma unroll
            for (int rg = 0; rg < 4; ++rg) {
                float p = (sv[nt][rg] > -1e29f) ? __expf(sv[nt][rg] - rm[rg]) : 0.0f;
                int row = w * 16 + lg * 4 + rg;
                PS[row * 64 + (((jc >> 3) ^ (row & 7)) * 8) + (jc & 7)] = (__bf16)p;
            }
        }

        // (6) PV + row-sum via all-ones MFMA (rl from Os; no shuffle reduce)
        bf16x8 pa0 = LDF(PS, mrow, lg), pa1 = LDF(PS, mrow, lg + 4);
        f32x4 Os = {};
        __builtin_amdgcn_s_setprio(1);
        Os = __builtin_amdgcn_mfma_f32_16x16x32_bf16(pa0, ones, Os, 0, 0, 0);
        Os = __builtin_amdgcn_mfma_f32_16x16x32_bf16(pa1, ones, Os, 0, 0, 0);
        O0 = __builtin_amdgcn_mfma_f32_16x16x32_bf16(pa0, LDF(VSc,  0 + l15, lg),     O0, 0, 0, 0);
        O0 = __builtin_amdgcn_mfma_f32_16x16x32_bf16(pa1, LDF(VSc,  0 + l15, lg + 4), O0, 0, 0, 0);
        O1 = __builtin_amdgcn_mfma_f32_16x16x32_bf16(pa0, LDF(VSc, 16 + l15, lg),     O1, 0, 0, 0);
        O1 = __builtin_amdgcn_mfma_f32_16x16x32_bf16(pa1, LDF(VSc, 16 + l15, lg + 4), O1, 0, 0, 0);
        O2 = __builtin_amdgcn_mfma_f32_16x16x32_bf16(pa0, LDF(VSc, 32 + l15, lg),     O2, 0, 0, 0);
        O2 = __builtin_amdgcn_mfma_f32_16x16x32_bf16(pa1, LDF(VSc, 32 + l15, lg + 4), O2, 0, 0, 0);
        O3 = __builtin_amdgcn_mfma_f32_16x16x32_bf16(pa0, LDF(VSc, 48 + l15, lg),     O3, 0, 0, 0);
        O3 = __builtin_amdgcn_mfma_f32_16x16x32_bf16(pa1, LDF(VSc, 48 + l15, lg + 4), O3, 0, 0, 0);
        __builtin_amdgcn_s_setprio(0);
        #pragma unroll
        for (int rg = 0; rg < 4; ++rg) rl[rg] += Os[rg];

        // (7) single end-of-iter drain + barrier
        asm volatile("s_waitcnt vmcnt(0)" ::: "memory");
        __builtin_amdgcn_sched_barrier(0);
        __builtin_amdgcn_s_barrier();
        cur ^= 1;
    }

    // ---- epilogue
    #pragma unroll
    for (int rg = 0; rg < 4; ++rg) {
        float inv = 1.0f / rl[rg];
        int q = i0 + w * 16 + lg * 4 + rg;
        long long base = ((long long)b * 1024 + q) * 1024 + fco;
        AVt[base +  0 + l15] = (__bf16)(O0[rg] * inv);
        AVt[base + 16 + l15] = (__bf16)(O1[rg] * inv);
        AVt[base + 32 + l15] = (__bf16)(O2[rg] * inv);
        AVt[base + 48 + l15] = (__bf16)(O3[rg] * inv);
    }
    #undef LDF
}

// ================= LN1: h = LN_d(ao_a + ao_b + b_o + z), z read from cat_t (bf16) ====
__global__ __launch_bounds__(256) void ln1_kernel(
    const float* __restrict__ AO, const float* __restrict__ AO2,
    const float* __restrict__ bo, const __bf16* __restrict__ CatT,
    __bf16* __restrict__ Hb)
{
    int i = blockIdx.x, b = blockIdx.y, t = threadIdx.x;
    __shared__ float xs[D_MODEL];
    __shared__ float red[256];
    __shared__ float smu, srstd;
    long long tb = ((long long)b * 1024 + i) * 1024;
    long long zb = ((long long)b * 2048 + 1024 + i) * 1024;

    float lsum = 0.0f;
    for (int dd = t; dd < D_MODEL; dd += 256) {
        float v = AO[tb + dd] + AO2[tb + dd] + bo[dd] + (float)CatT[zb + dd];
        xs[dd] = v;
        lsum += v;
    }
    red[t] = lsum; __syncthreads();
    for (int s2 = 128; s2 > 0; s2 >>= 1) { if (t < s2) red[t] += red[t + s2]; __syncthreads(); }
    if (t == 0) smu = red[0] * (1.0f / D_MODEL);
    __syncthreads();
    float mu = smu;

    float lq = 0.0f;
    for (int dd = t; dd < D_MODEL; dd += 256) { float c = xs[dd] - mu; lq += c * c; }
    red[t] = lq; __syncthreads();
    for (int s2 = 128; s2 > 0; s2 >>= 1) { if (t < s2) red[t] += red[t + s2]; __syncthreads(); }
    if (t == 0) srstd = rsqrtf(red[0] * (1.0f / D_MODEL) + 1e-5f);
    __syncthreads();
    float rstd = srstd;

    for (int dd = t; dd < D_MODEL; dd += 256)
        Hb[tb + dd] = (__bf16)((xs[dd] - mu) * rstd);
}

// ================= LN2 pass 1: per-token mu / rstd =================
__global__ __launch_bounds__(256) void ln2_stats(
    const float* __restrict__ F2a, const float* __restrict__ F2b,
    const __bf16* __restrict__ Hb, float2* __restrict__ st)
{
    int i = blockIdx.x, b = blockIdx.y, t = threadIdx.x;
    __shared__ float rs[256], rq[256];
    long long tb = ((long long)b * 1024 + i) * 1024;

    float s = 0.f, q = 0.f;
    for (int dd = t; dd < D_MODEL; dd += 256) {
        float v = F2a[tb + dd] + F2b[tb + dd] + (float)Hb[tb + dd];
        s += v; q += v * v;
    }
    rs[t] = s; rq[t] = q; __syncthreads();
    for (int s2 = 128; s2 > 0; s2 >>= 1) {
        if (t < s2) { rs[t] += rs[t + s2]; rq[t] += rq[t + s2]; }
        __syncthreads();
    }
    if (t == 0) {
        float mu = rs[0] * (1.0f / D_MODEL);
        float var = rq[0] * (1.0f / D_MODEL) - mu * mu;
        st[(long long)b * 1024 + i] = make_float2(mu, rsqrtf(var + 1e-5f));
    }
}

// ================= LN2 pass 2: normalized transpose-write (coalesced) =================
__global__ __launch_bounds__(256) void ln2_write(
    const float* __restrict__ F2a, const float* __restrict__ F2b,
    const __bf16* __restrict__ Hb, const float2* __restrict__ st,
    float* __restrict__ OUT)
{
    __shared__ float ts[32][33];
    int f0 = blockIdx.x * 32, i0 = blockIdx.y * 32, b = blockIdx.z;
    int tr = threadIdx.x >> 5, tc = threadIdx.x & 31;
    #pragma unroll
    for (int p = 0; p < 4; ++p) {
        int tok = i0 + tr + p * 8;
        long long tb = ((long long)b * 1024 + tok) * 1024;
        float2 s = st[(long long)b * 1024 + tok];
        float v = F2a[tb + f0 + tc] + F2b[tb + f0 + tc] + (float)Hb[tb + f0 + tc];
        ts[tr + p * 8][tc] = (v - s.x) * s.y;
    }
    __syncthreads();
    #pragma unroll
    for (int p = 0; p < 4; ++p)
        OUT[((long long)b * 1024 + f0 + tr + p * 8) * 1024 + i0 + tc] = ts[tc][tr + p * 8];
}

// ================= launch =================
extern "C" void kernel_launch(void* const* d_in, const int* in_sizes, int n_in,
                              void* d_out, int out_size, void* d_ws, size_t ws_size,
                              hipStream_t stream) {
    const float* z    = (const float*)d_in[0];
    const float* zh   = (const float*)d_in[1];
    const float* u    = (const float*)d_in[2];
    const float* pos  = (const float*)d_in[3];
    const float* Wqkv = (const float*)d_in[4];
    const float* Wr   = (const float*)d_in[5];
    const float* rwb  = (const float*)d_in[6];
    const float* rrb  = (const float*)d_in[7];
    const float* Wo   = (const float*)d_in[8];
    const float* bo   = (const float*)d_in[9];
    const float* Wff1 = (const float*)d_in[10];
    const float* bff1 = (const float*)d_in[11];
    const float* Wff2 = (const float*)d_in[12];
    const float* bff2 = (const float*)d_in[13];
    float* out = (float*)d_out;
    float* ws  = (float*)d_ws;

    // ---- workspace (f32-slot offsets) ----
    __bf16* cat_t = (__bf16*)ws;                         // [2][2048][1024]
    __bf16* pos_t = (__bf16*)(ws + 2097152);             // [2112][1024]
    __bf16* Wqkvb = (__bf16*)(ws + 3178496);
    __bf16* Wrb   = (__bf16*)(ws + 4751360);
    __bf16* Wob   = (__bf16*)(ws + 5275648);
    __bf16* Wff1b = (__bf16*)(ws + 5799936);
    __bf16* Wff2b = (__bf16*)(ws + 7897088);
    __bf16* uqkT  = (__bf16*)(ws + 9994240);             // [2][2048][2048]
    __bf16* qkT   = (__bf16*)(ws + 14188544);            // [2][2048][2048]
    __bf16* wh_v  = (__bf16*)(ws + 18382848);            // [2][1024][2048]
    __bf16* rkT   = (__bf16*)(ws + 20480000);            // [1152][1024]
    __bf16* av_t  = (__bf16*)(ws + 21069824);            // [2][1024][1024]
    float*  ao    = ws + 22118400;                       // [2 halves][2048][1024]
    __bf16* h_bf  = (__bf16*)(ws + 26312704);            // [2048][1024]
    float2* st2   = (float2*)(ws + 27361280);            // [2][1024] float2
    __bf16* f1b   = (__bf16*)(ws + 14188544);            // overlays qkT (dead after attn)
    float*  f2    = ws + 9994240;                        // overlays uqkT (dead after qkT GEMM)

    // ---- prep ----
    conv_multi<<<13312, 256, 0, stream>>>(
        Wqkv, Wqkvb, 3145728, Wr, Wrb, 1048576, Wo, Wob, 1048576,
        Wff1, Wff1b, 4194304, Wff2, Wff2b, 4194304);
    transp_bf16<<<dim3(32, 32, 2), 256, 0, stream>>>(zh, cat_t,           1024, 1024, 1048576LL, 2097152LL);
    transp_bf16<<<dim3(32, 32, 2), 256, 0, stream>>>(z,  cat_t + 1048576, 1024, 1024, 1048576LL, 2097152LL);
    transp_bf16<<<dim3(64, 32, 1), 256, 0, stream>>>(pos, pos_t, 1024, 2048, 0LL, 0LL);
    pad_pos<<<64, 256, 0, stream>>>(pos_t);
    transp_bf16<<<dim3(64, 64, 2), 256, 0, stream>>>(u, uqkT, 2048, 2048, 6291456LL, 4194304LL);

    // ---- qkT = bf16(cat^T @ Wqkv[0:2048]^T + u^T) ----
    gemm_bf16_k<4, 0><<<dim3(16, 16, 2), 256, 0, stream>>>(
        cat_t, Wqkvb, nullptr, qkT, nullptr, uqkT, nullptr,
        1024, 1024, 1024, 2048, 2048, 0, 2097152LL, 0LL, 4194304LL, 4194304LL, 0LL);
    // ---- wh_v = bf16(Wqkv[2048:] @ cat + u_V) ----
    gemm_bf16_k<2, 0><<<dim3(16, 16, 2), 256, 0, stream>>>(
        Wqkvb + 2048 * 1024, cat_t, nullptr, wh_v, u + 4194304, nullptr, nullptr,
        1024, 1024, 1024, 2048, 2048, 0, 0LL, 2097152LL, 2097152LL, 6291456LL, 0LL);
    // ---- rkT = bf16(pos^T[960:2112] @ Wr^T) ----
    gemm_bf16_k<2, 0><<<dim3(8, 18, 1), 256, 0, stream>>>(
        pos_t + 960 * 1024, Wrb, nullptr, rkT, nullptr, nullptr, nullptr,
        1024, 1024, 1024, 1024, 0, 0, 0LL, 0LL, 0LL, 0LL, 0LL);
    // ---- attention -> av_t ----
    attn_mfma<<<512, 256, 0, stream>>>(qkT, wh_v, rkT, rwb, rrb, av_t);
    // ---- ao_t partials = av_t @ Wo^T (K-split 2x512) ----
    gemm_bf16_k<2, 1><<<dim3(8, 64, 1), 256, 0, stream>>>(
        av_t, Wob, ao, nullptr, nullptr, nullptr, nullptr,
        512, 1024, 1024, 1024, 0, 0, 0LL, 0LL, 0LL, 0LL, 2097152LL);
    // ---- h = LN(ao_a + ao_b + bo + z) ----
    ln1_kernel<<<dim3(1024, 2), 256, 0, stream>>>(ao, ao + 2097152, bo, cat_t, h_bf);
    // ---- f1 = relu(h @ Wff1^T + bff1) ----
    gemm_bf16_k<4, 0><<<dim3(32, 16, 1), 256, 0, stream>>>(
        h_bf, Wff1b, nullptr, f1b, nullptr, nullptr, bff1,
        1024, 1024, 1024, 4096, 0, 1, 0LL, 0LL, 0LL, 0LL, 0LL);
    // ---- f2 partials = f1 @ Wff2^T + bff2 (K-split 2x2048) ----
    gemm_bf16_k<2, 1><<<dim3(8, 64, 1), 256, 0, stream>>>(
        f1b, Wff2b, f2, nullptr, nullptr, nullptr, bff2,
        2048, 4096, 4096, 1024, 0, 0, 0LL, 0LL, 0LL, 0LL, 2097152LL);
    // ---- out = LN(f2a + f2b + h), two-pass transposed ----
    ln2_stats<<<dim3(1024, 2), 256, 0, stream>>>(f2, f2 + 2097152, h_bf, st2);
    ln2_write<<<dim3(32, 32, 2), 256, 0, stream>>>(f2, f2 + 2097152, h_bf, st2, out);
}

// Round 9
// 275.063 us; speedup vs baseline: 1.6172x; 1.0313x over previous
//
#include <hip/hip_runtime.h>

#define D_MODEL 1024
#define QLEN 1024

typedef __bf16 bf16x8 __attribute__((ext_vector_type(8)));
typedef __bf16 bf16x4 __attribute__((ext_vector_type(4)));
typedef float f32x4 __attribute__((ext_vector_type(4)));

__device__ __forceinline__ void gload16(const void* g, void* l) {
    __builtin_amdgcn_global_load_lds(
        (const __attribute__((address_space(1))) void*)g,
        (__attribute__((address_space(3))) void*)l, 16, 0, 0);
}

// ============ bf16 MFMA GEMM, double-buffered (T3-minimum 2-phase) ============
// C[M,N] = A[M,K] @ Bt[N,K]^T (+U/Ub, +bias, relu). 4 waves 2x2. BM=MT*32, BN=128, BK=64.
// Per K-step: issue next-tile global_load_lds BEFORE computing current tile; wait
// vmcnt(LOADS_NEXT) not 0 -> staging latency hides under MFMA.
template<int MT, int KS>
__global__ __launch_bounds__(256) void gemm_bf16_k(
    const __bf16* __restrict__ A, const __bf16* __restrict__ Bt,
    float* __restrict__ C, __bf16* __restrict__ Cb,
    const float* __restrict__ U, const __bf16* __restrict__ Ub,
    const float* __restrict__ bias,
    int K, int lda, int ldb, int ldC, int ldU, int relu,
    long long sA, long long sB, long long sC, long long sU, long long sSplit)
{
    __shared__ __bf16 As[2][MT * 32][64];
    __shared__ __bf16 Bs[2][128][64];

    const int bz = blockIdx.z;
    int yb = blockIdx.y;
    int half = 0;
    if (KS) { half = yb & 1; yb >>= 1; }
    A  += (long long)bz * sA + (long long)half * K;
    Bt += (long long)bz * sB + (long long)half * K;
    if (C)  C  += (long long)bz * sC + (long long)half * sSplit;
    if (Cb) Cb += (long long)bz * sC;
    if (U)  U  += (long long)bz * sU;
    if (Ub) Ub += (long long)bz * sU;
    if (KS && half) { bias = nullptr; U = nullptr; Ub = nullptr; }

    const int t = threadIdx.x;
    const int lane = t & 63, w = t >> 6;
    const int l15 = lane & 15, lg = lane >> 4;
    const int m0 = yb * (MT * 32);
    const int n0 = blockIdx.x * 128;
    const int wm = w >> 1, wn = w & 1;

    const int srow = lane >> 3;
    const int cpr  = lane & 7;

    const int NK = K >> 6;

    #define STAGE(buf, kt)                                                                  \
    {                                                                                       \
        int k0s = (kt) * 64;                                                                \
        _Pragma("unroll")                                                                   \
        for (int i = 0; i < MT; ++i) {                                                      \
            int r = i * 32 + w * 8 + srow;                                                  \
            int c = cpr ^ (r & 7);                                                          \
            gload16(&A[(long long)(m0 + r) * lda + k0s + c * 8], &As[buf][i * 32 + w * 8][0]); \
        }                                                                                   \
        _Pragma("unroll")                                                                   \
        for (int i = 0; i < 4; ++i) {                                                       \
            int r = i * 32 + w * 8 + srow;                                                  \
            int c = cpr ^ (r & 7);                                                          \
            gload16(&Bt[(long long)(n0 + r) * ldb + k0s + c * 8], &Bs[buf][i * 32 + w * 8][0]); \
        }                                                                                   \
    }

    f32x4 acc[MT][4] = {};

    STAGE(0, 0);

    for (int kt = 0; kt < NK; ++kt) {
        const int cbuf = kt & 1;
        if (kt + 1 < NK) {
            STAGE(cbuf ^ 1, kt + 1);
            if constexpr (MT == 4) asm volatile("s_waitcnt vmcnt(8)" ::: "memory");
            else                   asm volatile("s_waitcnt vmcnt(6)" ::: "memory");
        } else {
            asm volatile("s_waitcnt vmcnt(0)" ::: "memory");
        }
        __builtin_amdgcn_sched_barrier(0);
        __builtin_amdgcn_s_barrier();      // current tile resident for all waves

        #pragma unroll
        for (int kk = 0; kk < 2; ++kk) {
            bf16x8 bfr[4];
            #pragma unroll
            for (int nt = 0; nt < 4; ++nt) {
                int nr = wn * 64 + nt * 16 + l15;
                bfr[nt] = *(const bf16x8*)&Bs[cbuf][nr][((kk * 4 + lg) ^ (nr & 7)) * 8];
            }
            #pragma unroll
            for (int mt = 0; mt < MT; ++mt) {
                int mr = wm * (MT * 16) + mt * 16 + l15;
                bf16x8 afr = *(const bf16x8*)&As[cbuf][mr][((kk * 4 + lg) ^ (mr & 7)) * 8];
                #pragma unroll
                for (int nt = 0; nt < 4; ++nt)
                    acc[mt][nt] = __builtin_amdgcn_mfma_f32_16x16x32_bf16(afr, bfr[nt], acc[mt][nt], 0, 0, 0);
            }
        }
        asm volatile("s_waitcnt lgkmcnt(0)" ::: "memory");
        __builtin_amdgcn_sched_barrier(0);
        __builtin_amdgcn_s_barrier();      // reads of cbuf done; next iter may overwrite
    }
    #undef STAGE

    #pragma unroll
    for (int mt = 0; mt < MT; ++mt) {
        #pragma unroll
        for (int nt = 0; nt < 4; ++nt) {
            #pragma unroll
            for (int rg = 0; rg < 4; ++rg) {
                int m = m0 + wm * (MT * 16) + mt * 16 + lg * 4 + rg;
                int n = n0 + wn * 64 + nt * 16 + l15;
                float v = acc[mt][nt][rg];
                if (U)    v += U[(long long)m * ldU + n];
                if (Ub)   v += (float)Ub[(long long)m * ldU + n];
                if (bias) v += bias[n];
                if (relu) v = fmaxf(v, 0.0f);
                if (Cb) Cb[(long long)m * ldC + n] = (__bf16)v;
                else    C [(long long)m * ldC + n] = v;
            }
        }
    }
}

// ============ fused fp32 -> bf16 convert over 5 weight arrays ============
__global__ __launch_bounds__(256) void conv_multi(
    const float* __restrict__ s0, __bf16* __restrict__ d0, int n0,
    const float* __restrict__ s1, __bf16* __restrict__ d1, int n1,
    const float* __restrict__ s2, __bf16* __restrict__ d2, int n2,
    const float* __restrict__ s3, __bf16* __restrict__ d3, int n3,
    const float* __restrict__ s4, __bf16* __restrict__ d4, int n4)
{
    long long i = ((long long)blockIdx.x * 256 + threadIdx.x) * 4;
    const float* s; __bf16* dd;
    if (i < n0)              { s = s0 + i; dd = d0 + i; }
    else if ((i -= n0) < n1) { s = s1 + i; dd = d1 + i; }
    else if ((i -= n1) < n2) { s = s2 + i; dd = d2 + i; }
    else if ((i -= n2) < n3) { s = s3 + i; dd = d3 + i; }
    else if ((i -= n3) < n4) { s = s4 + i; dd = d4 + i; }
    else return;
    float4 v = *(const float4*)s;
    bf16x4 o = { (__bf16)v.x, (__bf16)v.y, (__bf16)v.z, (__bf16)v.w };
    *(bf16x4*)dd = o;
}

// ============ transpose-convert: S[R][Cc] fp32 -> D[Cc][R] bf16 ============
__global__ __launch_bounds__(256) void transp_bf16(
    const float* __restrict__ S, __bf16* __restrict__ D,
    int R, int Cc, long long sS, long long sD)
{
    S += (long long)blockIdx.z * sS;
    D += (long long)blockIdx.z * sD;
    __shared__ float ts[32][33];
    int r0 = blockIdx.y * 32, c0 = blockIdx.x * 32;
    int tr = threadIdx.x >> 5, tc = threadIdx.x & 31;
    #pragma unroll
    for (int p = 0; p < 4; ++p)
        ts[tr + p * 8][tc] = S[(long long)(r0 + tr + p * 8) * Cc + c0 + tc];
    __syncthreads();
    #pragma unroll
    for (int p = 0; p < 4; ++p)
        D[(long long)(c0 + tr + p * 8) * R + r0 + tc] = (__bf16)ts[tc][tr + p * 8];
}

// zero pos_t rows [2048, 2112)
__global__ __launch_bounds__(256) void pad_pos(__bf16* __restrict__ pt) {
    int i = (blockIdx.x * 256 + threadIdx.x) * 4;
    bf16x4 zv = { (__bf16)0.f, (__bf16)0.f, (__bf16)0.f, (__bf16)0.f };
    *(bf16x4*)&pt[2048 * 1024 + i] = zv;
}

// ================= MFMA flash attention, 1-barrier pipelined =================
// RT ring = 192 rows; BT per-wave [16][84] (stride 84 = conflict-free write banks).
__global__ __launch_bounds__(256) void attn_mfma(
    const __bf16* __restrict__ QKT, const __bf16* __restrict__ WHV,
    const __bf16* __restrict__ RKT,
    const float* __restrict__ rwb, const float* __restrict__ rrb,
    __bf16* __restrict__ AVt)
{
    __shared__ __bf16 SM[38144];
    __bf16* KT0 = SM;              // [64][64] sw
    __bf16* KT1 = SM + 4096;
    __bf16* VS0 = SM + 8192;       // [64][64] sw (prologue: Qr temp)
    __bf16* VS1 = SM + 12288;
    __bf16* RT  = SM + 16384;      // [192][64] sw ring
    __bf16* PS  = SM + 28672;      // [64][64] sw (prologue: Qw temp; then P)
    __bf16* BT  = SM + 32768;      // per-wave [16][84], w*1344 offset

    const int d = blockIdx.x;
    const int xcd = d & 7, idx = d >> 3;
    const int qt = idx & 15;
    const int gq = xcd + 8 * (idx >> 4);
    const int b = gq >> 4, n = gq & 15;
    const int i0 = qt * 64;

    const int t = threadIdx.x;
    const int lane = t & 63, w = t >> 6;
    const int l15 = lane & 15, lg = lane >> 4;
    const int fco = n * 64;

    const __bf16* qkb = QKT + (long long)b * (2048 * 2048);
    const __bf16* vb  = WHV + (long long)b * (1024 * 2048) + (long long)fco * 2048;
    __bf16* BTw = BT + w * 1344;

    // ---- prologue: Qw -> PS, Qr -> VS0 (swizzled [q][dh])
    #pragma unroll
    for (int pp = 0; pp < 2; ++pp) {
        int cid = pp * 256 + t;
        int q = cid >> 3, s = cid & 7, c = s ^ (q & 7);
        bf16x8 qv = *(const bf16x8*)&qkb[(long long)(1024 + i0 + q) * 2048 + fco + c * 8];
        bf16x8 ow, orr;
        #pragma unroll
        for (int e = 0; e < 8; ++e) {
            float qf = (float)qv[e];
            ow[e]  = (__bf16)(qf + rwb[fco + c * 8 + e]);
            orr[e] = (__bf16)(qf + rrb[fco + c * 8 + e]);
        }
        *(bf16x8*)&PS[q * 64 + s * 8] = ow;
        *(bf16x8*)&VS0[q * 64 + s * 8] = orr;
    }
    __syncthreads();

    #define LDF(buf, row, ch) (*(const bf16x8*)&(buf)[(row) * 64 + ((((ch) ^ ((row) & 7))) * 8)])

    const int mrow = w * 16 + l15;
    bf16x8 qw0 = LDF(PS, mrow, lg), qw1 = LDF(PS, mrow, lg + 4);
    bf16x8 qr0 = LDF(VS0, mrow, lg), qr1 = LDF(VS0, mrow, lg + 4);
    asm volatile("s_waitcnt lgkmcnt(0)" ::: "memory");
    __builtin_amdgcn_sched_barrier(0);
    __builtin_amdgcn_s_barrier();        // all waves' Q-frag reads done

    // ---- prologue gloads: KT0/VS0 (kt=0), RT ring rows 0..191
    #pragma unroll
    for (int pp = 0; pp < 2; ++pp) {
        int cid = pp * 256 + t;
        int r = cid >> 3, s = cid & 7, c = s ^ (r & 7);
        gload16(&qkb[(long long)(i0 + r) * 2048 + 1024 + fco + c * 8], &KT0[(pp * 32 + w * 8) * 64]);
        gload16(&vb[(long long)r * 2048 + i0 + c * 8], &VS0[(pp * 32 + w * 8) * 64]);
    }
    #pragma unroll
    for (int pp = 0; pp < 6; ++pp) {
        int cid = pp * 256 + t;
        int r = cid >> 3, s = cid & 7, c = s ^ (r & 7);
        gload16(&RKT[(long long)r * 1024 + fco + c * 8], &RT[(pp * 32 + w * 8) * 64]);
    }
    asm volatile("s_waitcnt vmcnt(0)" ::: "memory");
    __builtin_amdgcn_sched_barrier(0);
    __builtin_amdgcn_s_barrier();

    const bf16x8 ones = { (__bf16)1.f, (__bf16)1.f, (__bf16)1.f, (__bf16)1.f,
                          (__bf16)1.f, (__bf16)1.f, (__bf16)1.f, (__bf16)1.f };

    f32x4 O0 = {}, O1 = {}, O2 = {}, O3 = {};
    float rm[4] = {-1e30f, -1e30f, -1e30f, -1e30f};
    float rl[4] = {0.f, 0.f, 0.f, 0.f};
    int cur = 0;

    for (int kt = 0; kt <= 16; ++kt) {
        __bf16* KTc = cur ? KT1 : KT0;
        __bf16* VSc = cur ? VS1 : VS0;
        __bf16* KTn = cur ? KT0 : KT1;
        __bf16* VSn = cur ? VS0 : VS1;
        const int rbase = (kt % 3) * 64;          // ring base for this iter's p-window

        // (1) issue ALL prefetches for kt+1: KT/VS (dbuf) + RT ring rows 64kt+128..+191
        if (kt < 16) {
            int j0n = i0 + (kt + 1) * 64;
            #pragma unroll
            for (int pp = 0; pp < 2; ++pp) {
                int cid = pp * 256 + t;
                int r = cid >> 3, s = cid & 7, c = s ^ (r & 7);
                gload16(&qkb[(long long)(j0n + r) * 2048 + 1024 + fco + c * 8], &KTn[(pp * 32 + w * 8) * 64]);
                gload16(&vb[(long long)r * 2048 + j0n + c * 8], &VSn[(pp * 32 + w * 8) * 64]);
            }
            int rb = kt * 64 + 128;               // absolute rkT row
            int lb = ((kt + 2) % 3) * 64;         // ring slot (contiguous 64 rows)
            #pragma unroll
            for (int pp = 0; pp < 2; ++pp) {
                int cid = pp * 256 + t;
                int r = cid >> 3, s = cid & 7, c = s ^ (r & 7);
                gload16(&RKT[(long long)(rb + r) * 1024 + fco + c * 8], &RT[(lb + pp * 32 + w * 8) * 64]);
            }
        }
        __builtin_amdgcn_sched_barrier(0);

        // (2) BD: 5 p-tiles, write per-wave BT[16][84]
        __builtin_amdgcn_s_setprio(1);
        #pragma unroll
        for (int k5 = 0; k5 < 5; ++k5) {
            int pr = (3 - w + k5) * 16 + l15;     // p-index within [0,128)
            int lr = rbase + pr; if (lr >= 192) lr -= 192;
            const __bf16* rrow = &RT[lr * 64];
            f32x4 cc = {};
            cc = __builtin_amdgcn_mfma_f32_16x16x32_bf16(qr0, *(const bf16x8*)&rrow[((lg ^ (pr & 7)) * 8)], cc, 0, 0, 0);
            cc = __builtin_amdgcn_mfma_f32_16x16x32_bf16(qr1, *(const bf16x8*)&rrow[(((lg + 4) ^ (pr & 7)) * 8)], cc, 0, 0, 0);
            #pragma unroll
            for (int rg = 0; rg < 4; ++rg)
                BTw[(lg * 4 + rg) * 84 + k5 * 16 + l15] = (__bf16)cc[rg];
        }
        __builtin_amdgcn_s_setprio(0);

        // (3) AC + BD lookup + scale + band mask (BT read col = jr - r4 + 15)
        float sv[4][4];
        __builtin_amdgcn_s_setprio(1);
        #pragma unroll
        for (int nt = 0; nt < 4; ++nt) {
            int jr = nt * 16 + l15;
            f32x4 cc = {};
            cc = __builtin_amdgcn_mfma_f32_16x16x32_bf16(qw0, LDF(KTc, jr, lg), cc, 0, 0, 0);
            cc = __builtin_amdgcn_mfma_f32_16x16x32_bf16(qw1, LDF(KTc, jr, lg + 4), cc, 0, 0, 0);
            #pragma unroll
            for (int rg = 0; rg < 4; ++rg) {
                int r4 = lg * 4 + rg;
                int dji = jr - (w * 16 + r4);
                float s = (cc[rg] + (float)BTw[r4 * 84 + jr - r4 + 15]) * 0.125f;
                bool valid = (kt == 0) ? (dji >= 25)
                           : (kt == 1) ? (dji >= -39)
                           : (kt == 16) ? (dji <= 0) : true;
                sv[nt][rg] = valid ? s : -1e30f;
            }
        }
        __builtin_amdgcn_s_setprio(0);

        // (4) defer-max from LANE-LOCAL max (shuffle-free common path)
        float lmax[4];
        bool need = false;
        #pragma unroll
        for (int rg = 0; rg < 4; ++rg) {
            lmax[rg] = fmaxf(fmaxf(sv[0][rg], sv[1][rg]), fmaxf(sv[2][rg], sv[3][rg]));
            need = need || (lmax[rg] > rm[rg] + 8.0f);
        }
        if (__any(need)) {
            #pragma unroll
            for (int rg = 0; rg < 4; ++rg) {
                float m = lmax[rg];
                m = fmaxf(m, __shfl_xor(m, 1, 16));
                m = fmaxf(m, __shfl_xor(m, 2, 16));
                m = fmaxf(m, __shfl_xor(m, 4, 16));
                m = fmaxf(m, __shfl_xor(m, 8, 16));
                float nm = fmaxf(rm[rg], m);
                float fac = __expf(rm[rg] - nm);
                rm[rg] = nm;
                rl[rg] *= fac;
                O0[rg] *= fac; O1[rg] *= fac; O2[rg] *= fac; O3[rg] *= fac;
            }
        }

        // (5) exp + write P (bf16, swizzled)
        #pragma unroll
        for (int nt = 0; nt < 4; ++nt) {
            int jc = nt * 16 + l15;
            #pragma unroll
            for (int rg = 0; rg < 4; ++rg) {
                float p = (sv[nt][rg] > -1e29f) ? __expf(sv[nt][rg] - rm[rg]) : 0.0f;
                int row = w * 16 + lg * 4 + rg;
                PS[row * 64 + (((jc >> 3) ^ (row & 7)) * 8) + (jc & 7)] = (__bf16)p;
            }
        }

        // (6) PV + row-sum via all-ones MFMA
        bf16x8 pa0 = LDF(PS, mrow, lg), pa1 = LDF(PS, mrow, lg + 4);
        f32x4 Os = {};
        __builtin_amdgcn_s_setprio(1);
        Os = __builtin_amdgcn_mfma_f32_16x16x32_bf16(pa0, ones, Os, 0, 0, 0);
        Os = __builtin_amdgcn_mfma_f32_16x16x32_bf16(pa1, ones, Os, 0, 0, 0);
        O0 = __builtin_amdgcn_mfma_f32_16x16x32_bf16(pa0, LDF(VSc,  0 + l15, lg),     O0, 0, 0, 0);
        O0 = __builtin_amdgcn_mfma_f32_16x16x32_bf16(pa1, LDF(VSc,  0 + l15, lg + 4), O0, 0, 0, 0);
        O1 = __builtin_amdgcn_mfma_f32_16x16x32_bf16(pa0, LDF(VSc, 16 + l15, lg),     O1, 0, 0, 0);
        O1 = __builtin_amdgcn_mfma_f32_16x16x32_bf16(pa1, LDF(VSc, 16 + l15, lg + 4), O1, 0, 0, 0);
        O2 = __builtin_amdgcn_mfma_f32_16x16x32_bf16(pa0, LDF(VSc, 32 + l15, lg),     O2, 0, 0, 0);
        O2 = __builtin_amdgcn_mfma_f32_16x16x32_bf16(pa1, LDF(VSc, 32 + l15, lg + 4), O2, 0, 0, 0);
        O3 = __builtin_amdgcn_mfma_f32_16x16x32_bf16(pa0, LDF(VSc, 48 + l15, lg),     O3, 0, 0, 0);
        O3 = __builtin_amdgcn_mfma_f32_16x16x32_bf16(pa1, LDF(VSc, 48 + l15, lg + 4), O3, 0, 0, 0);
        __builtin_amdgcn_s_setprio(0);
        #pragma unroll
        for (int rg = 0; rg < 4; ++rg) rl[rg] += Os[rg];

        // (7) single end-of-iter drain + barrier
        asm volatile("s_waitcnt vmcnt(0)" ::: "memory");
        __builtin_amdgcn_sched_barrier(0);
        __builtin_amdgcn_s_barrier();
        cur ^= 1;
    }

    // ---- epilogue
    #pragma unroll
    for (int rg = 0; rg < 4; ++rg) {
        float inv = 1.0f / rl[rg];
        int q = i0 + w * 16 + lg * 4 + rg;
        long long base = ((long long)b * 1024 + q) * 1024 + fco;
        AVt[base +  0 + l15] = (__bf16)(O0[rg] * inv);
        AVt[base + 16 + l15] = (__bf16)(O1[rg] * inv);
        AVt[base + 32 + l15] = (__bf16)(O2[rg] * inv);
        AVt[base + 48 + l15] = (__bf16)(O3[rg] * inv);
    }
    #undef LDF
}

// ================= LN1: h = LN_d(ao_a + ao_b + b_o + z), z read from cat_t (bf16) ====
__global__ __launch_bounds__(256) void ln1_kernel(
    const float* __restrict__ AO, const float* __restrict__ AO2,
    const float* __restrict__ bo, const __bf16* __restrict__ CatT,
    __bf16* __restrict__ Hb)
{
    int i = blockIdx.x, b = blockIdx.y, t = threadIdx.x;
    __shared__ float xs[D_MODEL];
    __shared__ float red[256];
    __shared__ float smu, srstd;
    long long tb = ((long long)b * 1024 + i) * 1024;
    long long zb = ((long long)b * 2048 + 1024 + i) * 1024;

    float lsum = 0.0f;
    for (int dd = t; dd < D_MODEL; dd += 256) {
        float v = AO[tb + dd] + AO2[tb + dd] + bo[dd] + (float)CatT[zb + dd];
        xs[dd] = v;
        lsum += v;
    }
    red[t] = lsum; __syncthreads();
    for (int s2 = 128; s2 > 0; s2 >>= 1) { if (t < s2) red[t] += red[t + s2]; __syncthreads(); }
    if (t == 0) smu = red[0] * (1.0f / D_MODEL);
    __syncthreads();
    float mu = smu;

    float lq = 0.0f;
    for (int dd = t; dd < D_MODEL; dd += 256) { float c = xs[dd] - mu; lq += c * c; }
    red[t] = lq; __syncthreads();
    for (int s2 = 128; s2 > 0; s2 >>= 1) { if (t < s2) red[t] += red[t + s2]; __syncthreads(); }
    if (t == 0) srstd = rsqrtf(red[0] * (1.0f / D_MODEL) + 1e-5f);
    __syncthreads();
    float rstd = srstd;

    for (int dd = t; dd < D_MODEL; dd += 256)
        Hb[tb + dd] = (__bf16)((xs[dd] - mu) * rstd);
}

// ================= LN2 pass 1: per-token mu / rstd =================
__global__ __launch_bounds__(256) void ln2_stats(
    const float* __restrict__ F2a, const float* __restrict__ F2b,
    const __bf16* __restrict__ Hb, float2* __restrict__ st)
{
    int i = blockIdx.x, b = blockIdx.y, t = threadIdx.x;
    __shared__ float rs[256], rq[256];
    long long tb = ((long long)b * 1024 + i) * 1024;

    float s = 0.f, q = 0.f;
    for (int dd = t; dd < D_MODEL; dd += 256) {
        float v = F2a[tb + dd] + F2b[tb + dd] + (float)Hb[tb + dd];
        s += v; q += v * v;
    }
    rs[t] = s; rq[t] = q; __syncthreads();
    for (int s2 = 128; s2 > 0; s2 >>= 1) {
        if (t < s2) { rs[t] += rs[t + s2]; rq[t] += rq[t + s2]; }
        __syncthreads();
    }
    if (t == 0) {
        float mu = rs[0] * (1.0f / D_MODEL);
        float var = rq[0] * (1.0f / D_MODEL) - mu * mu;
        st[(long long)b * 1024 + i] = make_float2(mu, rsqrtf(var + 1e-5f));
    }
}

// ================= LN2 pass 2: normalized transpose-write (coalesced) =================
__global__ __launch_bounds__(256) void ln2_write(
    const float* __restrict__ F2a, const float* __restrict__ F2b,
    const __bf16* __restrict__ Hb, const float2* __restrict__ st,
    float* __restrict__ OUT)
{
    __shared__ float ts[32][33];
    int f0 = blockIdx.x * 32, i0 = blockIdx.y * 32, b = blockIdx.z;
    int tr = threadIdx.x >> 5, tc = threadIdx.x & 31;
    #pragma unroll
    for (int p = 0; p < 4; ++p) {
        int tok = i0 + tr + p * 8;
        long long tb = ((long long)b * 1024 + tok) * 1024;
        float2 s = st[(long long)b * 1024 + tok];
        float v = F2a[tb + f0 + tc] + F2b[tb + f0 + tc] + (float)Hb[tb + f0 + tc];
        ts[tr + p * 8][tc] = (v - s.x) * s.y;
    }
    __syncthreads();
    #pragma unroll
    for (int p = 0; p < 4; ++p)
        OUT[((long long)b * 1024 + f0 + tr + p * 8) * 1024 + i0 + tc] = ts[tc][tr + p * 8];
}

// ================= launch =================
extern "C" void kernel_launch(void* const* d_in, const int* in_sizes, int n_in,
                              void* d_out, int out_size, void* d_ws, size_t ws_size,
                              hipStream_t stream) {
    const float* z    = (const float*)d_in[0];
    const float* zh   = (const float*)d_in[1];
    const float* u    = (const float*)d_in[2];
    const float* pos  = (const float*)d_in[3];
    const float* Wqkv = (const float*)d_in[4];
    const float* Wr   = (const float*)d_in[5];
    const float* rwb  = (const float*)d_in[6];
    const float* rrb  = (const float*)d_in[7];
    const float* Wo   = (const float*)d_in[8];
    const float* bo   = (const float*)d_in[9];
    const float* Wff1 = (const float*)d_in[10];
    const float* bff1 = (const float*)d_in[11];
    const float* Wff2 = (const float*)d_in[12];
    const float* bff2 = (const float*)d_in[13];
    float* out = (float*)d_out;
    float* ws  = (float*)d_ws;

    // ---- workspace (f32-slot offsets) ----
    __bf16* cat_t = (__bf16*)ws;                         // [2][2048][1024]
    __bf16* pos_t = (__bf16*)(ws + 2097152);             // [2112][1024]
    __bf16* Wqkvb = (__bf16*)(ws + 3178496);
    __bf16* Wrb   = (__bf16*)(ws + 4751360);
    __bf16* Wob   = (__bf16*)(ws + 5275648);
    __bf16* Wff1b = (__bf16*)(ws + 5799936);
    __bf16* Wff2b = (__bf16*)(ws + 7897088);
    __bf16* uqkT  = (__bf16*)(ws + 9994240);             // [2][2048][2048]
    __bf16* qkT   = (__bf16*)(ws + 14188544);            // [2][2048][2048]
    __bf16* wh_v  = (__bf16*)(ws + 18382848);            // [2][1024][2048]
    __bf16* rkT   = (__bf16*)(ws + 20480000);            // [1152][1024]
    __bf16* av_t  = (__bf16*)(ws + 21069824);            // [2][1024][1024]
    float*  ao    = ws + 22118400;                       // [2 halves][2048][1024]
    __bf16* h_bf  = (__bf16*)(ws + 26312704);            // [2048][1024]
    float2* st2   = (float2*)(ws + 27361280);            // [2][1024] float2
    __bf16* f1b   = (__bf16*)(ws + 14188544);            // overlays qkT (dead after attn)
    float*  f2    = ws + 9994240;                        // overlays uqkT (dead after qkT GEMM)

    // ---- prep ----
    conv_multi<<<13312, 256, 0, stream>>>(
        Wqkv, Wqkvb, 3145728, Wr, Wrb, 1048576, Wo, Wob, 1048576,
        Wff1, Wff1b, 4194304, Wff2, Wff2b, 4194304);
    transp_bf16<<<dim3(32, 32, 2), 256, 0, stream>>>(zh, cat_t,           1024, 1024, 1048576LL, 2097152LL);
    transp_bf16<<<dim3(32, 32, 2), 256, 0, stream>>>(z,  cat_t + 1048576, 1024, 1024, 1048576LL, 2097152LL);
    transp_bf16<<<dim3(64, 32, 1), 256, 0, stream>>>(pos, pos_t, 1024, 2048, 0LL, 0LL);
    pad_pos<<<64, 256, 0, stream>>>(pos_t);
    transp_bf16<<<dim3(64, 64, 2), 256, 0, stream>>>(u, uqkT, 2048, 2048, 6291456LL, 4194304LL);

    // ---- qkT = bf16(cat^T @ Wqkv[0:2048]^T + u^T) ----
    gemm_bf16_k<4, 0><<<dim3(16, 16, 2), 256, 0, stream>>>(
        cat_t, Wqkvb, nullptr, qkT, nullptr, uqkT, nullptr,
        1024, 1024, 1024, 2048, 2048, 0, 2097152LL, 0LL, 4194304LL, 4194304LL, 0LL);
    // ---- wh_v = bf16(Wqkv[2048:] @ cat + u_V) ----
    gemm_bf16_k<2, 0><<<dim3(16, 16, 2), 256, 0, stream>>>(
        Wqkvb + 2048 * 1024, cat_t, nullptr, wh_v, u + 4194304, nullptr, nullptr,
        1024, 1024, 1024, 2048, 2048, 0, 0LL, 2097152LL, 2097152LL, 6291456LL, 0LL);
    // ---- rkT = bf16(pos^T[960:2112] @ Wr^T) ----
    gemm_bf16_k<2, 0><<<dim3(8, 18, 1), 256, 0, stream>>>(
        pos_t + 960 * 1024, Wrb, nullptr, rkT, nullptr, nullptr, nullptr,
        1024, 1024, 1024, 1024, 0, 0, 0LL, 0LL, 0LL, 0LL, 0LL);
    // ---- attention -> av_t ----
    attn_mfma<<<512, 256, 0, stream>>>(qkT, wh_v, rkT, rwb, rrb, av_t);
    // ---- ao_t partials = av_t @ Wo^T (K-split 2x512) ----
    gemm_bf16_k<2, 1><<<dim3(8, 64, 1), 256, 0, stream>>>(
        av_t, Wob, ao, nullptr, nullptr, nullptr, nullptr,
        512, 1024, 1024, 1024, 0, 0, 0LL, 0LL, 0LL, 0LL, 2097152LL);
    // ---- h = LN(ao_a + ao_b + bo + z) ----
    ln1_kernel<<<dim3(1024, 2), 256, 0, stream>>>(ao, ao + 2097152, bo, cat_t, h_bf);
    // ---- f1 = relu(h @ Wff1^T + bff1) ----
    gemm_bf16_k<4, 0><<<dim3(32, 16, 1), 256, 0, stream>>>(
        h_bf, Wff1b, nullptr, f1b, nullptr, nullptr, bff1,
        1024, 1024, 1024, 4096, 0, 1, 0LL, 0LL, 0LL, 0LL, 0LL);
    // ---- f2 partials = f1 @ Wff2^T + bff2 (K-split 2x2048) ----
    gemm_bf16_k<2, 1><<<dim3(8, 64, 1), 256, 0, stream>>>(
        f1b, Wff2b, f2, nullptr, nullptr, nullptr, bff2,
        2048, 4096, 4096, 1024, 0, 0, 0LL, 0LL, 0LL, 0LL, 2097152LL);
    // ---- out = LN(f2a + f2b + h), two-pass transposed ----
    ln2_stats<<<dim3(1024, 2), 256, 0, stream>>>(f2, f2 + 2097152, h_bf, st2);
    ln2_write<<<dim3(32, 32, 2), 256, 0, stream>>>(f2, f2 + 2097152, h_bf, st2, out);
}

// Round 10
// 248.037 us; speedup vs baseline: 1.7934x; 1.1090x over previous
//
#include <hip/hip_runtime.h>

#define D_MODEL 1024
#define QLEN 1024

typedef __bf16 bf16x8 __attribute__((ext_vector_type(8)));
typedef __bf16 bf16x4 __attribute__((ext_vector_type(4)));
typedef float f32x4 __attribute__((ext_vector_type(4)));

__device__ __forceinline__ void gload16(const void* g, void* l) {
    __builtin_amdgcn_global_load_lds(
        (const __attribute__((address_space(1))) void*)g,
        (__attribute__((address_space(3))) void*)l, 16, 0, 0);
}

// ============ GEMM core: C[M,N] tile at (m0,n0) = A @ Bt^T, double-buffered ============
template<int MT>
__device__ __forceinline__ void gemm_core(
    __bf16* __restrict__ smA, __bf16* __restrict__ smB,
    const __bf16* __restrict__ A, const __bf16* __restrict__ Bt,
    float* __restrict__ C, __bf16* __restrict__ Cb,
    const float* __restrict__ U, const __bf16* __restrict__ Ub,
    const float* __restrict__ bias,
    int K, int lda, int ldb, int ldC, int ldU, int relu, int m0, int n0)
{
    const int t = threadIdx.x;
    const int lane = t & 63, w = t >> 6;
    const int l15 = lane & 15, lg = lane >> 4;
    const int wm = w >> 1, wn = w & 1;
    const int srow = lane >> 3, cpr = lane & 7;
    const int NK = K >> 6;
    const int ASZ = MT * 32 * 64;
    const int BSZ = 128 * 64;

    #define STAGE(buf, kt)                                                                   \
    {                                                                                        \
        int k0s = (kt) * 64;                                                                 \
        _Pragma("unroll")                                                                    \
        for (int i = 0; i < MT; ++i) {                                                       \
            int r = i * 32 + w * 8 + srow;                                                   \
            int c = cpr ^ (r & 7);                                                           \
            gload16(&A[(long long)(m0 + r) * lda + k0s + c * 8],                             \
                    &smA[(buf) * ASZ + (i * 32 + w * 8) * 64]);                              \
        }                                                                                    \
        _Pragma("unroll")                                                                    \
        for (int i = 0; i < 4; ++i) {                                                        \
            int r = i * 32 + w * 8 + srow;                                                   \
            int c = cpr ^ (r & 7);                                                           \
            gload16(&Bt[(long long)(n0 + r) * ldb + k0s + c * 8],                            \
                    &smB[(buf) * BSZ + (i * 32 + w * 8) * 64]);                              \
        }                                                                                    \
    }

    f32x4 acc[MT][4] = {};
    STAGE(0, 0);

    for (int kt = 0; kt < NK; ++kt) {
        const int cb = kt & 1;
        if (kt + 1 < NK) {
            STAGE(cb ^ 1, kt + 1);
            asm volatile("s_waitcnt vmcnt(8)" ::: "memory");   // MT=4: 8 new in flight
        } else {
            asm volatile("s_waitcnt vmcnt(0)" ::: "memory");
        }
        __builtin_amdgcn_sched_barrier(0);
        __builtin_amdgcn_s_barrier();

        #pragma unroll
        for (int kk = 0; kk < 2; ++kk) {
            bf16x8 bfr[4];
            #pragma unroll
            for (int nt = 0; nt < 4; ++nt) {
                int nr = wn * 64 + nt * 16 + l15;
                bfr[nt] = *(const bf16x8*)&smB[cb * BSZ + nr * 64 + (((kk * 4 + lg) ^ (nr & 7)) * 8)];
            }
            #pragma unroll
            for (int mt = 0; mt < MT; ++mt) {
                int mr = wm * (MT * 16) + mt * 16 + l15;
                bf16x8 afr = *(const bf16x8*)&smA[cb * ASZ + mr * 64 + (((kk * 4 + lg) ^ (mr & 7)) * 8)];
                #pragma unroll
                for (int nt = 0; nt < 4; ++nt)
                    acc[mt][nt] = __builtin_amdgcn_mfma_f32_16x16x32_bf16(afr, bfr[nt], acc[mt][nt], 0, 0, 0);
            }
        }
        asm volatile("s_waitcnt lgkmcnt(0)" ::: "memory");
        __builtin_amdgcn_sched_barrier(0);
        __builtin_amdgcn_s_barrier();
    }
    #undef STAGE

    #pragma unroll
    for (int mt = 0; mt < MT; ++mt) {
        #pragma unroll
        for (int nt = 0; nt < 4; ++nt) {
            #pragma unroll
            for (int rg = 0; rg < 4; ++rg) {
                int m = m0 + wm * (MT * 16) + mt * 16 + lg * 4 + rg;
                int n = n0 + wn * 64 + nt * 16 + l15;
                float v = acc[mt][nt][rg];
                if (U)    v += U[(long long)m * ldU + n];
                if (Ub)   v += (float)Ub[(long long)m * ldU + n];
                if (bias) v += bias[n];
                if (relu) v = fmaxf(v, 0.0f);
                if (Cb) Cb[(long long)m * ldC + n] = (__bf16)v;
                else    C [(long long)m * ldC + n] = v;
            }
        }
    }
}

// ============ generic wrapper (MT=4), optional K-split ============
template<int KS>
__global__ __launch_bounds__(256) void gemm_bf16_k(
    const __bf16* __restrict__ A, const __bf16* __restrict__ Bt,
    float* __restrict__ C, __bf16* __restrict__ Cb,
    const float* __restrict__ U, const __bf16* __restrict__ Ub,
    const float* __restrict__ bias,
    int K, int lda, int ldb, int ldC, int ldU, int relu,
    long long sA, long long sB, long long sC, long long sU, long long sSplit)
{
    __shared__ __bf16 SM[32768];
    const int bz = blockIdx.z;
    int yb = blockIdx.y;
    int half = 0;
    if (KS) { half = yb & 1; yb >>= 1; }
    A  += (long long)bz * sA + (long long)half * K;
    Bt += (long long)bz * sB + (long long)half * K;
    if (C)  C  += (long long)bz * sC + (long long)half * sSplit;
    if (Cb) Cb += (long long)bz * sC;
    if (U)  U  += (long long)bz * sU;
    if (Ub) Ub += (long long)bz * sU;
    if (KS && half) { bias = nullptr; U = nullptr; Ub = nullptr; }
    gemm_core<4>(SM, SM + 16384, A, Bt, C, Cb, U, Ub, bias,
                 K, lda, ldb, ldC, ldU, relu, yb * 128, blockIdx.x * 128);
}

// ============ fused 3-job GEMM: qkT (512) + wh_v (256) + rkT (72) ============
__global__ __launch_bounds__(256) void gemm_fused3(
    const __bf16* __restrict__ cat_t, const __bf16* __restrict__ Wqkvb,
    __bf16* __restrict__ qkT, const __bf16* __restrict__ uqkT,
    __bf16* __restrict__ wh_v, const float* __restrict__ uv,
    const __bf16* __restrict__ pos_t, const __bf16* __restrict__ Wrb,
    __bf16* __restrict__ rkT)
{
    __shared__ __bf16 SM[32768];
    int bid = blockIdx.x;
    if (bid < 512) {
        int zz = bid >> 8, rem = bid & 255, y = rem >> 4, x = rem & 15;
        gemm_core<4>(SM, SM + 16384,
                     cat_t + (long long)zz * 2097152, Wqkvb,
                     nullptr, qkT + (long long)zz * 4194304,
                     nullptr, uqkT + (long long)zz * 4194304, nullptr,
                     1024, 1024, 1024, 2048, 2048, 0, y * 128, x * 128);
    } else if (bid < 768) {
        int l = bid - 512, zz = l >> 7, rem = l & 127, y = rem >> 4, x = rem & 15;
        gemm_core<4>(SM, SM + 16384,
                     Wqkvb + 2048 * 1024, cat_t + (long long)zz * 2097152,
                     nullptr, wh_v + (long long)zz * 2097152,
                     uv + (long long)zz * 6291456, nullptr, nullptr,
                     1024, 1024, 1024, 2048, 2048, 0, y * 128, x * 128);
    } else {
        int l = bid - 768, y = l >> 3, x = l & 7;
        gemm_core<4>(SM, SM + 16384,
                     pos_t + 960 * 1024, Wrb,
                     nullptr, rkT, nullptr, nullptr, nullptr,
                     1024, 1024, 1024, 1024, 0, 0, y * 128, x * 128);
    }
}

// ============ fused prep: weight converts + 4 transposes + pos pad ============
__global__ __launch_bounds__(256) void prep_all(
    const float* __restrict__ Wqkv, __bf16* __restrict__ Wqkvb,
    const float* __restrict__ Wr,   __bf16* __restrict__ Wrb,
    const float* __restrict__ Wo,   __bf16* __restrict__ Wob,
    const float* __restrict__ Wff1, __bf16* __restrict__ Wff1b,
    const float* __restrict__ Wff2, __bf16* __restrict__ Wff2b,
    const float* __restrict__ zh, const float* __restrict__ z, __bf16* __restrict__ cat_t,
    const float* __restrict__ pos, __bf16* __restrict__ pos_t,
    const float* __restrict__ u, __bf16* __restrict__ uqkT)
{
    __shared__ float ts[32][33];
    int bid = blockIdx.x;
    const int t = threadIdx.x;
    if (bid < 13312) {   // weight converts
        long long i = ((long long)bid * 256 + t) * 4;
        const float* s; __bf16* dd;
        if (i < 3145728)                    { s = Wqkv + i; dd = Wqkvb + i; }
        else if ((i -= 3145728) < 1048576)  { s = Wr + i;   dd = Wrb + i; }
        else if ((i -= 1048576) < 1048576)  { s = Wo + i;   dd = Wob + i; }
        else if ((i -= 1048576) < 4194304)  { s = Wff1 + i; dd = Wff1b + i; }
        else { i -= 4194304;                  s = Wff2 + i; dd = Wff2b + i; }
        float4 v = *(const float4*)s;
        bf16x4 o = { (__bf16)v.x, (__bf16)v.y, (__bf16)v.z, (__bf16)v.w };
        *(bf16x4*)dd = o;
        return;
    }
    bid -= 13312;
    const float* S; __bf16* D; int R, Cc, bx, by;
    if (bid < 2048) {            // zh -> cat_t[:, 0:1024]
        int zz = bid >> 10, r2 = bid & 1023;
        S = zh + (long long)zz * 1048576; D = cat_t + (long long)zz * 2097152;
        R = 1024; Cc = 1024; bx = r2 & 31; by = r2 >> 5;
    } else if (bid < 4096) {     // z -> cat_t[:, 1024:2048]
        int l = bid - 2048; int zz = l >> 10, r2 = l & 1023;
        S = z + (long long)zz * 1048576; D = cat_t + 1048576 + (long long)zz * 2097152;
        R = 1024; Cc = 1024; bx = r2 & 31; by = r2 >> 5;
    } else if (bid < 6144) {     // pos -> pos_t
        int l = bid - 4096;
        S = pos; D = pos_t; R = 1024; Cc = 2048; bx = l & 63; by = l >> 6;
    } else if (bid < 14336) {    // u QK-part -> uqkT
        int l = bid - 6144; int zz = l >> 12, r2 = l & 4095;
        S = u + (long long)zz * 6291456; D = uqkT + (long long)zz * 4194304;
        R = 2048; Cc = 2048; bx = r2 & 63; by = r2 >> 6;
    } else {                     // pad pos_t rows [2048,2112)
        int l = bid - 14336;
        int i = (l * 256 + t) * 4;
        bf16x4 zv = { (__bf16)0.f, (__bf16)0.f, (__bf16)0.f, (__bf16)0.f };
        *(bf16x4*)&pos_t[2048 * 1024 + i] = zv;
        return;
    }
    int r0 = by * 32, c0 = bx * 32;
    int tr = t >> 5, tc = t & 31;
    #pragma unroll
    for (int p = 0; p < 4; ++p)
        ts[tr + p * 8][tc] = S[(long long)(r0 + tr + p * 8) * Cc + c0 + tc];
    __syncthreads();
    #pragma unroll
    for (int p = 0; p < 4; ++p)
        D[(long long)(c0 + tr + p * 8) * R + r0 + tc] = (__bf16)ts[tc][tr + p * 8];
}

// ================= MFMA flash attention, 1-barrier pipelined =================
__global__ __launch_bounds__(256) void attn_mfma(
    const __bf16* __restrict__ QKT, const __bf16* __restrict__ WHV,
    const __bf16* __restrict__ RKT,
    const float* __restrict__ rwb, const float* __restrict__ rrb,
    __bf16* __restrict__ AVt)
{
    __shared__ __bf16 SM[38144];
    __bf16* KT0 = SM;
    __bf16* KT1 = SM + 4096;
    __bf16* VS0 = SM + 8192;
    __bf16* VS1 = SM + 12288;
    __bf16* RT  = SM + 16384;      // [192][64] sw ring
    __bf16* PS  = SM + 28672;
    __bf16* BT  = SM + 32768;      // per-wave [16][84]

    const int d = blockIdx.x;
    const int xcd = d & 7, idx = d >> 3;
    const int qt = idx & 15;
    const int gq = xcd + 8 * (idx >> 4);
    const int b = gq >> 4, n = gq & 15;
    const int i0 = qt * 64;

    const int t = threadIdx.x;
    const int lane = t & 63, w = t >> 6;
    const int l15 = lane & 15, lg = lane >> 4;
    const int fco = n * 64;

    const __bf16* qkb = QKT + (long long)b * (2048 * 2048);
    const __bf16* vb  = WHV + (long long)b * (1024 * 2048) + (long long)fco * 2048;
    __bf16* BTw = BT + w * 1344;

    #pragma unroll
    for (int pp = 0; pp < 2; ++pp) {
        int cid = pp * 256 + t;
        int q = cid >> 3, s = cid & 7, c = s ^ (q & 7);
        bf16x8 qv = *(const bf16x8*)&qkb[(long long)(1024 + i0 + q) * 2048 + fco + c * 8];
        bf16x8 ow, orr;
        #pragma unroll
        for (int e = 0; e < 8; ++e) {
            float qf = (float)qv[e];
            ow[e]  = (__bf16)(qf + rwb[fco + c * 8 + e]);
            orr[e] = (__bf16)(qf + rrb[fco + c * 8 + e]);
        }
        *(bf16x8*)&PS[q * 64 + s * 8] = ow;
        *(bf16x8*)&VS0[q * 64 + s * 8] = orr;
    }
    __syncthreads();

    #define LDF(buf, row, ch) (*(const bf16x8*)&(buf)[(row) * 64 + ((((ch) ^ ((row) & 7))) * 8)])

    const int mrow = w * 16 + l15;
    bf16x8 qw0 = LDF(PS, mrow, lg), qw1 = LDF(PS, mrow, lg + 4);
    bf16x8 qr0 = LDF(VS0, mrow, lg), qr1 = LDF(VS0, mrow, lg + 4);
    asm volatile("s_waitcnt lgkmcnt(0)" ::: "memory");
    __builtin_amdgcn_sched_barrier(0);
    __builtin_amdgcn_s_barrier();

    #pragma unroll
    for (int pp = 0; pp < 2; ++pp) {
        int cid = pp * 256 + t;
        int r = cid >> 3, s = cid & 7, c = s ^ (r & 7);
        gload16(&qkb[(long long)(i0 + r) * 2048 + 1024 + fco + c * 8], &KT0[(pp * 32 + w * 8) * 64]);
        gload16(&vb[(long long)r * 2048 + i0 + c * 8], &VS0[(pp * 32 + w * 8) * 64]);
    }
    #pragma unroll
    for (int pp = 0; pp < 6; ++pp) {
        int cid = pp * 256 + t;
        int r = cid >> 3, s = cid & 7, c = s ^ (r & 7);
        gload16(&RKT[(long long)r * 1024 + fco + c * 8], &RT[(pp * 32 + w * 8) * 64]);
    }
    asm volatile("s_waitcnt vmcnt(0)" ::: "memory");
    __builtin_amdgcn_sched_barrier(0);
    __builtin_amdgcn_s_barrier();

    const bf16x8 ones = { (__bf16)1.f, (__bf16)1.f, (__bf16)1.f, (__bf16)1.f,
                          (__bf16)1.f, (__bf16)1.f, (__bf16)1.f, (__bf16)1.f };

    f32x4 O0 = {}, O1 = {}, O2 = {}, O3 = {};
    float rm[4] = {-1e30f, -1e30f, -1e30f, -1e30f};
    float rl[4] = {0.f, 0.f, 0.f, 0.f};
    int cur = 0;

    for (int kt = 0; kt <= 16; ++kt) {
        __bf16* KTc = cur ? KT1 : KT0;
        __bf16* VSc = cur ? VS1 : VS0;
        __bf16* KTn = cur ? KT0 : KT1;
        __bf16* VSn = cur ? VS0 : VS1;
        const int rbase = (kt % 3) * 64;

        // (1) prefetches for kt+1
        if (kt < 16) {
            int j0n = i0 + (kt + 1) * 64;
            #pragma unroll
            for (int pp = 0; pp < 2; ++pp) {
                int cid = pp * 256 + t;
                int r = cid >> 3, s = cid & 7, c = s ^ (r & 7);
                gload16(&qkb[(long long)(j0n + r) * 2048 + 1024 + fco + c * 8], &KTn[(pp * 32 + w * 8) * 64]);
                gload16(&vb[(long long)r * 2048 + j0n + c * 8], &VSn[(pp * 32 + w * 8) * 64]);
            }
            int rb = kt * 64 + 128;
            int lb = ((kt + 2) % 3) * 64;
            #pragma unroll
            for (int pp = 0; pp < 2; ++pp) {
                int cid = pp * 256 + t;
                int r = cid >> 3, s = cid & 7, c = s ^ (r & 7);
                gload16(&RKT[(long long)(rb + r) * 1024 + fco + c * 8], &RT[(lb + pp * 32 + w * 8) * 64]);
            }
        }
        __builtin_amdgcn_sched_barrier(0);

        // (2) BD: 5 p-tiles -> per-wave BT
        __builtin_amdgcn_s_setprio(1);
        #pragma unroll
        for (int k5 = 0; k5 < 5; ++k5) {
            int pr = (3 - w + k5) * 16 + l15;
            int lr = rbase + pr; if (lr >= 192) lr -= 192;
            const __bf16* rrow = &RT[lr * 64];
            f32x4 cc = {};
            cc = __builtin_amdgcn_mfma_f32_16x16x32_bf16(qr0, *(const bf16x8*)&rrow[((lg ^ (pr & 7)) * 8)], cc, 0, 0, 0);
            cc = __builtin_amdgcn_mfma_f32_16x16x32_bf16(qr1, *(const bf16x8*)&rrow[(((lg + 4) ^ (pr & 7)) * 8)], cc, 0, 0, 0);
            #pragma unroll
            for (int rg = 0; rg < 4; ++rg)
                BTw[(lg * 4 + rg) * 84 + k5 * 16 + l15] = (__bf16)cc[rg];
        }
        __builtin_amdgcn_s_setprio(0);

        // (3) AC MFMAs -> cc4
        f32x4 cc4[4];
        __builtin_amdgcn_s_setprio(1);
        #pragma unroll
        for (int nt = 0; nt < 4; ++nt) {
            int jr = nt * 16 + l15;
            f32x4 cc = {};
            cc = __builtin_amdgcn_mfma_f32_16x16x32_bf16(qw0, LDF(KTc, jr, lg), cc, 0, 0, 0);
            cc = __builtin_amdgcn_mfma_f32_16x16x32_bf16(qw1, LDF(KTc, jr, lg + 4), cc, 0, 0, 0);
            cc4[nt] = cc;
        }
        __builtin_amdgcn_s_setprio(0);

        // score assembly: interior iterations (kt 2..15) are provably mask-free
        const bool bnd = (kt < 2) | (kt == 16);
        float sv[4][4];
        if (!bnd) {
            #pragma unroll
            for (int nt = 0; nt < 4; ++nt) {
                int jr = nt * 16 + l15;
                #pragma unroll
                for (int rg = 0; rg < 4; ++rg) {
                    int r4 = lg * 4 + rg;
                    sv[nt][rg] = (cc4[nt][rg] + (float)BTw[r4 * 84 + jr - r4 + 15]) * 0.125f;
                }
            }
        } else {
            #pragma unroll
            for (int nt = 0; nt < 4; ++nt) {
                int jr = nt * 16 + l15;
                #pragma unroll
                for (int rg = 0; rg < 4; ++rg) {
                    int r4 = lg * 4 + rg;
                    int dji = jr - (w * 16 + r4);
                    float s = (cc4[nt][rg] + (float)BTw[r4 * 84 + jr - r4 + 15]) * 0.125f;
                    bool valid = (kt == 0) ? (dji >= 25)
                               : (kt == 1) ? (dji >= -39)
                               : (dji <= 0);
                    sv[nt][rg] = valid ? s : -1e30f;
                }
            }
        }

        // (4) defer-max (lane-local trigger)
        float lmax[4];
        bool need = false;
        #pragma unroll
        for (int rg = 0; rg < 4; ++rg) {
            lmax[rg] = fmaxf(fmaxf(sv[0][rg], sv[1][rg]), fmaxf(sv[2][rg], sv[3][rg]));
            need = need || (lmax[rg] > rm[rg] + 8.0f);
        }
        if (__any(need)) {
            #pragma unroll
            for (int rg = 0; rg < 4; ++rg) {
                float m = lmax[rg];
                m = fmaxf(m, __shfl_xor(m, 1, 16));
                m = fmaxf(m, __shfl_xor(m, 2, 16));
                m = fmaxf(m, __shfl_xor(m, 4, 16));
                m = fmaxf(m, __shfl_xor(m, 8, 16));
                float nm = fmaxf(rm[rg], m);
                float fac = __expf(rm[rg] - nm);
                rm[rg] = nm;
                rl[rg] *= fac;
                O0[rg] *= fac; O1[rg] *= fac; O2[rg] *= fac; O3[rg] *= fac;
            }
        }

        // (5) exp + write P (guard only on boundary iterations)
        if (!bnd) {
            #pragma unroll
            for (int nt = 0; nt < 4; ++nt) {
                int jc = nt * 16 + l15;
                #pragma unroll
                for (int rg = 0; rg < 4; ++rg) {
                    float p = __expf(sv[nt][rg] - rm[rg]);
                    int row = w * 16 + lg * 4 + rg;
                    PS[row * 64 + (((jc >> 3) ^ (row & 7)) * 8) + (jc & 7)] = (__bf16)p;
                }
            }
        } else {
            #pragma unroll
            for (int nt = 0; nt < 4; ++nt) {
                int jc = nt * 16 + l15;
                #pragma unroll
                for (int rg = 0; rg < 4; ++rg) {
                    float p = (sv[nt][rg] > -1e29f) ? __expf(sv[nt][rg] - rm[rg]) : 0.0f;
                    int row = w * 16 + lg * 4 + rg;
                    PS[row * 64 + (((jc >> 3) ^ (row & 7)) * 8) + (jc & 7)] = (__bf16)p;
                }
            }
        }

        // (6) PV + row-sum via all-ones MFMA
        bf16x8 pa0 = LDF(PS, mrow, lg), pa1 = LDF(PS, mrow, lg + 4);
        f32x4 Os = {};
        __builtin_amdgcn_s_setprio(1);
        Os = __builtin_amdgcn_mfma_f32_16x16x32_bf16(pa0, ones, Os, 0, 0, 0);
        Os = __builtin_amdgcn_mfma_f32_16x16x32_bf16(pa1, ones, Os, 0, 0, 0);
        O0 = __builtin_amdgcn_mfma_f32_16x16x32_bf16(pa0, LDF(VSc,  0 + l15, lg),     O0, 0, 0, 0);
        O0 = __builtin_amdgcn_mfma_f32_16x16x32_bf16(pa1, LDF(VSc,  0 + l15, lg + 4), O0, 0, 0, 0);
        O1 = __builtin_amdgcn_mfma_f32_16x16x32_bf16(pa0, LDF(VSc, 16 + l15, lg),     O1, 0, 0, 0);
        O1 = __builtin_amdgcn_mfma_f32_16x16x32_bf16(pa1, LDF(VSc, 16 + l15, lg + 4), O1, 0, 0, 0);
        O2 = __builtin_amdgcn_mfma_f32_16x16x32_bf16(pa0, LDF(VSc, 32 + l15, lg),     O2, 0, 0, 0);
        O2 = __builtin_amdgcn_mfma_f32_16x16x32_bf16(pa1, LDF(VSc, 32 + l15, lg + 4), O2, 0, 0, 0);
        O3 = __builtin_amdgcn_mfma_f32_16x16x32_bf16(pa0, LDF(VSc, 48 + l15, lg),     O3, 0, 0, 0);
        O3 = __builtin_amdgcn_mfma_f32_16x16x32_bf16(pa1, LDF(VSc, 48 + l15, lg + 4), O3, 0, 0, 0);
        __builtin_amdgcn_s_setprio(0);
        #pragma unroll
        for (int rg = 0; rg < 4; ++rg) rl[rg] += Os[rg];

        // (7) single end-of-iter drain + barrier
        asm volatile("s_waitcnt vmcnt(0)" ::: "memory");
        __builtin_amdgcn_sched_barrier(0);
        __builtin_amdgcn_s_barrier();
        cur ^= 1;
    }

    #pragma unroll
    for (int rg = 0; rg < 4; ++rg) {
        float inv = 1.0f / rl[rg];
        int q = i0 + w * 16 + lg * 4 + rg;
        long long base = ((long long)b * 1024 + q) * 1024 + fco;
        AVt[base +  0 + l15] = (__bf16)(O0[rg] * inv);
        AVt[base + 16 + l15] = (__bf16)(O1[rg] * inv);
        AVt[base + 32 + l15] = (__bf16)(O2[rg] * inv);
        AVt[base + 48 + l15] = (__bf16)(O3[rg] * inv);
    }
    #undef LDF
}

// ================= LN1 =================
__global__ __launch_bounds__(256) void ln1_kernel(
    const float* __restrict__ AO, const float* __restrict__ AO2,
    const float* __restrict__ bo, const __bf16* __restrict__ CatT,
    __bf16* __restrict__ Hb)
{
    int i = blockIdx.x, b = blockIdx.y, t = threadIdx.x;
    __shared__ float xs[D_MODEL];
    __shared__ float red[256];
    __shared__ float smu, srstd;
    long long tb = ((long long)b * 1024 + i) * 1024;
    long long zb = ((long long)b * 2048 + 1024 + i) * 1024;

    float lsum = 0.0f;
    for (int dd = t; dd < D_MODEL; dd += 256) {
        float v = AO[tb + dd] + AO2[tb + dd] + bo[dd] + (float)CatT[zb + dd];
        xs[dd] = v;
        lsum += v;
    }
    red[t] = lsum; __syncthreads();
    for (int s2 = 128; s2 > 0; s2 >>= 1) { if (t < s2) red[t] += red[t + s2]; __syncthreads(); }
    if (t == 0) smu = red[0] * (1.0f / D_MODEL);
    __syncthreads();
    float mu = smu;

    float lq = 0.0f;
    for (int dd = t; dd < D_MODEL; dd += 256) { float c = xs[dd] - mu; lq += c * c; }
    red[t] = lq; __syncthreads();
    for (int s2 = 128; s2 > 0; s2 >>= 1) { if (t < s2) red[t] += red[t + s2]; __syncthreads(); }
    if (t == 0) srstd = rsqrtf(red[0] * (1.0f / D_MODEL) + 1e-5f);
    __syncthreads();
    float rstd = srstd;

    for (int dd = t; dd < D_MODEL; dd += 256)
        Hb[tb + dd] = (__bf16)((xs[dd] - mu) * rstd);
}

// ================= LN2 stats =================
__global__ __launch_bounds__(256) void ln2_stats(
    const float* __restrict__ F2a, const float* __restrict__ F2b,
    const __bf16* __restrict__ Hb, float2* __restrict__ st)
{
    int i = blockIdx.x, b = blockIdx.y, t = threadIdx.x;
    __shared__ float rs[256], rq[256];
    long long tb = ((long long)b * 1024 + i) * 1024;

    float s = 0.f, q = 0.f;
    for (int dd = t; dd < D_MODEL; dd += 256) {
        float v = F2a[tb + dd] + F2b[tb + dd] + (float)Hb[tb + dd];
        s += v; q += v * v;
    }
    rs[t] = s; rq[t] = q; __syncthreads();
    for (int s2 = 128; s2 > 0; s2 >>= 1) {
        if (t < s2) { rs[t] += rs[t + s2]; rq[t] += rq[t + s2]; }
        __syncthreads();
    }
    if (t == 0) {
        float mu = rs[0] * (1.0f / D_MODEL);
        float var = rq[0] * (1.0f / D_MODEL) - mu * mu;
        st[(long long)b * 1024 + i] = make_float2(mu, rsqrtf(var + 1e-5f));
    }
}

// ================= LN2 transposed write =================
__global__ __launch_bounds__(256) void ln2_write(
    const float* __restrict__ F2a, const float* __restrict__ F2b,
    const __bf16* __restrict__ Hb, const float2* __restrict__ st,
    float* __restrict__ OUT)
{
    __shared__ float ts[32][33];
    int f0 = blockIdx.x * 32, i0 = blockIdx.y * 32, b = blockIdx.z;
    int tr = threadIdx.x >> 5, tc = threadIdx.x & 31;
    #pragma unroll
    for (int p = 0; p < 4; ++p) {
        int tok = i0 + tr + p * 8;
        long long tb = ((long long)b * 1024 + tok) * 1024;
        float2 s = st[(long long)b * 1024 + tok];
        float v = F2a[tb + f0 + tc] + F2b[tb + f0 + tc] + (float)Hb[tb + f0 + tc];
        ts[tr + p * 8][tc] = (v - s.x) * s.y;
    }
    __syncthreads();
    #pragma unroll
    for (int p = 0; p < 4; ++p)
        OUT[((long long)b * 1024 + f0 + tr + p * 8) * 1024 + i0 + tc] = ts[tc][tr + p * 8];
}

// ================= launch =================
extern "C" void kernel_launch(void* const* d_in, const int* in_sizes, int n_in,
                              void* d_out, int out_size, void* d_ws, size_t ws_size,
                              hipStream_t stream) {
    const float* z    = (const float*)d_in[0];
    const float* zh   = (const float*)d_in[1];
    const float* u    = (const float*)d_in[2];
    const float* pos  = (const float*)d_in[3];
    const float* Wqkv = (const float*)d_in[4];
    const float* Wr   = (const float*)d_in[5];
    const float* rwb  = (const float*)d_in[6];
    const float* rrb  = (const float*)d_in[7];
    const float* Wo   = (const float*)d_in[8];
    const float* bo   = (const float*)d_in[9];
    const float* Wff1 = (const float*)d_in[10];
    const float* bff1 = (const float*)d_in[11];
    const float* Wff2 = (const float*)d_in[12];
    const float* bff2 = (const float*)d_in[13];
    float* out = (float*)d_out;
    float* ws  = (float*)d_ws;

    // ---- workspace (f32-slot offsets) ----
    __bf16* cat_t = (__bf16*)ws;                         // [2][2048][1024]
    __bf16* pos_t = (__bf16*)(ws + 2097152);             // [2112][1024]
    __bf16* Wqkvb = (__bf16*)(ws + 3178496);
    __bf16* Wrb   = (__bf16*)(ws + 4751360);
    __bf16* Wob   = (__bf16*)(ws + 5275648);
    __bf16* Wff1b = (__bf16*)(ws + 5799936);
    __bf16* Wff2b = (__bf16*)(ws + 7897088);
    __bf16* uqkT  = (__bf16*)(ws + 9994240);             // [2][2048][2048]
    __bf16* qkT   = (__bf16*)(ws + 14188544);            // [2][2048][2048]
    __bf16* wh_v  = (__bf16*)(ws + 18382848);            // [2][1024][2048]
    __bf16* rkT   = (__bf16*)(ws + 20480000);            // [1152][1024]
    __bf16* av_t  = (__bf16*)(ws + 21069824);            // [2][1024][1024]
    float*  ao    = ws + 22118400;                       // [2 halves][2048][1024]
    __bf16* h_bf  = (__bf16*)(ws + 26312704);            // [2048][1024]
    float2* st2   = (float2*)(ws + 27361280);            // [2][1024] float2
    __bf16* f1b   = (__bf16*)(ws + 14188544);            // overlays qkT (dead after attn)
    float*  f2    = ws + 9994240;                        // overlays uqkT (dead after qkT GEMM)

    // ---- fused prep (converts + transposes + pad) ----
    prep_all<<<27712, 256, 0, stream>>>(
        Wqkv, Wqkvb, Wr, Wrb, Wo, Wob, Wff1, Wff1b, Wff2, Wff2b,
        zh, z, cat_t, pos, pos_t, u, uqkT);

    // ---- fused qkT + wh_v + rkT GEMMs ----
    gemm_fused3<<<840, 256, 0, stream>>>(
        cat_t, Wqkvb, qkT, uqkT, wh_v, u + 4194304, pos_t, Wrb, rkT);

    // ---- attention -> av_t ----
    attn_mfma<<<512, 256, 0, stream>>>(qkT, wh_v, rkT, rwb, rrb, av_t);

    // ---- ao_t partials = av_t @ Wo^T (K-split 2x512, MT=4) ----
    gemm_bf16_k<1><<<dim3(8, 32, 1), 256, 0, stream>>>(
        av_t, Wob, ao, nullptr, nullptr, nullptr, nullptr,
        512, 1024, 1024, 1024, 0, 0, 0LL, 0LL, 0LL, 0LL, 2097152LL);
    // ---- h = LN(ao_a + ao_b + bo + z) ----
    ln1_kernel<<<dim3(1024, 2), 256, 0, stream>>>(ao, ao + 2097152, bo, cat_t, h_bf);
    // ---- f1 = relu(h @ Wff1^T + bff1) (MT=4) ----
    gemm_bf16_k<0><<<dim3(32, 16, 1), 256, 0, stream>>>(
        h_bf, Wff1b, nullptr, f1b, nullptr, nullptr, bff1,
        1024, 1024, 1024, 4096, 0, 1, 0LL, 0LL, 0LL, 0LL, 0LL);
    // ---- f2 partials = f1 @ Wff2^T + bff2 (K-split 2x2048, MT=4) ----
    gemm_bf16_k<1><<<dim3(8, 32, 1), 256, 0, stream>>>(
        f1b, Wff2b, f2, nullptr, nullptr, nullptr, bff2,
        2048, 4096, 4096, 1024, 0, 0, 0LL, 0LL, 0LL, 0LL, 2097152LL);
    // ---- out = LN(f2a + f2b + h), two-pass transposed ----
    ln2_stats<<<dim3(1024, 2), 256, 0, stream>>>(f2, f2 + 2097152, h_bf, st2);
    ln2_write<<<dim3(32, 32, 2), 256, 0, stream>>>(f2, f2 + 2097152, h_bf, st2, out);
}

// Round 11
// 232.804 us; speedup vs baseline: 1.9107x; 1.0654x over previous
//
#include <hip/hip_runtime.h>

#define D_MODEL 1024
#define QLEN 1024

typedef __bf16 bf16x8 __attribute__((ext_vector_type(8)));
typedef __bf16 bf16x4 __attribute__((ext_vector_type(4)));
typedef float f32x4 __attribute__((ext_vector_type(4)));

__device__ __forceinline__ void gload16(const void* g, void* l) {
    __builtin_amdgcn_global_load_lds(
        (const __attribute__((address_space(1))) void*)g,
        (__attribute__((address_space(3))) void*)l, 16, 0, 0);
}

// ============ GEMM core: C tile (BM=MT*32 x 128) at (m0,n0) = A @ Bt^T, double-buffered ============
// MT=2: LDS = 2*(64*64 + 128*64)*2B = 48KB -> 3 blocks/CU (latency-bound regime: TLP > intensity)
template<int MT>
__device__ __forceinline__ void gemm_core(
    __bf16* __restrict__ smA, __bf16* __restrict__ smB,
    const __bf16* __restrict__ A, const __bf16* __restrict__ Bt,
    float* __restrict__ C, __bf16* __restrict__ Cb,
    const float* __restrict__ U, const __bf16* __restrict__ Ub,
    const float* __restrict__ bias,
    int K, int lda, int ldb, int ldC, int ldU, int relu, int m0, int n0)
{
    const int t = threadIdx.x;
    const int lane = t & 63, w = t >> 6;
    const int l15 = lane & 15, lg = lane >> 4;
    const int wm = w >> 1, wn = w & 1;
    const int srow = lane >> 3, cpr = lane & 7;
    const int NK = K >> 6;
    const int ASZ = MT * 32 * 64;
    const int BSZ = 128 * 64;

    #define STAGE(buf, kt)                                                                   \
    {                                                                                        \
        int k0s = (kt) * 64;                                                                 \
        _Pragma("unroll")                                                                    \
        for (int i = 0; i < MT; ++i) {                                                       \
            int r = i * 32 + w * 8 + srow;                                                   \
            int c = cpr ^ (r & 7);                                                           \
            gload16(&A[(long long)(m0 + r) * lda + k0s + c * 8],                             \
                    &smA[(buf) * ASZ + (i * 32 + w * 8) * 64]);                              \
        }                                                                                    \
        _Pragma("unroll")                                                                    \
        for (int i = 0; i < 4; ++i) {                                                        \
            int r = i * 32 + w * 8 + srow;                                                   \
            int c = cpr ^ (r & 7);                                                           \
            gload16(&Bt[(long long)(n0 + r) * ldb + k0s + c * 8],                            \
                    &smB[(buf) * BSZ + (i * 32 + w * 8) * 64]);                              \
        }                                                                                    \
    }

    f32x4 acc[MT][4] = {};
    STAGE(0, 0);

    for (int kt = 0; kt < NK; ++kt) {
        const int cb = kt & 1;
        if (kt + 1 < NK) {
            STAGE(cb ^ 1, kt + 1);
            if constexpr (MT == 4) asm volatile("s_waitcnt vmcnt(8)" ::: "memory");
            else                   asm volatile("s_waitcnt vmcnt(6)" ::: "memory");
        } else {
            asm volatile("s_waitcnt vmcnt(0)" ::: "memory");
        }
        __builtin_amdgcn_sched_barrier(0);
        __builtin_amdgcn_s_barrier();

        #pragma unroll
        for (int kk = 0; kk < 2; ++kk) {
            bf16x8 bfr[4];
            #pragma unroll
            for (int nt = 0; nt < 4; ++nt) {
                int nr = wn * 64 + nt * 16 + l15;
                bfr[nt] = *(const bf16x8*)&smB[cb * BSZ + nr * 64 + (((kk * 4 + lg) ^ (nr & 7)) * 8)];
            }
            #pragma unroll
            for (int mt = 0; mt < MT; ++mt) {
                int mr = wm * (MT * 16) + mt * 16 + l15;
                bf16x8 afr = *(const bf16x8*)&smA[cb * ASZ + mr * 64 + (((kk * 4 + lg) ^ (mr & 7)) * 8)];
                #pragma unroll
                for (int nt = 0; nt < 4; ++nt)
                    acc[mt][nt] = __builtin_amdgcn_mfma_f32_16x16x32_bf16(afr, bfr[nt], acc[mt][nt], 0, 0, 0);
            }
        }
        asm volatile("s_waitcnt lgkmcnt(0)" ::: "memory");
        __builtin_amdgcn_sched_barrier(0);
        __builtin_amdgcn_s_barrier();
    }
    #undef STAGE

    #pragma unroll
    for (int mt = 0; mt < MT; ++mt) {
        #pragma unroll
        for (int nt = 0; nt < 4; ++nt) {
            #pragma unroll
            for (int rg = 0; rg < 4; ++rg) {
                int m = m0 + wm * (MT * 16) + mt * 16 + lg * 4 + rg;
                int n = n0 + wn * 64 + nt * 16 + l15;
                float v = acc[mt][nt][rg];
                if (U)    v += U[(long long)m * ldU + n];
                if (Ub)   v += (float)Ub[(long long)m * ldU + n];
                if (bias) v += bias[n];
                if (relu) v = fmaxf(v, 0.0f);
                if (Cb) Cb[(long long)m * ldC + n] = (__bf16)v;
                else    C [(long long)m * ldC + n] = v;
            }
        }
    }
}

// ============ generic wrapper (MT=2), optional K-split ============
template<int KS>
__global__ __launch_bounds__(256) void gemm_bf16_k(
    const __bf16* __restrict__ A, const __bf16* __restrict__ Bt,
    float* __restrict__ C, __bf16* __restrict__ Cb,
    const float* __restrict__ U, const __bf16* __restrict__ Ub,
    const float* __restrict__ bias,
    int K, int lda, int ldb, int ldC, int ldU, int relu,
    long long sA, long long sB, long long sC, long long sU, long long sSplit)
{
    __shared__ __bf16 SM[24576];
    const int bz = blockIdx.z;
    int yb = blockIdx.y;
    int half = 0;
    if (KS) { half = yb & 1; yb >>= 1; }
    A  += (long long)bz * sA + (long long)half * K;
    Bt += (long long)bz * sB + (long long)half * K;
    if (C)  C  += (long long)bz * sC + (long long)half * sSplit;
    if (Cb) Cb += (long long)bz * sC;
    if (U)  U  += (long long)bz * sU;
    if (Ub) Ub += (long long)bz * sU;
    if (KS && half) { bias = nullptr; U = nullptr; Ub = nullptr; }
    gemm_core<2>(SM, SM + 8192, A, Bt, C, Cb, U, Ub, bias,
                 K, lda, ldb, ldC, ldU, relu, yb * 64, blockIdx.x * 128);
}

// ============ fused 3-job GEMM (MT=2): qkT (1024) + wh_v (512) + rkT (144) ============
__global__ __launch_bounds__(256) void gemm_fused3(
    const __bf16* __restrict__ cat_t, const __bf16* __restrict__ Wqkvb,
    __bf16* __restrict__ qkT, const __bf16* __restrict__ uqkT,
    __bf16* __restrict__ wh_v, const float* __restrict__ uv,
    const __bf16* __restrict__ pos_t, const __bf16* __restrict__ Wrb,
    __bf16* __restrict__ rkT)
{
    __shared__ __bf16 SM[24576];
    int bid = blockIdx.x;
    if (bid < 1024) {            // qkT: M=2048 (y 0..31), N=2048 (x 0..15), z=2
        int zz = bid >> 9, rem = bid & 511, y = rem >> 4, x = rem & 15;
        gemm_core<2>(SM, SM + 8192,
                     cat_t + (long long)zz * 2097152, Wqkvb,
                     nullptr, qkT + (long long)zz * 4194304,
                     nullptr, uqkT + (long long)zz * 4194304, nullptr,
                     1024, 1024, 1024, 2048, 2048, 0, y * 64, x * 128);
    } else if (bid < 1536) {     // wh_v: M=1024 (y 0..15), N=2048 (x 0..15), z=2
        int l = bid - 1024, zz = l >> 8, rem = l & 255, y = rem >> 4, x = rem & 15;
        gemm_core<2>(SM, SM + 8192,
                     Wqkvb + 2048 * 1024, cat_t + (long long)zz * 2097152,
                     nullptr, wh_v + (long long)zz * 2097152,
                     uv + (long long)zz * 6291456, nullptr, nullptr,
                     1024, 1024, 1024, 2048, 2048, 0, y * 64, x * 128);
    } else {                     // rkT: M=1152 (y 0..17), N=1024 (x 0..7)
        int l = bid - 1536, y = l >> 3, x = l & 7;
        gemm_core<2>(SM, SM + 8192,
                     pos_t + 960 * 1024, Wrb,
                     nullptr, rkT, nullptr, nullptr, nullptr,
                     1024, 1024, 1024, 1024, 0, 0, y * 64, x * 128);
    }
}

// ============ fused prep: weight converts + 4 transposes + pos pad ============
__global__ __launch_bounds__(256) void prep_all(
    const float* __restrict__ Wqkv, __bf16* __restrict__ Wqkvb,
    const float* __restrict__ Wr,   __bf16* __restrict__ Wrb,
    const float* __restrict__ Wo,   __bf16* __restrict__ Wob,
    const float* __restrict__ Wff1, __bf16* __restrict__ Wff1b,
    const float* __restrict__ Wff2, __bf16* __restrict__ Wff2b,
    const float* __restrict__ zh, const float* __restrict__ z, __bf16* __restrict__ cat_t,
    const float* __restrict__ pos, __bf16* __restrict__ pos_t,
    const float* __restrict__ u, __bf16* __restrict__ uqkT)
{
    __shared__ float ts[32][33];
    int bid = blockIdx.x;
    const int t = threadIdx.x;
    if (bid < 13312) {   // weight converts
        long long i = ((long long)bid * 256 + t) * 4;
        const float* s; __bf16* dd;
        if (i < 3145728)                    { s = Wqkv + i; dd = Wqkvb + i; }
        else if ((i -= 3145728) < 1048576)  { s = Wr + i;   dd = Wrb + i; }
        else if ((i -= 1048576) < 1048576)  { s = Wo + i;   dd = Wob + i; }
        else if ((i -= 1048576) < 4194304)  { s = Wff1 + i; dd = Wff1b + i; }
        else { i -= 4194304;                  s = Wff2 + i; dd = Wff2b + i; }
        float4 v = *(const float4*)s;
        bf16x4 o = { (__bf16)v.x, (__bf16)v.y, (__bf16)v.z, (__bf16)v.w };
        *(bf16x4*)dd = o;
        return;
    }
    bid -= 13312;
    const float* S; __bf16* D; int R, Cc, bx, by;
    if (bid < 2048) {            // zh -> cat_t[:, 0:1024]
        int zz = bid >> 10, r2 = bid & 1023;
        S = zh + (long long)zz * 1048576; D = cat_t + (long long)zz * 2097152;
        R = 1024; Cc = 1024; bx = r2 & 31; by = r2 >> 5;
    } else if (bid < 4096) {     // z -> cat_t[:, 1024:2048]
        int l = bid - 2048; int zz = l >> 10, r2 = l & 1023;
        S = z + (long long)zz * 1048576; D = cat_t + 1048576 + (long long)zz * 2097152;
        R = 1024; Cc = 1024; bx = r2 & 31; by = r2 >> 5;
    } else if (bid < 6144) {     // pos -> pos_t
        int l = bid - 4096;
        S = pos; D = pos_t; R = 1024; Cc = 2048; bx = l & 63; by = l >> 6;
    } else if (bid < 14336) {    // u QK-part -> uqkT
        int l = bid - 6144; int zz = l >> 12, r2 = l & 4095;
        S = u + (long long)zz * 6291456; D = uqkT + (long long)zz * 4194304;
        R = 2048; Cc = 2048; bx = r2 & 63; by = r2 >> 6;
    } else {                     // pad pos_t rows [2048,2112)
        int l = bid - 14336;
        int i = (l * 256 + t) * 4;
        bf16x4 zv = { (__bf16)0.f, (__bf16)0.f, (__bf16)0.f, (__bf16)0.f };
        *(bf16x4*)&pos_t[2048 * 1024 + i] = zv;
        return;
    }
    int r0 = by * 32, c0 = bx * 32;
    int tr = t >> 5, tc = t & 31;
    #pragma unroll
    for (int p = 0; p < 4; ++p)
        ts[tr + p * 8][tc] = S[(long long)(r0 + tr + p * 8) * Cc + c0 + tc];
    __syncthreads();
    #pragma unroll
    for (int p = 0; p < 4; ++p)
        D[(long long)(c0 + tr + p * 8) * R + r0 + tc] = (__bf16)ts[tc][tr + p * 8];
}

// ================= MFMA flash attention, 1-barrier pipelined =================
__global__ __launch_bounds__(256) void attn_mfma(
    const __bf16* __restrict__ QKT, const __bf16* __restrict__ WHV,
    const __bf16* __restrict__ RKT,
    const float* __restrict__ rwb, const float* __restrict__ rrb,
    __bf16* __restrict__ AVt)
{
    __shared__ __bf16 SM[38144];
    __bf16* KT0 = SM;
    __bf16* KT1 = SM + 4096;
    __bf16* VS0 = SM + 8192;
    __bf16* VS1 = SM + 12288;
    __bf16* RT  = SM + 16384;      // [192][64] sw ring
    __bf16* PS  = SM + 28672;
    __bf16* BT  = SM + 32768;      // per-wave [16][84]

    const int d = blockIdx.x;
    const int xcd = d & 7, idx = d >> 3;
    const int qt = idx & 15;
    const int gq = xcd + 8 * (idx >> 4);
    const int b = gq >> 4, n = gq & 15;
    const int i0 = qt * 64;

    const int t = threadIdx.x;
    const int lane = t & 63, w = t >> 6;
    const int l15 = lane & 15, lg = lane >> 4;
    const int fco = n * 64;

    const __bf16* qkb = QKT + (long long)b * (2048 * 2048);
    const __bf16* vb  = WHV + (long long)b * (1024 * 2048) + (long long)fco * 2048;
    __bf16* BTw = BT + w * 1344;

    #pragma unroll
    for (int pp = 0; pp < 2; ++pp) {
        int cid = pp * 256 + t;
        int q = cid >> 3, s = cid & 7, c = s ^ (q & 7);
        bf16x8 qv = *(const bf16x8*)&qkb[(long long)(1024 + i0 + q) * 2048 + fco + c * 8];
        bf16x8 ow, orr;
        #pragma unroll
        for (int e = 0; e < 8; ++e) {
            float qf = (float)qv[e];
            ow[e]  = (__bf16)(qf + rwb[fco + c * 8 + e]);
            orr[e] = (__bf16)(qf + rrb[fco + c * 8 + e]);
        }
        *(bf16x8*)&PS[q * 64 + s * 8] = ow;
        *(bf16x8*)&VS0[q * 64 + s * 8] = orr;
    }
    __syncthreads();

    #define LDF(buf, row, ch) (*(const bf16x8*)&(buf)[(row) * 64 + ((((ch) ^ ((row) & 7))) * 8)])

    const int mrow = w * 16 + l15;
    bf16x8 qw0 = LDF(PS, mrow, lg), qw1 = LDF(PS, mrow, lg + 4);
    bf16x8 qr0 = LDF(VS0, mrow, lg), qr1 = LDF(VS0, mrow, lg + 4);
    asm volatile("s_waitcnt lgkmcnt(0)" ::: "memory");
    __builtin_amdgcn_sched_barrier(0);
    __builtin_amdgcn_s_barrier();

    #pragma unroll
    for (int pp = 0; pp < 2; ++pp) {
        int cid = pp * 256 + t;
        int r = cid >> 3, s = cid & 7, c = s ^ (r & 7);
        gload16(&qkb[(long long)(i0 + r) * 2048 + 1024 + fco + c * 8], &KT0[(pp * 32 + w * 8) * 64]);
        gload16(&vb[(long long)r * 2048 + i0 + c * 8], &VS0[(pp * 32 + w * 8) * 64]);
    }
    #pragma unroll
    for (int pp = 0; pp < 6; ++pp) {
        int cid = pp * 256 + t;
        int r = cid >> 3, s = cid & 7, c = s ^ (r & 7);
        gload16(&RKT[(long long)r * 1024 + fco + c * 8], &RT[(pp * 32 + w * 8) * 64]);
    }
    asm volatile("s_waitcnt vmcnt(0)" ::: "memory");
    __builtin_amdgcn_sched_barrier(0);
    __builtin_amdgcn_s_barrier();

    const bf16x8 ones = { (__bf16)1.f, (__bf16)1.f, (__bf16)1.f, (__bf16)1.f,
                          (__bf16)1.f, (__bf16)1.f, (__bf16)1.f, (__bf16)1.f };

    f32x4 O0 = {}, O1 = {}, O2 = {}, O3 = {};
    float rm[4] = {-1e30f, -1e30f, -1e30f, -1e30f};
    float rl[4] = {0.f, 0.f, 0.f, 0.f};
    int cur = 0;

    for (int kt = 0; kt <= 16; ++kt) {
        __bf16* KTc = cur ? KT1 : KT0;
        __bf16* VSc = cur ? VS1 : VS0;
        __bf16* KTn = cur ? KT0 : KT1;
        __bf16* VSn = cur ? VS0 : VS1;
        const int rbase = (kt % 3) * 64;

        // (1) prefetches for kt+1
        if (kt < 16) {
            int j0n = i0 + (kt + 1) * 64;
            #pragma unroll
            for (int pp = 0; pp < 2; ++pp) {
                int cid = pp * 256 + t;
                int r = cid >> 3, s = cid & 7, c = s ^ (r & 7);
                gload16(&qkb[(long long)(j0n + r) * 2048 + 1024 + fco + c * 8], &KTn[(pp * 32 + w * 8) * 64]);
                gload16(&vb[(long long)r * 2048 + j0n + c * 8], &VSn[(pp * 32 + w * 8) * 64]);
            }
            int rb = kt * 64 + 128;
            int lb = ((kt + 2) % 3) * 64;
            #pragma unroll
            for (int pp = 0; pp < 2; ++pp) {
                int cid = pp * 256 + t;
                int r = cid >> 3, s = cid & 7, c = s ^ (r & 7);
                gload16(&RKT[(long long)(rb + r) * 1024 + fco + c * 8], &RT[(lb + pp * 32 + w * 8) * 64]);
            }
        }
        __builtin_amdgcn_sched_barrier(0);

        // (2) BD: 5 p-tiles -> per-wave BT
        __builtin_amdgcn_s_setprio(1);
        #pragma unroll
        for (int k5 = 0; k5 < 5; ++k5) {
            int pr = (3 - w + k5) * 16 + l15;
            int lr = rbase + pr; if (lr >= 192) lr -= 192;
            const __bf16* rrow = &RT[lr * 64];
            f32x4 cc = {};
            cc = __builtin_amdgcn_mfma_f32_16x16x32_bf16(qr0, *(const bf16x8*)&rrow[((lg ^ (pr & 7)) * 8)], cc, 0, 0, 0);
            cc = __builtin_amdgcn_mfma_f32_16x16x32_bf16(qr1, *(const bf16x8*)&rrow[(((lg + 4) ^ (pr & 7)) * 8)], cc, 0, 0, 0);
            #pragma unroll
            for (int rg = 0; rg < 4; ++rg)
                BTw[(lg * 4 + rg) * 84 + k5 * 16 + l15] = (__bf16)cc[rg];
        }
        __builtin_amdgcn_s_setprio(0);

        // (3) AC MFMAs -> cc4
        f32x4 cc4[4];
        __builtin_amdgcn_s_setprio(1);
        #pragma unroll
        for (int nt = 0; nt < 4; ++nt) {
            int jr = nt * 16 + l15;
            f32x4 cc = {};
            cc = __builtin_amdgcn_mfma_f32_16x16x32_bf16(qw0, LDF(KTc, jr, lg), cc, 0, 0, 0);
            cc = __builtin_amdgcn_mfma_f32_16x16x32_bf16(qw1, LDF(KTc, jr, lg + 4), cc, 0, 0, 0);
            cc4[nt] = cc;
        }
        __builtin_amdgcn_s_setprio(0);

        // score assembly: interior iterations (kt 2..15) are provably mask-free
        const bool bnd = (kt < 2) | (kt == 16);
        float sv[4][4];
        if (!bnd) {
            #pragma unroll
            for (int nt = 0; nt < 4; ++nt) {
                int jr = nt * 16 + l15;
                #pragma unroll
                for (int rg = 0; rg < 4; ++rg) {
                    int r4 = lg * 4 + rg;
                    sv[nt][rg] = (cc4[nt][rg] + (float)BTw[r4 * 84 + jr - r4 + 15]) * 0.125f;
                }
            }
        } else {
            #pragma unroll
            for (int nt = 0; nt < 4; ++nt) {
                int jr = nt * 16 + l15;
                #pragma unroll
                for (int rg = 0; rg < 4; ++rg) {
                    int r4 = lg * 4 + rg;
                    int dji = jr - (w * 16 + r4);
                    float s = (cc4[nt][rg] + (float)BTw[r4 * 84 + jr - r4 + 15]) * 0.125f;
                    bool valid = (kt == 0) ? (dji >= 25)
                               : (kt == 1) ? (dji >= -39)
                               : (dji <= 0);
                    sv[nt][rg] = valid ? s : -1e30f;
                }
            }
        }

        // (4) defer-max (lane-local trigger)
        float lmax[4];
        bool need = false;
        #pragma unroll
        for (int rg = 0; rg < 4; ++rg) {
            lmax[rg] = fmaxf(fmaxf(sv[0][rg], sv[1][rg]), fmaxf(sv[2][rg], sv[3][rg]));
            need = need || (lmax[rg] > rm[rg] + 8.0f);
        }
        if (__any(need)) {
            #pragma unroll
            for (int rg = 0; rg < 4; ++rg) {
                float m = lmax[rg];
                m = fmaxf(m, __shfl_xor(m, 1, 16));
                m = fmaxf(m, __shfl_xor(m, 2, 16));
                m = fmaxf(m, __shfl_xor(m, 4, 16));
                m = fmaxf(m, __shfl_xor(m, 8, 16));
                float nm = fmaxf(rm[rg], m);
                float fac = __expf(rm[rg] - nm);
                rm[rg] = nm;
                rl[rg] *= fac;
                O0[rg] *= fac; O1[rg] *= fac; O2[rg] *= fac; O3[rg] *= fac;
            }
        }

        // (5) exp + write P (guard only on boundary iterations)
        if (!bnd) {
            #pragma unroll
            for (int nt = 0; nt < 4; ++nt) {
                int jc = nt * 16 + l15;
                #pragma unroll
                for (int rg = 0; rg < 4; ++rg) {
                    float p = __expf(sv[nt][rg] - rm[rg]);
                    int row = w * 16 + lg * 4 + rg;
                    PS[row * 64 + (((jc >> 3) ^ (row & 7)) * 8) + (jc & 7)] = (__bf16)p;
                }
            }
        } else {
            #pragma unroll
            for (int nt = 0; nt < 4; ++nt) {
                int jc = nt * 16 + l15;
                #pragma unroll
                for (int rg = 0; rg < 4; ++rg) {
                    float p = (sv[nt][rg] > -1e29f) ? __expf(sv[nt][rg] - rm[rg]) : 0.0f;
                    int row = w * 16 + lg * 4 + rg;
                    PS[row * 64 + (((jc >> 3) ^ (row & 7)) * 8) + (jc & 7)] = (__bf16)p;
                }
            }
        }

        // (6) PV + row-sum via all-ones MFMA
        bf16x8 pa0 = LDF(PS, mrow, lg), pa1 = LDF(PS, mrow, lg + 4);
        f32x4 Os = {};
        __builtin_amdgcn_s_setprio(1);
        Os = __builtin_amdgcn_mfma_f32_16x16x32_bf16(pa0, ones, Os, 0, 0, 0);
        Os = __builtin_amdgcn_mfma_f32_16x16x32_bf16(pa1, ones, Os, 0, 0, 0);
        O0 = __builtin_amdgcn_mfma_f32_16x16x32_bf16(pa0, LDF(VSc,  0 + l15, lg),     O0, 0, 0, 0);
        O0 = __builtin_amdgcn_mfma_f32_16x16x32_bf16(pa1, LDF(VSc,  0 + l15, lg + 4), O0, 0, 0, 0);
        O1 = __builtin_amdgcn_mfma_f32_16x16x32_bf16(pa0, LDF(VSc, 16 + l15, lg),     O1, 0, 0, 0);
        O1 = __builtin_amdgcn_mfma_f32_16x16x32_bf16(pa1, LDF(VSc, 16 + l15, lg + 4), O1, 0, 0, 0);
        O2 = __builtin_amdgcn_mfma_f32_16x16x32_bf16(pa0, LDF(VSc, 32 + l15, lg),     O2, 0, 0, 0);
        O2 = __builtin_amdgcn_mfma_f32_16x16x32_bf16(pa1, LDF(VSc, 32 + l15, lg + 4), O2, 0, 0, 0);
        O3 = __builtin_amdgcn_mfma_f32_16x16x32_bf16(pa0, LDF(VSc, 48 + l15, lg),     O3, 0, 0, 0);
        O3 = __builtin_amdgcn_mfma_f32_16x16x32_bf16(pa1, LDF(VSc, 48 + l15, lg + 4), O3, 0, 0, 0);
        __builtin_amdgcn_s_setprio(0);
        #pragma unroll
        for (int rg = 0; rg < 4; ++rg) rl[rg] += Os[rg];

        // (7) single end-of-iter drain + barrier
        asm volatile("s_waitcnt vmcnt(0)" ::: "memory");
        __builtin_amdgcn_sched_barrier(0);
        __builtin_amdgcn_s_barrier();
        cur ^= 1;
    }

    #pragma unroll
    for (int rg = 0; rg < 4; ++rg) {
        float inv = 1.0f / rl[rg];
        int q = i0 + w * 16 + lg * 4 + rg;
        long long base = ((long long)b * 1024 + q) * 1024 + fco;
        AVt[base +  0 + l15] = (__bf16)(O0[rg] * inv);
        AVt[base + 16 + l15] = (__bf16)(O1[rg] * inv);
        AVt[base + 32 + l15] = (__bf16)(O2[rg] * inv);
        AVt[base + 48 + l15] = (__bf16)(O3[rg] * inv);
    }
    #undef LDF
}

// ================= LN1 =================
__global__ __launch_bounds__(256) void ln1_kernel(
    const float* __restrict__ AO, const float* __restrict__ AO2,
    const float* __restrict__ bo, const __bf16* __restrict__ CatT,
    __bf16* __restrict__ Hb)
{
    int i = blockIdx.x, b = blockIdx.y, t = threadIdx.x;
    __shared__ float xs[D_MODEL];
    __shared__ float red[256];
    __shared__ float smu, srstd;
    long long tb = ((long long)b * 1024 + i) * 1024;
    long long zb = ((long long)b * 2048 + 1024 + i) * 1024;

    float lsum = 0.0f;
    for (int dd = t; dd < D_MODEL; dd += 256) {
        float v = AO[tb + dd] + AO2[tb + dd] + bo[dd] + (float)CatT[zb + dd];
        xs[dd] = v;
        lsum += v;
    }
    red[t] = lsum; __syncthreads();
    for (int s2 = 128; s2 > 0; s2 >>= 1) { if (t < s2) red[t] += red[t + s2]; __syncthreads(); }
    if (t == 0) smu = red[0] * (1.0f / D_MODEL);
    __syncthreads();
    float mu = smu;

    float lq = 0.0f;
    for (int dd = t; dd < D_MODEL; dd += 256) { float c = xs[dd] - mu; lq += c * c; }
    red[t] = lq; __syncthreads();
    for (int s2 = 128; s2 > 0; s2 >>= 1) { if (t < s2) red[t] += red[t + s2]; __syncthreads(); }
    if (t == 0) srstd = rsqrtf(red[0] * (1.0f / D_MODEL) + 1e-5f);
    __syncthreads();
    float rstd = srstd;

    for (int dd = t; dd < D_MODEL; dd += 256)
        Hb[tb + dd] = (__bf16)((xs[dd] - mu) * rstd);
}

// ================= LN2 stats =================
__global__ __launch_bounds__(256) void ln2_stats(
    const float* __restrict__ F2a, const float* __restrict__ F2b,
    const __bf16* __restrict__ Hb, float2* __restrict__ st)
{
    int i = blockIdx.x, b = blockIdx.y, t = threadIdx.x;
    __shared__ float rs[256], rq[256];
    long long tb = ((long long)b * 1024 + i) * 1024;

    float s = 0.f, q = 0.f;
    for (int dd = t; dd < D_MODEL; dd += 256) {
        float v = F2a[tb + dd] + F2b[tb + dd] + (float)Hb[tb + dd];
        s += v; q += v * v;
    }
    rs[t] = s; rq[t] = q; __syncthreads();
    for (int s2 = 128; s2 > 0; s2 >>= 1) {
        if (t < s2) { rs[t] += rs[t + s2]; rq[t] += rq[t + s2]; }
        __syncthreads();
    }
    if (t == 0) {
        float mu = rs[0] * (1.0f / D_MODEL);
        float var = rq[0] * (1.0f / D_MODEL) - mu * mu;
        st[(long long)b * 1024 + i] = make_float2(mu, rsqrtf(var + 1e-5f));
    }
}

// ================= LN2 transposed write =================
__global__ __launch_bounds__(256) void ln2_write(
    const float* __restrict__ F2a, const float* __restrict__ F2b,
    const __bf16* __restrict__ Hb, const float2* __restrict__ st,
    float* __restrict__ OUT)
{
    __shared__ float ts[32][33];
    int f0 = blockIdx.x * 32, i0 = blockIdx.y * 32, b = blockIdx.z;
    int tr = threadIdx.x >> 5, tc = threadIdx.x & 31;
    #pragma unroll
    for (int p = 0; p < 4; ++p) {
        int tok = i0 + tr + p * 8;
        long long tb = ((long long)b * 1024 + tok) * 1024;
        float2 s = st[(long long)b * 1024 + tok];
        float v = F2a[tb + f0 + tc] + F2b[tb + f0 + tc] + (float)Hb[tb + f0 + tc];
        ts[tr + p * 8][tc] = (v - s.x) * s.y;
    }
    __syncthreads();
    #pragma unroll
    for (int p = 0; p < 4; ++p)
        OUT[((long long)b * 1024 + f0 + tr + p * 8) * 1024 + i0 + tc] = ts[tc][tr + p * 8];
}

// ================= launch =================
extern "C" void kernel_launch(void* const* d_in, const int* in_sizes, int n_in,
                              void* d_out, int out_size, void* d_ws, size_t ws_size,
                              hipStream_t stream) {
    const float* z    = (const float*)d_in[0];
    const float* zh   = (const float*)d_in[1];
    const float* u    = (const float*)d_in[2];
    const float* pos  = (const float*)d_in[3];
    const float* Wqkv = (const float*)d_in[4];
    const float* Wr   = (const float*)d_in[5];
    const float* rwb  = (const float*)d_in[6];
    const float* rrb  = (const float*)d_in[7];
    const float* Wo   = (const float*)d_in[8];
    const float* bo   = (const float*)d_in[9];
    const float* Wff1 = (const float*)d_in[10];
    const float* bff1 = (const float*)d_in[11];
    const float* Wff2 = (const float*)d_in[12];
    const float* bff2 = (const float*)d_in[13];
    float* out = (float*)d_out;
    float* ws  = (float*)d_ws;

    // ---- workspace (f32-slot offsets) ----
    __bf16* cat_t = (__bf16*)ws;                         // [2][2048][1024]
    __bf16* pos_t = (__bf16*)(ws + 2097152);             // [2112][1024]
    __bf16* Wqkvb = (__bf16*)(ws + 3178496);
    __bf16* Wrb   = (__bf16*)(ws + 4751360);
    __bf16* Wob   = (__bf16*)(ws + 5275648);
    __bf16* Wff1b = (__bf16*)(ws + 5799936);
    __bf16* Wff2b = (__bf16*)(ws + 7897088);
    __bf16* uqkT  = (__bf16*)(ws + 9994240);             // [2][2048][2048]
    __bf16* qkT   = (__bf16*)(ws + 14188544);            // [2][2048][2048]
    __bf16* wh_v  = (__bf16*)(ws + 18382848);            // [2][1024][2048]
    __bf16* rkT   = (__bf16*)(ws + 20480000);            // [1152][1024]
    __bf16* av_t  = (__bf16*)(ws + 21069824);            // [2][1024][1024]
    float*  ao    = ws + 22118400;                       // [2 halves][2048][1024]
    __bf16* h_bf  = (__bf16*)(ws + 26312704);            // [2048][1024]
    float2* st2   = (float2*)(ws + 27361280);            // [2][1024] float2
    __bf16* f1b   = (__bf16*)(ws + 14188544);            // overlays qkT (dead after attn)
    float*  f2    = ws + 9994240;                        // overlays uqkT (dead after qkT GEMM)

    // ---- fused prep (converts + transposes + pad) ----
    prep_all<<<27712, 256, 0, stream>>>(
        Wqkv, Wqkvb, Wr, Wrb, Wo, Wob, Wff1, Wff1b, Wff2, Wff2b,
        zh, z, cat_t, pos, pos_t, u, uqkT);

    // ---- fused qkT + wh_v + rkT GEMMs (MT=2, 3 blocks/CU) ----
    gemm_fused3<<<1680, 256, 0, stream>>>(
        cat_t, Wqkvb, qkT, uqkT, wh_v, u + 4194304, pos_t, Wrb, rkT);

    // ---- attention -> av_t ----
    attn_mfma<<<512, 256, 0, stream>>>(qkT, wh_v, rkT, rwb, rrb, av_t);

    // ---- ao_t partials = av_t @ Wo^T (K-split 2x512, MT=2) ----
    gemm_bf16_k<1><<<dim3(8, 64, 1), 256, 0, stream>>>(
        av_t, Wob, ao, nullptr, nullptr, nullptr, nullptr,
        512, 1024, 1024, 1024, 0, 0, 0LL, 0LL, 0LL, 0LL, 2097152LL);
    // ---- h = LN(ao_a + ao_b + bo + z) ----
    ln1_kernel<<<dim3(1024, 2), 256, 0, stream>>>(ao, ao + 2097152, bo, cat_t, h_bf);
    // ---- f1 = relu(h @ Wff1^T + bff1) (MT=2) ----
    gemm_bf16_k<0><<<dim3(32, 32, 1), 256, 0, stream>>>(
        h_bf, Wff1b, nullptr, f1b, nullptr, nullptr, bff1,
        1024, 1024, 1024, 4096, 0, 1, 0LL, 0LL, 0LL, 0LL, 0LL);
    // ---- f2 partials = f1 @ Wff2^T + bff2 (K-split 2x2048, MT=2) ----
    gemm_bf16_k<1><<<dim3(8, 64, 1), 256, 0, stream>>>(
        f1b, Wff2b, f2, nullptr, nullptr, nullptr, bff2,
        2048, 4096, 4096, 1024, 0, 0, 0LL, 0LL, 0LL, 0LL, 2097152LL);
    // ---- out = LN(f2a + f2b + h), two-pass transposed ----
    ln2_stats<<<dim3(1024, 2), 256, 0, stream>>>(f2, f2 + 2097152, h_bf, st2);
    ln2_write<<<dim3(32, 32, 2), 256, 0, stream>>>(f2, f2 + 2097152, h_bf, st2, out);
}

// Round 12
// 218.110 us; speedup vs baseline: 2.0395x; 1.0674x over previous
//
#include <hip/hip_runtime.h>

#define D_MODEL 1024
#define QLEN 1024

typedef __bf16 bf16x8 __attribute__((ext_vector_type(8)));
typedef __bf16 bf16x4 __attribute__((ext_vector_type(4)));
typedef float f32x4 __attribute__((ext_vector_type(4)));

__device__ __forceinline__ void gload16(const void* g, void* l) {
    __builtin_amdgcn_global_load_lds(
        (const __attribute__((address_space(1))) void*)g,
        (__attribute__((address_space(3))) void*)l, 16, 0, 0);
}

// ============ GEMM core, 8 waves / 512 threads: C tile 128x128 at (m0,n0) ============
// wave tile 64x32 (4m x 2n frags). dbuf LDS 64KB -> 2 blocks/CU = 16 waves/CU.
// Per step/wave: 4 gloads (vmcnt(4) counted), 12 ds_read_b128, 16 MFMA.
__device__ __forceinline__ void gemm_core8(
    __bf16* __restrict__ smA, __bf16* __restrict__ smB,
    const __bf16* __restrict__ A, const __bf16* __restrict__ Bt,
    float* __restrict__ C, __bf16* __restrict__ Cb,
    const float* __restrict__ U, const __bf16* __restrict__ Ub,
    const float* __restrict__ bias,
    int K, int lda, int ldb, int ldC, int ldU, int relu, int m0, int n0)
{
    const int t = threadIdx.x;             // 0..511
    const int lane = t & 63, w = t >> 6;   // 8 waves
    const int l15 = lane & 15, lg = lane >> 4;
    const int wm = w >> 2, wn = w & 3;     // 2m x 4n wave grid
    const int srow = lane >> 3, cpr = lane & 7;
    const int NK = K >> 6;
    const int SZ = 128 * 64;

    #define STAGE(buf, kt)                                                                   \
    {                                                                                        \
        int k0s = (kt) * 64;                                                                 \
        _Pragma("unroll")                                                                    \
        for (int i = 0; i < 2; ++i) {                                                        \
            int r = w * 16 + i * 8 + srow;                                                   \
            int c = cpr ^ (r & 7);                                                           \
            gload16(&A[(long long)(m0 + r) * lda + k0s + c * 8],                             \
                    &smA[(buf) * SZ + (w * 16 + i * 8) * 64]);                               \
            gload16(&Bt[(long long)(n0 + r) * ldb + k0s + c * 8],                            \
                    &smB[(buf) * SZ + (w * 16 + i * 8) * 64]);                               \
        }                                                                                    \
    }

    f32x4 acc[4][2] = {};
    STAGE(0, 0);

    for (int kt = 0; kt < NK; ++kt) {
        const int cb = kt & 1;
        if (kt + 1 < NK) {
            STAGE(cb ^ 1, kt + 1);
            asm volatile("s_waitcnt vmcnt(4)" ::: "memory");
        } else {
            asm volatile("s_waitcnt vmcnt(0)" ::: "memory");
        }
        __builtin_amdgcn_sched_barrier(0);
        __builtin_amdgcn_s_barrier();

        #pragma unroll
        for (int kk = 0; kk < 2; ++kk) {
            bf16x8 bfr[2];
            #pragma unroll
            for (int nt = 0; nt < 2; ++nt) {
                int nr = wn * 32 + nt * 16 + l15;
                bfr[nt] = *(const bf16x8*)&smB[cb * SZ + nr * 64 + (((kk * 4 + lg) ^ (nr & 7)) * 8)];
            }
            #pragma unroll
            for (int mt = 0; mt < 4; ++mt) {
                int mr = wm * 64 + mt * 16 + l15;
                bf16x8 afr = *(const bf16x8*)&smA[cb * SZ + mr * 64 + (((kk * 4 + lg) ^ (mr & 7)) * 8)];
                #pragma unroll
                for (int nt = 0; nt < 2; ++nt)
                    acc[mt][nt] = __builtin_amdgcn_mfma_f32_16x16x32_bf16(afr, bfr[nt], acc[mt][nt], 0, 0, 0);
            }
        }
        asm volatile("s_waitcnt lgkmcnt(0)" ::: "memory");
        __builtin_amdgcn_sched_barrier(0);
        __builtin_amdgcn_s_barrier();
    }
    #undef STAGE

    #pragma unroll
    for (int mt = 0; mt < 4; ++mt) {
        #pragma unroll
        for (int nt = 0; nt < 2; ++nt) {
            #pragma unroll
            for (int rg = 0; rg < 4; ++rg) {
                int m = m0 + wm * 64 + mt * 16 + lg * 4 + rg;
                int n = n0 + wn * 32 + nt * 16 + l15;
                float v = acc[mt][nt][rg];
                if (U)    v += U[(long long)m * ldU + n];
                if (Ub)   v += (float)Ub[(long long)m * ldU + n];
                if (bias) v += bias[n];
                if (relu) v = fmaxf(v, 0.0f);
                if (Cb) Cb[(long long)m * ldC + n] = (__bf16)v;
                else    C [(long long)m * ldC + n] = v;
            }
        }
    }
}

// ============ generic wrapper (512 threads), optional K-split ============
template<int KS>
__global__ __launch_bounds__(512) void gemm_bf16_k(
    const __bf16* __restrict__ A, const __bf16* __restrict__ Bt,
    float* __restrict__ C, __bf16* __restrict__ Cb,
    const float* __restrict__ U, const __bf16* __restrict__ Ub,
    const float* __restrict__ bias,
    int K, int lda, int ldb, int ldC, int ldU, int relu,
    long long sA, long long sB, long long sC, long long sU, long long sSplit)
{
    __shared__ __bf16 SM[32768];
    const int bz = blockIdx.z;
    int yb = blockIdx.y;
    int half = 0;
    if (KS) { half = yb & 1; yb >>= 1; }
    A  += (long long)bz * sA + (long long)half * K;
    Bt += (long long)bz * sB + (long long)half * K;
    if (C)  C  += (long long)bz * sC + (long long)half * sSplit;
    if (Cb) Cb += (long long)bz * sC;
    if (U)  U  += (long long)bz * sU;
    if (Ub) Ub += (long long)bz * sU;
    if (KS && half) { bias = nullptr; U = nullptr; Ub = nullptr; }
    gemm_core8(SM, SM + 16384, A, Bt, C, Cb, U, Ub, bias,
               K, lda, ldb, ldC, ldU, relu, yb * 128, blockIdx.x * 128);
}

// ============ fused 3-job GEMM (8-wave 128x128): qkT (512) + wh_v (256) + rkT (72) ============
__global__ __launch_bounds__(512) void gemm_fused3(
    const __bf16* __restrict__ cat_t, const __bf16* __restrict__ Wqkvb,
    __bf16* __restrict__ qkT, const __bf16* __restrict__ uqkT,
    __bf16* __restrict__ wh_v, const float* __restrict__ uv,
    const __bf16* __restrict__ pos_t, const __bf16* __restrict__ Wrb,
    __bf16* __restrict__ rkT)
{
    __shared__ __bf16 SM[32768];
    int bid = blockIdx.x;
    if (bid < 512) {             // qkT: M=2048 (y 0..15), N=2048 (x 0..15), z=2
        int zz = bid >> 8, rem = bid & 255, y = rem >> 4, x = rem & 15;
        gemm_core8(SM, SM + 16384,
                   cat_t + (long long)zz * 2097152, Wqkvb,
                   nullptr, qkT + (long long)zz * 4194304,
                   nullptr, uqkT + (long long)zz * 4194304, nullptr,
                   1024, 1024, 1024, 2048, 2048, 0, y * 128, x * 128);
    } else if (bid < 768) {      // wh_v: M=1024 (y 0..7), N=2048 (x 0..15), z=2
        int l = bid - 512, zz = l >> 7, rem = l & 127, y = rem >> 4, x = rem & 15;
        gemm_core8(SM, SM + 16384,
                   Wqkvb + 2048 * 1024, cat_t + (long long)zz * 2097152,
                   nullptr, wh_v + (long long)zz * 2097152,
                   uv + (long long)zz * 6291456, nullptr, nullptr,
                   1024, 1024, 1024, 2048, 2048, 0, y * 128, x * 128);
    } else {                     // rkT: M=1152 (y 0..8), N=1024 (x 0..7)
        int l = bid - 768, y = l >> 3, x = l & 7;
        gemm_core8(SM, SM + 16384,
                   pos_t + 960 * 1024, Wrb,
                   nullptr, rkT, nullptr, nullptr, nullptr,
                   1024, 1024, 1024, 1024, 0, 0, y * 128, x * 128);
    }
}

// ============ fused prep: weight converts + 4 transposes + pos pad ============
__global__ __launch_bounds__(256) void prep_all(
    const float* __restrict__ Wqkv, __bf16* __restrict__ Wqkvb,
    const float* __restrict__ Wr,   __bf16* __restrict__ Wrb,
    const float* __restrict__ Wo,   __bf16* __restrict__ Wob,
    const float* __restrict__ Wff1, __bf16* __restrict__ Wff1b,
    const float* __restrict__ Wff2, __bf16* __restrict__ Wff2b,
    const float* __restrict__ zh, const float* __restrict__ z, __bf16* __restrict__ cat_t,
    const float* __restrict__ pos, __bf16* __restrict__ pos_t,
    const float* __restrict__ u, __bf16* __restrict__ uqkT)
{
    __shared__ float ts[32][33];
    int bid = blockIdx.x;
    const int t = threadIdx.x;
    if (bid < 13312) {   // weight converts
        long long i = ((long long)bid * 256 + t) * 4;
        const float* s; __bf16* dd;
        if (i < 3145728)                    { s = Wqkv + i; dd = Wqkvb + i; }
        else if ((i -= 3145728) < 1048576)  { s = Wr + i;   dd = Wrb + i; }
        else if ((i -= 1048576) < 1048576)  { s = Wo + i;   dd = Wob + i; }
        else if ((i -= 1048576) < 4194304)  { s = Wff1 + i; dd = Wff1b + i; }
        else { i -= 4194304;                  s = Wff2 + i; dd = Wff2b + i; }
        float4 v = *(const float4*)s;
        bf16x4 o = { (__bf16)v.x, (__bf16)v.y, (__bf16)v.z, (__bf16)v.w };
        *(bf16x4*)dd = o;
        return;
    }
    bid -= 13312;
    const float* S; __bf16* D; int R, Cc, bx, by;
    if (bid < 2048) {
        int zz = bid >> 10, r2 = bid & 1023;
        S = zh + (long long)zz * 1048576; D = cat_t + (long long)zz * 2097152;
        R = 1024; Cc = 1024; bx = r2 & 31; by = r2 >> 5;
    } else if (bid < 4096) {
        int l = bid - 2048; int zz = l >> 10, r2 = l & 1023;
        S = z + (long long)zz * 1048576; D = cat_t + 1048576 + (long long)zz * 2097152;
        R = 1024; Cc = 1024; bx = r2 & 31; by = r2 >> 5;
    } else if (bid < 6144) {
        int l = bid - 4096;
        S = pos; D = pos_t; R = 1024; Cc = 2048; bx = l & 63; by = l >> 6;
    } else if (bid < 14336) {
        int l = bid - 6144; int zz = l >> 12, r2 = l & 4095;
        S = u + (long long)zz * 6291456; D = uqkT + (long long)zz * 4194304;
        R = 2048; Cc = 2048; bx = r2 & 63; by = r2 >> 6;
    } else {
        int l = bid - 14336;
        int i = (l * 256 + t) * 4;
        bf16x4 zv = { (__bf16)0.f, (__bf16)0.f, (__bf16)0.f, (__bf16)0.f };
        *(bf16x4*)&pos_t[2048 * 1024 + i] = zv;
        return;
    }
    int r0 = by * 32, c0 = bx * 32;
    int tr = t >> 5, tc = t & 31;
    #pragma unroll
    for (int p = 0; p < 4; ++p)
        ts[tr + p * 8][tc] = S[(long long)(r0 + tr + p * 8) * Cc + c0 + tc];
    __syncthreads();
    #pragma unroll
    for (int p = 0; p < 4; ++p)
        D[(long long)(c0 + tr + p * 8) * R + r0 + tc] = (__bf16)ts[tc][tr + p * 8];
}

// ================= MFMA flash attention, 1-barrier pipelined (unchanged R11) =================
__global__ __launch_bounds__(256) void attn_mfma(
    const __bf16* __restrict__ QKT, const __bf16* __restrict__ WHV,
    const __bf16* __restrict__ RKT,
    const float* __restrict__ rwb, const float* __restrict__ rrb,
    __bf16* __restrict__ AVt)
{
    __shared__ __bf16 SM[38144];
    __bf16* KT0 = SM;
    __bf16* KT1 = SM + 4096;
    __bf16* VS0 = SM + 8192;
    __bf16* VS1 = SM + 12288;
    __bf16* RT  = SM + 16384;      // [192][64] sw ring
    __bf16* PS  = SM + 28672;
    __bf16* BT  = SM + 32768;      // per-wave [16][84]

    const int d = blockIdx.x;
    const int xcd = d & 7, idx = d >> 3;
    const int qt = idx & 15;
    const int gq = xcd + 8 * (idx >> 4);
    const int b = gq >> 4, n = gq & 15;
    const int i0 = qt * 64;

    const int t = threadIdx.x;
    const int lane = t & 63, w = t >> 6;
    const int l15 = lane & 15, lg = lane >> 4;
    const int fco = n * 64;

    const __bf16* qkb = QKT + (long long)b * (2048 * 2048);
    const __bf16* vb  = WHV + (long long)b * (1024 * 2048) + (long long)fco * 2048;
    __bf16* BTw = BT + w * 1344;

    #pragma unroll
    for (int pp = 0; pp < 2; ++pp) {
        int cid = pp * 256 + t;
        int q = cid >> 3, s = cid & 7, c = s ^ (q & 7);
        bf16x8 qv = *(const bf16x8*)&qkb[(long long)(1024 + i0 + q) * 2048 + fco + c * 8];
        bf16x8 ow, orr;
        #pragma unroll
        for (int e = 0; e < 8; ++e) {
            float qf = (float)qv[e];
            ow[e]  = (__bf16)(qf + rwb[fco + c * 8 + e]);
            orr[e] = (__bf16)(qf + rrb[fco + c * 8 + e]);
        }
        *(bf16x8*)&PS[q * 64 + s * 8] = ow;
        *(bf16x8*)&VS0[q * 64 + s * 8] = orr;
    }
    __syncthreads();

    #define LDF(buf, row, ch) (*(const bf16x8*)&(buf)[(row) * 64 + ((((ch) ^ ((row) & 7))) * 8)])

    const int mrow = w * 16 + l15;
    bf16x8 qw0 = LDF(PS, mrow, lg), qw1 = LDF(PS, mrow, lg + 4);
    bf16x8 qr0 = LDF(VS0, mrow, lg), qr1 = LDF(VS0, mrow, lg + 4);
    asm volatile("s_waitcnt lgkmcnt(0)" ::: "memory");
    __builtin_amdgcn_sched_barrier(0);
    __builtin_amdgcn_s_barrier();

    #pragma unroll
    for (int pp = 0; pp < 2; ++pp) {
        int cid = pp * 256 + t;
        int r = cid >> 3, s = cid & 7, c = s ^ (r & 7);
        gload16(&qkb[(long long)(i0 + r) * 2048 + 1024 + fco + c * 8], &KT0[(pp * 32 + w * 8) * 64]);
        gload16(&vb[(long long)r * 2048 + i0 + c * 8], &VS0[(pp * 32 + w * 8) * 64]);
    }
    #pragma unroll
    for (int pp = 0; pp < 6; ++pp) {
        int cid = pp * 256 + t;
        int r = cid >> 3, s = cid & 7, c = s ^ (r & 7);
        gload16(&RKT[(long long)r * 1024 + fco + c * 8], &RT[(pp * 32 + w * 8) * 64]);
    }
    asm volatile("s_waitcnt vmcnt(0)" ::: "memory");
    __builtin_amdgcn_sched_barrier(0);
    __builtin_amdgcn_s_barrier();

    const bf16x8 ones = { (__bf16)1.f, (__bf16)1.f, (__bf16)1.f, (__bf16)1.f,
                          (__bf16)1.f, (__bf16)1.f, (__bf16)1.f, (__bf16)1.f };

    f32x4 O0 = {}, O1 = {}, O2 = {}, O3 = {};
    float rm[4] = {-1e30f, -1e30f, -1e30f, -1e30f};
    float rl[4] = {0.f, 0.f, 0.f, 0.f};
    int cur = 0;

    for (int kt = 0; kt <= 16; ++kt) {
        __bf16* KTc = cur ? KT1 : KT0;
        __bf16* VSc = cur ? VS1 : VS0;
        __bf16* KTn = cur ? KT0 : KT1;
        __bf16* VSn = cur ? VS0 : VS1;
        const int rbase = (kt % 3) * 64;

        if (kt < 16) {
            int j0n = i0 + (kt + 1) * 64;
            #pragma unroll
            for (int pp = 0; pp < 2; ++pp) {
                int cid = pp * 256 + t;
                int r = cid >> 3, s = cid & 7, c = s ^ (r & 7);
                gload16(&qkb[(long long)(j0n + r) * 2048 + 1024 + fco + c * 8], &KTn[(pp * 32 + w * 8) * 64]);
                gload16(&vb[(long long)r * 2048 + j0n + c * 8], &VSn[(pp * 32 + w * 8) * 64]);
            }
            int rb = kt * 64 + 128;
            int lb = ((kt + 2) % 3) * 64;
            #pragma unroll
            for (int pp = 0; pp < 2; ++pp) {
                int cid = pp * 256 + t;
                int r = cid >> 3, s = cid & 7, c = s ^ (r & 7);
                gload16(&RKT[(long long)(rb + r) * 1024 + fco + c * 8], &RT[(lb + pp * 32 + w * 8) * 64]);
            }
        }
        __builtin_amdgcn_sched_barrier(0);

        __builtin_amdgcn_s_setprio(1);
        #pragma unroll
        for (int k5 = 0; k5 < 5; ++k5) {
            int pr = (3 - w + k5) * 16 + l15;
            int lr = rbase + pr; if (lr >= 192) lr -= 192;
            const __bf16* rrow = &RT[lr * 64];
            f32x4 cc = {};
            cc = __builtin_amdgcn_mfma_f32_16x16x32_bf16(qr0, *(const bf16x8*)&rrow[((lg ^ (pr & 7)) * 8)], cc, 0, 0, 0);
            cc = __builtin_amdgcn_mfma_f32_16x16x32_bf16(qr1, *(const bf16x8*)&rrow[(((lg + 4) ^ (pr & 7)) * 8)], cc, 0, 0, 0);
            #pragma unroll
            for (int rg = 0; rg < 4; ++rg)
                BTw[(lg * 4 + rg) * 84 + k5 * 16 + l15] = (__bf16)cc[rg];
        }
        __builtin_amdgcn_s_setprio(0);

        f32x4 cc4[4];
        __builtin_amdgcn_s_setprio(1);
        #pragma unroll
        for (int nt = 0; nt < 4; ++nt) {
            int jr = nt * 16 + l15;
            f32x4 cc = {};
            cc = __builtin_amdgcn_mfma_f32_16x16x32_bf16(qw0, LDF(KTc, jr, lg), cc, 0, 0, 0);
            cc = __builtin_amdgcn_mfma_f32_16x16x32_bf16(qw1, LDF(KTc, jr, lg + 4), cc, 0, 0, 0);
            cc4[nt] = cc;
        }
        __builtin_amdgcn_s_setprio(0);

        const bool bnd = (kt < 2) | (kt == 16);
        float sv[4][4];
        if (!bnd) {
            #pragma unroll
            for (int nt = 0; nt < 4; ++nt) {
                int jr = nt * 16 + l15;
                #pragma unroll
                for (int rg = 0; rg < 4; ++rg) {
                    int r4 = lg * 4 + rg;
                    sv[nt][rg] = (cc4[nt][rg] + (float)BTw[r4 * 84 + jr - r4 + 15]) * 0.125f;
                }
            }
        } else {
            #pragma unroll
            for (int nt = 0; nt < 4; ++nt) {
                int jr = nt * 16 + l15;
                #pragma unroll
                for (int rg = 0; rg < 4; ++rg) {
                    int r4 = lg * 4 + rg;
                    int dji = jr - (w * 16 + r4);
                    float s = (cc4[nt][rg] + (float)BTw[r4 * 84 + jr - r4 + 15]) * 0.125f;
                    bool valid = (kt == 0) ? (dji >= 25)
                               : (kt == 1) ? (dji >= -39)
                               : (dji <= 0);
                    sv[nt][rg] = valid ? s : -1e30f;
                }
            }
        }

        float lmax[4];
        bool need = false;
        #pragma unroll
        for (int rg = 0; rg < 4; ++rg) {
            lmax[rg] = fmaxf(fmaxf(sv[0][rg], sv[1][rg]), fmaxf(sv[2][rg], sv[3][rg]));
            need = need || (lmax[rg] > rm[rg] + 8.0f);
        }
        if (__any(need)) {
            #pragma unroll
            for (int rg = 0; rg < 4; ++rg) {
                float m = lmax[rg];
                m = fmaxf(m, __shfl_xor(m, 1, 16));
                m = fmaxf(m, __shfl_xor(m, 2, 16));
                m = fmaxf(m, __shfl_xor(m, 4, 16));
                m = fmaxf(m, __shfl_xor(m, 8, 16));
                float nm = fmaxf(rm[rg], m);
                float fac = __expf(rm[rg] - nm);
                rm[rg] = nm;
                rl[rg] *= fac;
                O0[rg] *= fac; O1[rg] *= fac; O2[rg] *= fac; O3[rg] *= fac;
            }
        }

        if (!bnd) {
            #pragma unroll
            for (int nt = 0; nt < 4; ++nt) {
                int jc = nt * 16 + l15;
                #pragma unroll
                for (int rg = 0; rg < 4; ++rg) {
                    float p = __expf(sv[nt][rg] - rm[rg]);
                    int row = w * 16 + lg * 4 + rg;
                    PS[row * 64 + (((jc >> 3) ^ (row & 7)) * 8) + (jc & 7)] = (__bf16)p;
                }
            }
        } else {
            #pragma unroll
            for (int nt = 0; nt < 4; ++nt) {
                int jc = nt * 16 + l15;
                #pragma unroll
                for (int rg = 0; rg < 4; ++rg) {
                    float p = (sv[nt][rg] > -1e29f) ? __expf(sv[nt][rg] - rm[rg]) : 0.0f;
                    int row = w * 16 + lg * 4 + rg;
                    PS[row * 64 + (((jc >> 3) ^ (row & 7)) * 8) + (jc & 7)] = (__bf16)p;
                }
            }
        }

        bf16x8 pa0 = LDF(PS, mrow, lg), pa1 = LDF(PS, mrow, lg + 4);
        f32x4 Os = {};
        __builtin_amdgcn_s_setprio(1);
        Os = __builtin_amdgcn_mfma_f32_16x16x32_bf16(pa0, ones, Os, 0, 0, 0);
        Os = __builtin_amdgcn_mfma_f32_16x16x32_bf16(pa1, ones, Os, 0, 0, 0);
        O0 = __builtin_amdgcn_mfma_f32_16x16x32_bf16(pa0, LDF(VSc,  0 + l15, lg),     O0, 0, 0, 0);
        O0 = __builtin_amdgcn_mfma_f32_16x16x32_bf16(pa1, LDF(VSc,  0 + l15, lg + 4), O0, 0, 0, 0);
        O1 = __builtin_amdgcn_mfma_f32_16x16x32_bf16(pa0, LDF(VSc, 16 + l15, lg),     O1, 0, 0, 0);
        O1 = __builtin_amdgcn_mfma_f32_16x16x32_bf16(pa1, LDF(VSc, 16 + l15, lg + 4), O1, 0, 0, 0);
        O2 = __builtin_amdgcn_mfma_f32_16x16x32_bf16(pa0, LDF(VSc, 32 + l15, lg),     O2, 0, 0, 0);
        O2 = __builtin_amdgcn_mfma_f32_16x16x32_bf16(pa1, LDF(VSc, 32 + l15, lg + 4), O2, 0, 0, 0);
        O3 = __builtin_amdgcn_mfma_f32_16x16x32_bf16(pa0, LDF(VSc, 48 + l15, lg),     O3, 0, 0, 0);
        O3 = __builtin_amdgcn_mfma_f32_16x16x32_bf16(pa1, LDF(VSc, 48 + l15, lg + 4), O3, 0, 0, 0);
        __builtin_amdgcn_s_setprio(0);
        #pragma unroll
        for (int rg = 0; rg < 4; ++rg) rl[rg] += Os[rg];

        asm volatile("s_waitcnt vmcnt(0)" ::: "memory");
        __builtin_amdgcn_sched_barrier(0);
        __builtin_amdgcn_s_barrier();
        cur ^= 1;
    }

    #pragma unroll
    for (int rg = 0; rg < 4; ++rg) {
        float inv = 1.0f / rl[rg];
        int q = i0 + w * 16 + lg * 4 + rg;
        long long base = ((long long)b * 1024 + q) * 1024 + fco;
        AVt[base +  0 + l15] = (__bf16)(O0[rg] * inv);
        AVt[base + 16 + l15] = (__bf16)(O1[rg] * inv);
        AVt[base + 32 + l15] = (__bf16)(O2[rg] * inv);
        AVt[base + 48 + l15] = (__bf16)(O3[rg] * inv);
    }
    #undef LDF
}

// ================= LN1 =================
__global__ __launch_bounds__(256) void ln1_kernel(
    const float* __restrict__ AO, const float* __restrict__ AO2,
    const float* __restrict__ bo, const __bf16* __restrict__ CatT,
    __bf16* __restrict__ Hb)
{
    int i = blockIdx.x, b = blockIdx.y, t = threadIdx.x;
    __shared__ float xs[D_MODEL];
    __shared__ float red[256];
    __shared__ float smu, srstd;
    long long tb = ((long long)b * 1024 + i) * 1024;
    long long zb = ((long long)b * 2048 + 1024 + i) * 1024;

    float lsum = 0.0f;
    for (int dd = t; dd < D_MODEL; dd += 256) {
        float v = AO[tb + dd] + AO2[tb + dd] + bo[dd] + (float)CatT[zb + dd];
        xs[dd] = v;
        lsum += v;
    }
    red[t] = lsum; __syncthreads();
    for (int s2 = 128; s2 > 0; s2 >>= 1) { if (t < s2) red[t] += red[t + s2]; __syncthreads(); }
    if (t == 0) smu = red[0] * (1.0f / D_MODEL);
    __syncthreads();
    float mu = smu;

    float lq = 0.0f;
    for (int dd = t; dd < D_MODEL; dd += 256) { float c = xs[dd] - mu; lq += c * c; }
    red[t] = lq; __syncthreads();
    for (int s2 = 128; s2 > 0; s2 >>= 1) { if (t < s2) red[t] += red[t + s2]; __syncthreads(); }
    if (t == 0) srstd = rsqrtf(red[0] * (1.0f / D_MODEL) + 1e-5f);
    __syncthreads();
    float rstd = srstd;

    for (int dd = t; dd < D_MODEL; dd += 256)
        Hb[tb + dd] = (__bf16)((xs[dd] - mu) * rstd);
}

// ================= LN2 stats =================
__global__ __launch_bounds__(256) void ln2_stats(
    const float* __restrict__ F2a, const float* __restrict__ F2b,
    const __bf16* __restrict__ Hb, float2* __restrict__ st)
{
    int i = blockIdx.x, b = blockIdx.y, t = threadIdx.x;
    __shared__ float rs[256], rq[256];
    long long tb = ((long long)b * 1024 + i) * 1024;

    float s = 0.f, q = 0.f;
    for (int dd = t; dd < D_MODEL; dd += 256) {
        float v = F2a[tb + dd] + F2b[tb + dd] + (float)Hb[tb + dd];
        s += v; q += v * v;
    }
    rs[t] = s; rq[t] = q; __syncthreads();
    for (int s2 = 128; s2 > 0; s2 >>= 1) {
        if (t < s2) { rs[t] += rs[t + s2]; rq[t] += rq[t + s2]; }
        __syncthreads();
    }
    if (t == 0) {
        float mu = rs[0] * (1.0f / D_MODEL);
        float var = rq[0] * (1.0f / D_MODEL) - mu * mu;
        st[(long long)b * 1024 + i] = make_float2(mu, rsqrtf(var + 1e-5f));
    }
}

// ================= LN2 transposed write =================
__global__ __launch_bounds__(256) void ln2_write(
    const float* __restrict__ F2a, const float* __restrict__ F2b,
    const __bf16* __restrict__ Hb, const float2* __restrict__ st,
    float* __restrict__ OUT)
{
    __shared__ float ts[32][33];
    int f0 = blockIdx.x * 32, i0 = blockIdx.y * 32, b = blockIdx.z;
    int tr = threadIdx.x >> 5, tc = threadIdx.x & 31;
    #pragma unroll
    for (int p = 0; p < 4; ++p) {
        int tok = i0 + tr + p * 8;
        long long tb = ((long long)b * 1024 + tok) * 1024;
        float2 s = st[(long long)b * 1024 + tok];
        float v = F2a[tb + f0 + tc] + F2b[tb + f0 + tc] + (float)Hb[tb + f0 + tc];
        ts[tr + p * 8][tc] = (v - s.x) * s.y;
    }
    __syncthreads();
    #pragma unroll
    for (int p = 0; p < 4; ++p)
        OUT[((long long)b * 1024 + f0 + tr + p * 8) * 1024 + i0 + tc] = ts[tc][tr + p * 8];
}

// ================= launch =================
extern "C" void kernel_launch(void* const* d_in, const int* in_sizes, int n_in,
                              void* d_out, int out_size, void* d_ws, size_t ws_size,
                              hipStream_t stream) {
    const float* z    = (const float*)d_in[0];
    const float* zh   = (const float*)d_in[1];
    const float* u    = (const float*)d_in[2];
    const float* pos  = (const float*)d_in[3];
    const float* Wqkv = (const float*)d_in[4];
    const float* Wr   = (const float*)d_in[5];
    const float* rwb  = (const float*)d_in[6];
    const float* rrb  = (const float*)d_in[7];
    const float* Wo   = (const float*)d_in[8];
    const float* bo   = (const float*)d_in[9];
    const float* Wff1 = (const float*)d_in[10];
    const float* bff1 = (const float*)d_in[11];
    const float* Wff2 = (const float*)d_in[12];
    const float* bff2 = (const float*)d_in[13];
    float* out = (float*)d_out;
    float* ws  = (float*)d_ws;

    // ---- workspace (f32-slot offsets) ----
    __bf16* cat_t = (__bf16*)ws;                         // [2][2048][1024]
    __bf16* pos_t = (__bf16*)(ws + 2097152);             // [2112][1024]
    __bf16* Wqkvb = (__bf16*)(ws + 3178496);
    __bf16* Wrb   = (__bf16*)(ws + 4751360);
    __bf16* Wob   = (__bf16*)(ws + 5275648);
    __bf16* Wff1b = (__bf16*)(ws + 5799936);
    __bf16* Wff2b = (__bf16*)(ws + 7897088);
    __bf16* uqkT  = (__bf16*)(ws + 9994240);             // [2][2048][2048]
    __bf16* qkT   = (__bf16*)(ws + 14188544);            // [2][2048][2048]
    __bf16* wh_v  = (__bf16*)(ws + 18382848);            // [2][1024][2048]
    __bf16* rkT   = (__bf16*)(ws + 20480000);            // [1152][1024]
    __bf16* av_t  = (__bf16*)(ws + 21069824);            // [2][1024][1024]
    float*  ao    = ws + 22118400;                       // [2 halves][2048][1024]
    __bf16* h_bf  = (__bf16*)(ws + 26312704);            // [2048][1024]
    float2* st2   = (float2*)(ws + 27361280);            // [2][1024] float2
    __bf16* f1b   = (__bf16*)(ws + 14188544);            // overlays qkT (dead after attn)
    float*  f2    = ws + 9994240;                        // overlays uqkT (dead after qkT GEMM)

    // ---- fused prep (converts + transposes + pad) ----
    prep_all<<<27712, 256, 0, stream>>>(
        Wqkv, Wqkvb, Wr, Wrb, Wo, Wob, Wff1, Wff1b, Wff2, Wff2b,
        zh, z, cat_t, pos, pos_t, u, uqkT);

    // ---- fused qkT + wh_v + rkT GEMMs (8-wave 128x128) ----
    gemm_fused3<<<840, 512, 0, stream>>>(
        cat_t, Wqkvb, qkT, uqkT, wh_v, u + 4194304, pos_t, Wrb, rkT);

    // ---- attention -> av_t ----
    attn_mfma<<<512, 256, 0, stream>>>(qkT, wh_v, rkT, rwb, rrb, av_t);

    // ---- ao_t partials = av_t @ Wo^T (K-split 2x512) ----
    gemm_bf16_k<1><<<dim3(8, 32, 1), 512, 0, stream>>>(
        av_t, Wob, ao, nullptr, nullptr, nullptr, nullptr,
        512, 1024, 1024, 1024, 0, 0, 0LL, 0LL, 0LL, 0LL, 2097152LL);
    // ---- h = LN(ao_a + ao_b + bo + z) ----
    ln1_kernel<<<dim3(1024, 2), 256, 0, stream>>>(ao, ao + 2097152, bo, cat_t, h_bf);
    // ---- f1 = relu(h @ Wff1^T + bff1) ----
    gemm_bf16_k<0><<<dim3(32, 16, 1), 512, 0, stream>>>(
        h_bf, Wff1b, nullptr, f1b, nullptr, nullptr, bff1,
        1024, 1024, 1024, 4096, 0, 1, 0LL, 0LL, 0LL, 0LL, 0LL);
    // ---- f2 partials = f1 @ Wff2^T + bff2 (K-split 2x2048) ----
    gemm_bf16_k<1><<<dim3(8, 32, 1), 512, 0, stream>>>(
        f1b, Wff2b, f2, nullptr, nullptr, nullptr, bff2,
        2048, 4096, 4096, 1024, 0, 0, 0LL, 0LL, 0LL, 0LL, 2097152LL);
    // ---- out = LN(f2a + f2b + h), two-pass transposed ----
    ln2_stats<<<dim3(1024, 2), 256, 0, stream>>>(f2, f2 + 2097152, h_bf, st2);
    ln2_write<<<dim3(32, 32, 2), 256, 0, stream>>>(f2, f2 + 2097152, h_bf, st2, out);
}